// Round 1
// baseline (1004.025 us; speedup 1.0000x reference)
//
#include <hip/hip_runtime.h>
#include <math.h>

#define EMB 768
#define MSUB 32
#define KCODE 256
#define DSUB 24
#define NCOLS 5120   // 1024 + 4096

#define TILE 64
#define BK 16

// ---------------- generic NT GEMM: C[i,j] = sum_k A[i,k]*B[j,k] ----------------
// A: (M, K) row-major lda, B: (N, K) row-major ldb, C: row-major ldc (pre-offset).
// M, N multiples of 64; K multiple of 16.
__global__ __launch_bounds__(256) void gemm_nt_kernel(
    const float* __restrict__ A, const float* __restrict__ B, float* __restrict__ C,
    int K, int lda, int ldb, int ldc)
{
    __shared__ float As[BK][TILE];
    __shared__ float Bs[BK][TILE];
    const int tid  = threadIdx.x;
    const int row0 = blockIdx.y * TILE;
    const int col0 = blockIdx.x * TILE;
    const int lrow = tid >> 2;          // 0..63
    const int lc4  = (tid & 3) << 2;    // 0,4,8,12
    const float* Ap = A + (size_t)(row0 + lrow) * lda + lc4;
    const float* Bp = B + (size_t)(col0 + lrow) * ldb + lc4;
    const int ty = tid >> 4;            // 0..15
    const int tx = tid & 15;            // 0..15
    float acc[4][4] = {};

    for (int k0 = 0; k0 < K; k0 += BK) {
        const float4 av = *(const float4*)(Ap + k0);
        const float4 bv = *(const float4*)(Bp + k0);
        __syncthreads();   // previous iteration's reads complete
        As[lc4 + 0][lrow] = av.x; As[lc4 + 1][lrow] = av.y;
        As[lc4 + 2][lrow] = av.z; As[lc4 + 3][lrow] = av.w;
        Bs[lc4 + 0][lrow] = bv.x; Bs[lc4 + 1][lrow] = bv.y;
        Bs[lc4 + 2][lrow] = bv.z; Bs[lc4 + 3][lrow] = bv.w;
        __syncthreads();
#pragma unroll
        for (int kk = 0; kk < BK; ++kk) {
            const float4 a = *(const float4*)&As[kk][ty << 2];
            const float4 b = *(const float4*)&Bs[kk][tx << 2];
            float ar[4] = {a.x, a.y, a.z, a.w};
            float br[4] = {b.x, b.y, b.z, b.w};
#pragma unroll
            for (int r = 0; r < 4; ++r)
#pragma unroll
                for (int c = 0; c < 4; ++c)
                    acc[r][c] += ar[r] * br[c];
        }
    }
#pragma unroll
    for (int r = 0; r < 4; ++r) {
        float4 v = make_float4(acc[r][0], acc[r][1], acc[r][2], acc[r][3]);
        *(float4*)&C[(size_t)(row0 + ty * 4 + r) * ldc + col0 + tx * 4] = v;
    }
}

// ---------------- IVF center gather ----------------
__global__ void gather_kernel(const float* __restrict__ centers,
                              const int* __restrict__ ids,
                              float* __restrict__ out)
{
    const int i = blockIdx.x;
    const int t = threadIdx.x;  // 192 threads, 192*4 = 768 floats
    const int id = ids[i];
    ((float4*)(out + (size_t)i * EMB))[t] =
        ((const float4*)(centers + (size_t)id * EMB))[t];
}

// ---------------- PQ quantize (in place): r <- codebook[m, argmin_k ||(r-c)-cb||^2] + c
__global__ __launch_bounds__(256) void pq_quantize_kernel(
    float* __restrict__ r, const float* __restrict__ centers,
    const float* __restrict__ cb)
{
    const int n = blockIdx.x;
    const int m = blockIdx.y;
    const int t = threadIdx.x;     // codeword index

    __shared__ float sub[DSUB];
    __shared__ float cvals[DSUB];
    __shared__ float sdist[256];
    __shared__ int   sidx[256];

    float* rp = r + (size_t)n * EMB + m * DSUB;
    const float* cp = centers + (size_t)n * EMB + m * DSUB;
    if (t < DSUB) {
        const float cv = cp[t];
        cvals[t] = cv;
        sub[t] = rp[t] - cv;
    }
    __syncthreads();

    const float* cbp = cb + ((size_t)m * KCODE + t) * DSUB;
    float dist = 0.f;
#pragma unroll
    for (int q = 0; q < DSUB / 4; ++q) {
        const float4 c4 = *(const float4*)(cbp + q * 4);
        float d0 = sub[q * 4 + 0] - c4.x;
        float d1 = sub[q * 4 + 1] - c4.y;
        float d2 = sub[q * 4 + 2] - c4.z;
        float d3 = sub[q * 4 + 3] - c4.w;
        dist += d0 * d0 + d1 * d1 + d2 * d2 + d3 * d3;
    }
    sdist[t] = dist;
    sidx[t] = t;
    __syncthreads();
#pragma unroll
    for (int s = 128; s > 0; s >>= 1) {
        if (t < s) {
            const float od = sdist[t + s];
            const int oi = sidx[t + s];
            if (od < sdist[t] || (od == sdist[t] && oi < sidx[t])) {
                sdist[t] = od;
                sidx[t] = oi;
            }
        }
        __syncthreads();
    }
    const int kmin = sidx[0];
    if (t < DSUB) {
        rp[t] = cb[((size_t)m * KCODE + kmin) * DSUB + t] + cvals[t];
    }
}

// ---------------- distill loss: one block per row ----------------
__device__ __forceinline__ float block_reduce(float v, float* red, bool is_max)
{
    const int t = threadIdx.x;
    red[t] = v;
    __syncthreads();
#pragma unroll
    for (int s = 128; s > 0; s >>= 1) {
        if (t < s) red[t] = is_max ? fmaxf(red[t], red[t + s]) : (red[t] + red[t + s]);
        __syncthreads();
    }
    const float r = red[0];
    __syncthreads();
    return r;
}

__global__ __launch_bounds__(256) void distill_loss_kernel(
    const float* __restrict__ T, const float* __restrict__ S,
    float* __restrict__ out, float scale)
{
    __shared__ float red[256];
    const int i = blockIdx.x;
    const float* trow = T + (size_t)i * NCOLS;
    const float* srow = S + (size_t)i * NCOLS;

    float tmax = -1e30f, smax = -1e30f;
    for (int c = threadIdx.x; c < NCOLS; c += 256) {
        tmax = fmaxf(tmax, trow[c]);
        smax = fmaxf(smax, srow[c]);
    }
    tmax = block_reduce(tmax, red, true);
    smax = block_reduce(smax, red, true);

    float tsum = 0.f, ssum = 0.f;
    for (int c = threadIdx.x; c < NCOLS; c += 256) {
        tsum += expf(trow[c] - tmax);
        ssum += expf(srow[c] - smax);
    }
    tsum = block_reduce(tsum, red, false);
    ssum = block_reduce(ssum, red, false);

    const float inv_t = 1.f / tsum;
    const float inv_s = 1.f / ssum;
    float loss = 0.f;
    for (int c = threadIdx.x; c < NCOLS; c += 256) {
        const float tp = expf(trow[c] - tmax) * inv_t;
        const float p = expf(srow[c] - smax) * inv_s + 1e-6f;
        loss -= tp * logf(p);
    }
    loss = block_reduce(loss, red, false);
    if (threadIdx.x == 0) atomicAdd(out, loss * scale);
}

__global__ void zero_out_kernel(float* __restrict__ out, int n)
{
    if ((int)threadIdx.x < n) out[threadIdx.x] = 0.f;
}

// ---------------- launch ----------------
extern "C" void kernel_launch(void* const* d_in, const int* in_sizes, int n_in,
                              void* d_out, int out_size, void* d_ws, size_t ws_size,
                              hipStream_t stream)
{
    const float* q       = (const float*)d_in[0];   // 1024 x 768
    const float* d       = (const float*)d_in[1];   // 1024 x 768
    const float* nneg    = (const float*)d_in[2];   // 4096 x 768
    const float* rot     = (const float*)d_in[3];   // 768 x 768
    const float* cb      = (const float*)d_in[4];   // 32 x 256 x 24
    const float* ivf     = (const float*)d_in[5];   // 10000 x 768
    const int* doc_ids   = (const int*)d_in[6];     // 1024
    const int* neg_ids   = (const int*)d_in[7];     // 4096
    float* out = (float*)d_out;

    const int NQ = 1024, ND = 1024, NN = 4096;

    float* ws = (float*)d_ws;
    float* rq      = ws;                              // 1024*768
    float* rd      = rq + (size_t)NQ * EMB;           // 1024*768 (becomes qd)
    float* rn      = rd + (size_t)ND * EMB;           // 4096*768 (becomes qn)
    float* dc      = rn + (size_t)NN * EMB;           // 1024*768
    float* nc      = dc + (size_t)ND * EMB;           // 4096*768
    float* teacher = nc + (size_t)NN * EMB;           // 1024*5120
    float* student = teacher + (size_t)NQ * NCOLS;    // 1024*5120

    const dim3 blk(256);

    zero_out_kernel<<<1, 64, 0, stream>>>(out, out_size);

    // teacher = [q@d.T | q@n.T]
    gemm_nt_kernel<<<dim3(ND / TILE, NQ / TILE), blk, 0, stream>>>(
        q, d, teacher, EMB, EMB, EMB, NCOLS);
    gemm_nt_kernel<<<dim3(NN / TILE, NQ / TILE), blk, 0, stream>>>(
        q, nneg, teacher + ND, EMB, EMB, EMB, NCOLS);

    // rotations
    gemm_nt_kernel<<<dim3(EMB / TILE, NQ / TILE), blk, 0, stream>>>(
        q, rot, rq, EMB, EMB, EMB, EMB);
    gemm_nt_kernel<<<dim3(EMB / TILE, ND / TILE), blk, 0, stream>>>(
        d, rot, rd, EMB, EMB, EMB, EMB);
    gemm_nt_kernel<<<dim3(EMB / TILE, NN / TILE), blk, 0, stream>>>(
        nneg, rot, rn, EMB, EMB, EMB, EMB);

    // dense score + loss -> out[0]
    gemm_nt_kernel<<<dim3(ND / TILE, NQ / TILE), blk, 0, stream>>>(
        rq, rd, student, EMB, EMB, EMB, NCOLS);
    gemm_nt_kernel<<<dim3(NN / TILE, NQ / TILE), blk, 0, stream>>>(
        rq, rn, student + ND, EMB, EMB, EMB, NCOLS);
    distill_loss_kernel<<<NQ, blk, 0, stream>>>(teacher, student, out + 0, 1.f / NQ);

    // gather centers
    gather_kernel<<<ND, 192, 0, stream>>>(ivf, doc_ids, dc);
    gather_kernel<<<NN, 192, 0, stream>>>(ivf, neg_ids, nc);

    // ivf score + loss -> out[1]
    gemm_nt_kernel<<<dim3(ND / TILE, NQ / TILE), blk, 0, stream>>>(
        rq, dc, student, EMB, EMB, EMB, NCOLS);
    gemm_nt_kernel<<<dim3(NN / TILE, NQ / TILE), blk, 0, stream>>>(
        rq, nc, student + ND, EMB, EMB, EMB, NCOLS);
    distill_loss_kernel<<<NQ, blk, 0, stream>>>(teacher, student, out + 1, 1.f / NQ);

    // PQ quantize in place: rd -> qd, rn -> qn
    pq_quantize_kernel<<<dim3(ND, MSUB), blk, 0, stream>>>(rd, dc, cb);
    pq_quantize_kernel<<<dim3(NN, MSUB), blk, 0, stream>>>(rn, nc, cb);

    // pq score + loss -> out[2]
    gemm_nt_kernel<<<dim3(ND / TILE, NQ / TILE), blk, 0, stream>>>(
        rq, rd, student, EMB, EMB, EMB, NCOLS);
    gemm_nt_kernel<<<dim3(NN / TILE, NQ / TILE), blk, 0, stream>>>(
        rq, rn, student + ND, EMB, EMB, EMB, NCOLS);
    distill_loss_kernel<<<NQ, blk, 0, stream>>>(teacher, student, out + 2, 1.f / NQ);
}

// Round 2
// 304.840 us; speedup vs baseline: 3.2936x; 3.2936x over previous
//
#include <hip/hip_runtime.h>
#include <math.h>

#define EMB 768
#define MSUB 32
#define KCODE 256
#define DSUB 24
#define NQ 1024
#define NTOT 5120    // 1024 docs + 4096 negs
#define NCOLS 5120

typedef __attribute__((ext_vector_type(8))) short short8;
typedef __attribute__((ext_vector_type(4))) float floatx4;

__device__ __forceinline__ unsigned short f2bf(float f) {
    unsigned int u = __float_as_uint(f);
    unsigned int r = (u + 0x7FFFu + ((u >> 16) & 1u)) >> 16;   // RNE
    return (unsigned short)r;
}

__device__ __forceinline__ void gload16(const void* g, void* l) {
    __builtin_amdgcn_global_load_lds(
        (const __attribute__((address_space(1))) void*)g,
        (__attribute__((address_space(3))) void*)l, 16, 0, 0);
}

// ================= bf16 MFMA NT-GEMM: C[i,j] = sum_k A[i,k]*B[j,k] =================
// A: (M,K) bf16 row-major lda. B: (N,K) bf16 row-major ldb. M,N %128==0, K %32==0.
// Cf (fp32) and/or Cb (bf16) outputs, row-major ldc.
#define BM 128
#define BN 128
#define BKG 32
__global__ __launch_bounds__(256) void mfma_gemm_nt(
    const unsigned short* __restrict__ A, const unsigned short* __restrict__ B,
    float* __restrict__ Cf, unsigned short* __restrict__ Cb,
    int K, int lda, int ldb, int ldc)
{
    __shared__ __align__(16) unsigned short As[BM * BKG];   // 8 KB, granule-swizzled
    __shared__ __align__(16) unsigned short Bs[BN * BKG];
    const int tid  = threadIdx.x;
    const int wave = tid >> 6;
    const int lane = tid & 63;
    const int wr = wave >> 1, wc = wave & 1;
    const int row0 = blockIdx.y * BM;
    const int col0 = blockIdx.x * BN;

    // staging: thread t writes LDS granules t and t+256 (16B each, linear dest).
    // granule g holds row=g>>2, k-chunk ksrc = (g&3) ^ ((row>>1)&3)  [XOR swizzle]
    const int g0 = tid, g1 = tid + 256;
    const int ar0 = g0 >> 2, as0 = (g0 & 3) ^ ((ar0 >> 1) & 3);
    const int ar1 = g1 >> 2, as1 = (g1 & 3) ^ ((ar1 >> 1) & 3);
    const unsigned short* Ap0 = A + (size_t)(row0 + ar0) * lda + as0 * 8;
    const unsigned short* Ap1 = A + (size_t)(row0 + ar1) * lda + as1 * 8;
    const unsigned short* Bp0 = B + (size_t)(col0 + ar0) * ldb + as0 * 8;
    const unsigned short* Bp1 = B + (size_t)(col0 + ar1) * ldb + as1 * 8;
    unsigned short* Al0 = &As[g0 * 8];
    unsigned short* Al1 = &As[g1 * 8];
    unsigned short* Bl0 = &Bs[g0 * 8];
    unsigned short* Bl1 = &Bs[g1 * 8];

    // fragment read offsets (shorts): frag row r, k-chunk kblk -> granule r*4 + (kblk ^ ((r>>1)&3))
    const int frow = lane & 15;
    const int kblk = lane >> 4;
    int aoff[4], boff[4];
#pragma unroll
    for (int m = 0; m < 4; ++m) {
        const int r = wr * 64 + m * 16 + frow;
        aoff[m] = (r * 4 + (kblk ^ ((r >> 1) & 3))) * 8;
        const int c = wc * 64 + m * 16 + frow;
        boff[m] = (c * 4 + (kblk ^ ((c >> 1) & 3))) * 8;
    }

    floatx4 acc[4][4];
#pragma unroll
    for (int m = 0; m < 4; ++m)
#pragma unroll
        for (int n = 0; n < 4; ++n)
            acc[m][n] = (floatx4){0.f, 0.f, 0.f, 0.f};

    for (int k0 = 0; k0 < K; k0 += BKG) {
        gload16(Ap0 + k0, Al0);
        gload16(Ap1 + k0, Al1);
        gload16(Bp0 + k0, Bl0);
        gload16(Bp1 + k0, Bl1);
        __syncthreads();   // drains vmcnt: staged tile visible
        short8 af[4], bf[4];
#pragma unroll
        for (int m = 0; m < 4; ++m) af[m] = *(const short8*)&As[aoff[m]];
#pragma unroll
        for (int n = 0; n < 4; ++n) bf[n] = *(const short8*)&Bs[boff[n]];
#pragma unroll
        for (int m = 0; m < 4; ++m)
#pragma unroll
            for (int n = 0; n < 4; ++n)
                acc[m][n] = __builtin_amdgcn_mfma_f32_16x16x32_bf16(
                    af[m], bf[n], acc[m][n], 0, 0, 0);
        __syncthreads();   // before next stage overwrites
    }

    // epilogue: C/D layout col=lane&15, row=(lane>>4)*4+reg  [m89-verified]
    const int crow = row0 + wr * 64 + (lane >> 4) * 4;
    const int ccol = col0 + wc * 64 + (lane & 15);
#pragma unroll
    for (int m = 0; m < 4; ++m)
#pragma unroll
        for (int n = 0; n < 4; ++n)
#pragma unroll
            for (int r = 0; r < 4; ++r) {
                const int rr = crow + m * 16 + r;
                const int cc = ccol + n * 16;
                const float v = acc[m][n][r];
                if (Cf) Cf[(size_t)rr * ldc + cc] = v;
                if (Cb) Cb[(size_t)rr * ldc + cc] = f2bf(v);
            }
}

// ================= fp32 -> bf16 conversion =================
__global__ __launch_bounds__(256) void cvt_kernel(const float* __restrict__ in,
                                                  unsigned short* __restrict__ out, int n4)
{
    const int i = blockIdx.x * 256 + threadIdx.x;
    if (i >= n4) return;
    const float4 v = ((const float4*)in)[i];
    ushort4 b;
    b.x = f2bf(v.x); b.y = f2bf(v.y); b.z = f2bf(v.z); b.w = f2bf(v.w);
    ((ushort4*)out)[i] = b;
}

// ================= IVF gather (fp32 + bf16) =================
__global__ void gather_kernel(const float* __restrict__ centers,
                              const int* __restrict__ doc_ids,
                              const int* __restrict__ neg_ids,
                              float* __restrict__ out32,
                              unsigned short* __restrict__ outb)
{
    const int i = blockIdx.x;   // 0..5119
    const int id = (i < NQ) ? doc_ids[i] : neg_ids[i - NQ];
    const int t = threadIdx.x;  // 192 threads * float4 = 768
    const float4 v = ((const float4*)(centers + (size_t)id * EMB))[t];
    ((float4*)(out32 + (size_t)i * EMB))[t] = v;
    ushort4 b;
    b.x = f2bf(v.x); b.y = f2bf(v.y); b.z = f2bf(v.z); b.w = f2bf(v.w);
    ((ushort4*)(outb + (size_t)i * EMB))[t] = b;
}

// ================= PQ quantize: thread-per-row, codebook[m] in LDS =================
// out_bf16[n][m*24..] = bf16( cb[m][argmin_k ||(r-c)-cb[m][k]||^2] + c )
__global__ __launch_bounds__(256) void pq_kernel(
    const float* __restrict__ r32, const float* __restrict__ c32,
    const float* __restrict__ cb, unsigned short* __restrict__ outb)
{
    const int m = blockIdx.y;
    const int n = blockIdx.x * 256 + threadIdx.x;
    __shared__ float scb[KCODE][DSUB];   // 24 KB

    const float* cbm = cb + (size_t)m * KCODE * DSUB;
    for (int idx = threadIdx.x; idx < KCODE * DSUB / 4; idx += 256)
        ((float4*)&scb[0][0])[idx] = ((const float4*)cbm)[idx];
    __syncthreads();

    const float* rp = r32 + (size_t)n * EMB + m * DSUB;
    const float* cp = c32 + (size_t)n * EMB + m * DSUB;
    float sub[DSUB], cv[DSUB];
#pragma unroll
    for (int j = 0; j < DSUB; j += 4) {
        const float4 a = *(const float4*)(rp + j);
        const float4 c = *(const float4*)(cp + j);
        cv[j + 0] = c.x; cv[j + 1] = c.y; cv[j + 2] = c.z; cv[j + 3] = c.w;
        sub[j + 0] = a.x - c.x; sub[j + 1] = a.y - c.y;
        sub[j + 2] = a.z - c.z; sub[j + 3] = a.w - c.w;
    }

    float best = 3.4e38f;
    int kmin = 0;
    for (int k = 0; k < KCODE; ++k) {
        const float4* crow = (const float4*)&scb[k][0];   // broadcast reads
        float dd = 0.f;
#pragma unroll
        for (int j = 0; j < 6; ++j) {
            const float4 c = crow[j];
            const float d0 = sub[j * 4 + 0] - c.x;
            const float d1 = sub[j * 4 + 1] - c.y;
            const float d2 = sub[j * 4 + 2] - c.z;
            const float d3 = sub[j * 4 + 3] - c.w;
            dd = fmaf(d0, d0, dd); dd = fmaf(d1, d1, dd);
            dd = fmaf(d2, d2, dd); dd = fmaf(d3, d3, dd);
        }
        if (dd < best) { best = dd; kmin = k; }   // strict < keeps first (argmax tie rule)
    }

    unsigned short* op = outb + (size_t)n * EMB + m * DSUB;
#pragma unroll
    for (int j = 0; j < 6; ++j) {
        ushort4 b;
        b.x = f2bf(scb[kmin][j * 4 + 0] + cv[j * 4 + 0]);
        b.y = f2bf(scb[kmin][j * 4 + 1] + cv[j * 4 + 1]);
        b.z = f2bf(scb[kmin][j * 4 + 2] + cv[j * 4 + 2]);
        b.w = f2bf(scb[kmin][j * 4 + 3] + cv[j * 4 + 3]);
        ((ushort4*)op)[j] = b;
    }
}

// ================= softmax stats (one pass, online max/sum) =================
__device__ __forceinline__ void ms_combine(float& m, float& s, float m2, float s2)
{
    const float M = fmaxf(m, m2);
    s = s * expf(m - M) + s2 * expf(m2 - M);
    m = M;
}

__global__ __launch_bounds__(256) void tstats_kernel(const float* __restrict__ T,
                                                     float* __restrict__ tst)
{
    __shared__ float redm[256], reds[256];
    const int i = blockIdx.x, t = threadIdx.x;
    const float4* t4 = (const float4*)(T + (size_t)i * NCOLS);
    float m = -3.4e38f, s = 0.f;
    for (int c = t; c < NCOLS / 4; c += 256) {
        const float4 v = t4[c];
        const float mx = fmaxf(fmaxf(v.x, v.y), fmaxf(v.z, v.w));
        const float M = fmaxf(m, mx);
        s = s * expf(m - M) + expf(v.x - M) + expf(v.y - M) + expf(v.z - M) + expf(v.w - M);
        m = M;
    }
    redm[t] = m; reds[t] = s;
    __syncthreads();
#pragma unroll
    for (int st = 128; st > 0; st >>= 1) {
        if (t < st) {
            float mm = redm[t], ss = reds[t];
            ms_combine(mm, ss, redm[t + st], reds[t + st]);
            redm[t] = mm; reds[t] = ss;
        }
        __syncthreads();
    }
    if (t == 0) { tst[i * 2] = redm[0]; tst[i * 2 + 1] = reds[0]; }
}

// ================= distill loss: stats(S) online + CE pass =================
__global__ __launch_bounds__(256) void loss_kernel(
    const float* __restrict__ T, const float* __restrict__ S,
    const float* __restrict__ tst, float* __restrict__ out, float scale)
{
    __shared__ float redm[256], reds[256];
    const int i = blockIdx.x, t = threadIdx.x;
    const float4* s4 = (const float4*)(S + (size_t)i * NCOLS);
    const float4* t4 = (const float4*)(T + (size_t)i * NCOLS);

    float m = -3.4e38f, s = 0.f;
    for (int c = t; c < NCOLS / 4; c += 256) {
        const float4 v = s4[c];
        const float mx = fmaxf(fmaxf(v.x, v.y), fmaxf(v.z, v.w));
        const float M = fmaxf(m, mx);
        s = s * expf(m - M) + expf(v.x - M) + expf(v.y - M) + expf(v.z - M) + expf(v.w - M);
        m = M;
    }
    redm[t] = m; reds[t] = s;
    __syncthreads();
#pragma unroll
    for (int st = 128; st > 0; st >>= 1) {
        if (t < st) {
            float mm = redm[t], ss = reds[t];
            ms_combine(mm, ss, redm[t + st], reds[t + st]);
            redm[t] = mm; reds[t] = ss;
        }
        __syncthreads();
    }
    const float smax = redm[0];
    const float inv_ssum = 1.f / reds[0];
    __syncthreads();
    const float tmax = tst[i * 2];
    const float inv_tsum = 1.f / tst[i * 2 + 1];

    float loss = 0.f;
    for (int c = t; c < NCOLS / 4; c += 256) {
        const float4 sv = s4[c];
        const float4 tv = t4[c];
        loss -= expf(tv.x - tmax) * inv_tsum * logf(expf(sv.x - smax) * inv_ssum + 1e-6f);
        loss -= expf(tv.y - tmax) * inv_tsum * logf(expf(sv.y - smax) * inv_ssum + 1e-6f);
        loss -= expf(tv.z - tmax) * inv_tsum * logf(expf(sv.z - smax) * inv_ssum + 1e-6f);
        loss -= expf(tv.w - tmax) * inv_tsum * logf(expf(sv.w - smax) * inv_ssum + 1e-6f);
    }
    redm[t] = loss;
    __syncthreads();
#pragma unroll
    for (int st = 128; st > 0; st >>= 1) {
        if (t < st) redm[t] += redm[t + st];
        __syncthreads();
    }
    if (t == 0) atomicAdd(out, redm[0] * scale);
}

__global__ void zero_out_kernel(float* __restrict__ out, int n)
{
    if ((int)threadIdx.x < n) out[threadIdx.x] = 0.f;
}

// ================= launch =================
extern "C" void kernel_launch(void* const* d_in, const int* in_sizes, int n_in,
                              void* d_out, int out_size, void* d_ws, size_t ws_size,
                              hipStream_t stream)
{
    const float* q    = (const float*)d_in[0];   // 1024 x 768
    const float* dpos = (const float*)d_in[1];   // 1024 x 768
    const float* nneg = (const float*)d_in[2];   // 4096 x 768
    const float* rot  = (const float*)d_in[3];   // 768 x 768
    const float* cb   = (const float*)d_in[4];   // 32 x 256 x 24
    const float* ivf  = (const float*)d_in[5];   // 10000 x 768
    const int* doc_ids = (const int*)d_in[6];
    const int* neg_ids = (const int*)d_in[7];
    float* out = (float*)d_out;

    // ---- workspace layout (256B-aligned) ----
    char* p = (char*)d_ws;
    auto take = [&](size_t bytes) { char* r = p; p += (bytes + 255) & ~(size_t)255; return r; };
    unsigned short* qb    = (unsigned short*)take((size_t)NQ * EMB * 2);
    unsigned short* dnb   = (unsigned short*)take((size_t)NTOT * EMB * 2);
    unsigned short* rotb  = (unsigned short*)take((size_t)EMB * EMB * 2);
    unsigned short* rqb   = (unsigned short*)take((size_t)NQ * EMB * 2);
    unsigned short* rdnb  = (unsigned short*)take((size_t)NTOT * EMB * 2);  // reused as qdnb
    float*          rdn32 = (float*)take((size_t)NTOT * EMB * 4);
    float*          cc32  = (float*)take((size_t)NTOT * EMB * 4);
    unsigned short* ccb   = (unsigned short*)take((size_t)NTOT * EMB * 2);
    float*          teacher = (float*)take((size_t)NQ * NCOLS * 4);
    float*          student = (float*)take((size_t)NQ * NCOLS * 4);
    float*          tst     = (float*)take((size_t)NQ * 2 * 4);

    const float scale = 1.f / NQ;
    zero_out_kernel<<<1, 64, 0, stream>>>(out, out_size);

    // bf16 conversions
    cvt_kernel<<<(NQ * EMB / 4 + 255) / 256, 256, 0, stream>>>(q, qb, NQ * EMB / 4);
    cvt_kernel<<<(NQ * EMB / 4 + 255) / 256, 256, 0, stream>>>(dpos, dnb, NQ * EMB / 4);
    cvt_kernel<<<(4096 * EMB / 4 + 255) / 256, 256, 0, stream>>>(nneg, dnb + (size_t)NQ * EMB, 4096 * EMB / 4);
    cvt_kernel<<<(EMB * EMB / 4 + 255) / 256, 256, 0, stream>>>(rot, rotb, EMB * EMB / 4);

    // teacher = q @ [d|n]^T  (fp32)
    mfma_gemm_nt<<<dim3(NTOT / BN, NQ / BM), 256, 0, stream>>>(
        qb, dnb, teacher, nullptr, EMB, EMB, EMB, NCOLS);
    tstats_kernel<<<NQ, 256, 0, stream>>>(teacher, tst);

    // rotations: rq (bf16 only), rdn (fp32 + bf16)
    mfma_gemm_nt<<<dim3(EMB / BN, NQ / BM), 256, 0, stream>>>(
        qb, rotb, nullptr, rqb, EMB, EMB, EMB, EMB);
    mfma_gemm_nt<<<dim3(EMB / BN, NTOT / BM), 256, 0, stream>>>(
        dnb, rotb, rdn32, rdnb, EMB, EMB, EMB, EMB);

    // dense score + loss
    mfma_gemm_nt<<<dim3(NTOT / BN, NQ / BM), 256, 0, stream>>>(
        rqb, rdnb, student, nullptr, EMB, EMB, EMB, NCOLS);
    loss_kernel<<<NQ, 256, 0, stream>>>(teacher, student, tst, out + 0, scale);

    // gather centers (fp32 + bf16)
    gather_kernel<<<NTOT, EMB / 4, 0, stream>>>(ivf, doc_ids, neg_ids, cc32, ccb);

    // ivf score + loss
    mfma_gemm_nt<<<dim3(NTOT / BN, NQ / BM), 256, 0, stream>>>(
        rqb, ccb, student, nullptr, EMB, EMB, EMB, NCOLS);
    loss_kernel<<<NQ, 256, 0, stream>>>(teacher, student, tst, out + 1, scale);

    // PQ quantize residuals -> bf16 codes (+center), overwrite rdnb
    pq_kernel<<<dim3(NTOT / 256, MSUB), 256, 0, stream>>>(rdn32, cc32, cb, rdnb);

    // pq score + loss
    mfma_gemm_nt<<<dim3(NTOT / BN, NQ / BM), 256, 0, stream>>>(
        rqb, rdnb, student, nullptr, EMB, EMB, EMB, NCOLS);
    loss_kernel<<<NQ, 256, 0, stream>>>(teacher, student, tst, out + 2, scale);
}

// Round 3
// 298.707 us; speedup vs baseline: 3.3612x; 1.0205x over previous
//
#include <hip/hip_runtime.h>
#include <math.h>

#define EMB 768
#define MSUB 32
#define KCODE 256
#define DSUB 24
#define NQ 1024
#define NTOT 5120    // 1024 docs + 4096 negs
#define NCOLS 5120

typedef __attribute__((ext_vector_type(8))) short short8;
typedef __attribute__((ext_vector_type(4))) float floatx4;

__device__ __forceinline__ unsigned short f2bf(float f) {
    unsigned int u = __float_as_uint(f);
    unsigned int r = (u + 0x7FFFu + ((u >> 16) & 1u)) >> 16;   // RNE
    return (unsigned short)r;
}
__device__ __forceinline__ float bf2f(unsigned short h) {
    return __uint_as_float((unsigned int)h << 16);
}

__device__ __forceinline__ void gload16(const void* g, void* l) {
    __builtin_amdgcn_global_load_lds(
        (const __attribute__((address_space(1))) void*)g,
        (__attribute__((address_space(3))) void*)l, 16, 0, 0);
}

// ================= bf16 MFMA NT-GEMM: C[i,j] = sum_k A[i,k]*B[j,k] =================
// BM=64 x BN=128 tile, 4 waves (2M x 2N), 640-ish block grids for CU balance.
// Optional epilogue: Cb = bf16(acc); Cf[(rr-row_off)] = acc - bf16dec(subC) for rr>=row_off.
#define BM 64
#define BN 128
#define BKG 32
__global__ __launch_bounds__(256) void mfma_gemm_nt(
    const unsigned short* __restrict__ A, const unsigned short* __restrict__ B,
    float* __restrict__ Cf, unsigned short* __restrict__ Cb,
    const unsigned short* __restrict__ subC,
    int K, int lda, int ldb, int ldcf, int ldcb, int row_off)
{
    __shared__ __align__(16) unsigned short As[BM * BKG];   // 4 KB
    __shared__ __align__(16) unsigned short Bs[BN * BKG];   // 8 KB
    const int tid  = threadIdx.x;
    const int wave = tid >> 6;
    const int lane = tid & 63;
    const int wr = wave >> 1, wc = wave & 1;
    const int row0 = blockIdx.y * BM;
    const int col0 = blockIdx.x * BN;

    // staging: granule g (16B) holds row=g>>2, k-chunk (g&3)^((row>>1)&3) [XOR swizzle]
    const int ar  = tid >> 2, aks  = (tid & 3) ^ ((ar >> 1) & 3);
    const unsigned short* Ap = A + (size_t)(row0 + ar) * lda + aks * 8;
    unsigned short* Al = &As[tid * 8];
    const int br0 = tid >> 2,        bks0 = (tid & 3) ^ ((br0 >> 1) & 3);
    const int br1 = 64 + (tid >> 2), bks1 = (tid & 3) ^ ((br1 >> 1) & 3);
    const unsigned short* Bp0 = B + (size_t)(col0 + br0) * ldb + bks0 * 8;
    const unsigned short* Bp1 = B + (size_t)(col0 + br1) * ldb + bks1 * 8;
    unsigned short* Bl0 = &Bs[tid * 8];
    unsigned short* Bl1 = &Bs[(tid + 256) * 8];

    const int frow = lane & 15;
    const int kblk = lane >> 4;
    int aoff[2], boff[4];
#pragma unroll
    for (int m = 0; m < 2; ++m) {
        const int r = wr * 32 + m * 16 + frow;
        aoff[m] = (r * 4 + (kblk ^ ((r >> 1) & 3))) * 8;
    }
#pragma unroll
    for (int n = 0; n < 4; ++n) {
        const int c = wc * 64 + n * 16 + frow;
        boff[n] = (c * 4 + (kblk ^ ((c >> 1) & 3))) * 8;
    }

    floatx4 acc[2][4];
#pragma unroll
    for (int m = 0; m < 2; ++m)
#pragma unroll
        for (int n = 0; n < 4; ++n)
            acc[m][n] = (floatx4){0.f, 0.f, 0.f, 0.f};

    for (int k0 = 0; k0 < K; k0 += BKG) {
        gload16(Ap + k0, Al);
        gload16(Bp0 + k0, Bl0);
        gload16(Bp1 + k0, Bl1);
        __syncthreads();   // drains vmcnt: staged tile visible
        short8 af[2], bf[4];
#pragma unroll
        for (int m = 0; m < 2; ++m) af[m] = *(const short8*)&As[aoff[m]];
#pragma unroll
        for (int n = 0; n < 4; ++n) bf[n] = *(const short8*)&Bs[boff[n]];
#pragma unroll
        for (int m = 0; m < 2; ++m)
#pragma unroll
            for (int n = 0; n < 4; ++n)
                acc[m][n] = __builtin_amdgcn_mfma_f32_16x16x32_bf16(
                    af[m], bf[n], acc[m][n], 0, 0, 0);
        __syncthreads();   // before next stage overwrites
    }

    // epilogue: C/D layout col=lane&15, row=(lane>>4)*4+reg
    const int crow = row0 + wr * 32 + (lane >> 4) * 4;
    const int ccol = col0 + wc * 64 + (lane & 15);
#pragma unroll
    for (int m = 0; m < 2; ++m)
#pragma unroll
        for (int n = 0; n < 4; ++n)
#pragma unroll
            for (int r = 0; r < 4; ++r) {
                const int rr = crow + m * 16 + r;
                const int cc = ccol + n * 16;
                const float v = acc[m][n][r];
                if (Cb) Cb[(size_t)rr * ldcb + cc] = f2bf(v);
                if (Cf && rr >= row_off) {
                    const size_t idx = (size_t)(rr - row_off) * ldcf + cc;
                    Cf[idx] = subC ? (v - bf2f(subC[idx])) : v;
                }
            }
}

// ================= fused fp32 -> bf16 conversion (q, d, n -> qdnb; rot -> rotb) ======
__global__ __launch_bounds__(256) void cvt_all_kernel(
    const float* __restrict__ q, const float* __restrict__ d,
    const float* __restrict__ n, const float* __restrict__ rot,
    unsigned short* __restrict__ qdnb, unsigned short* __restrict__ rotb)
{
    const int i = blockIdx.x * 256 + threadIdx.x;  // float4 index
    const int S1 = NQ * EMB / 4;              // q
    const int S2 = S1 + NQ * EMB / 4;         // d
    const int S3 = S2 + 4096 * EMB / 4;       // n
    const int S4 = S3 + EMB * EMB / 4;        // rot
    const float* src; unsigned short* dst; int off;
    if (i < S1)      { src = q;   dst = qdnb;                          off = i; }
    else if (i < S2) { src = d;   dst = qdnb + (size_t)NQ * EMB;       off = i - S1; }
    else if (i < S3) { src = n;   dst = qdnb + (size_t)2 * NQ * EMB;   off = i - S2; }
    else if (i < S4) { src = rot; dst = rotb;                          off = i - S3; }
    else return;
    const float4 v = ((const float4*)src)[off];
    ushort4 b;
    b.x = f2bf(v.x); b.y = f2bf(v.y); b.z = f2bf(v.z); b.w = f2bf(v.w);
    ((ushort4*)dst)[off] = b;
}

// ================= IVF gather (bf16) =================
__global__ void gather_kernel(const float* __restrict__ centers,
                              const int* __restrict__ doc_ids,
                              const int* __restrict__ neg_ids,
                              unsigned short* __restrict__ outb)
{
    const int i = blockIdx.x;   // 0..5119
    const int id = (i < NQ) ? doc_ids[i] : neg_ids[i - NQ];
    const int t = threadIdx.x;  // 192 threads * float4 = 768
    const float4 v = ((const float4*)(centers + (size_t)id * EMB))[t];
    ushort4 b;
    b.x = f2bf(v.x); b.y = f2bf(v.y); b.z = f2bf(v.z); b.w = f2bf(v.w);
    ((ushort4*)(outb + (size_t)i * EMB))[t] = b;
}

// ================= PQ argmin: lane owns 4 codewords in regs, rows broadcast =========
// argmin_k ||sub - c_k||^2 == argmin_k (0.5*||c_k||^2 - <sub, c_k>)
__global__ __launch_bounds__(256) void pq_argmin_kernel(
    const float* __restrict__ sub32, const float* __restrict__ cb,
    unsigned char* __restrict__ codes)
{
    const int m = blockIdx.y;
    const int wave = threadIdx.x >> 6, lane = threadIdx.x & 63;
    const int row0 = (blockIdx.x * 4 + wave) * 64;

    float c[4][DSUB];
    float bias[4];
#pragma unroll
    for (int kk = 0; kk < 4; ++kk) {
        const float* cp = cb + ((size_t)m * KCODE + kk * 64 + lane) * DSUB;
        float ss = 0.f;
#pragma unroll
        for (int j = 0; j < 6; ++j) {
            const float4 v = *(const float4*)(cp + j * 4);
            c[kk][j * 4 + 0] = v.x; c[kk][j * 4 + 1] = v.y;
            c[kk][j * 4 + 2] = v.z; c[kk][j * 4 + 3] = v.w;
            ss = fmaf(v.x, v.x, ss); ss = fmaf(v.y, v.y, ss);
            ss = fmaf(v.z, v.z, ss); ss = fmaf(v.w, v.w, ss);
        }
        bias[kk] = 0.5f * ss;
    }

    for (int row = row0; row < row0 + 64; ++row) {
        const float* sp = sub32 + (size_t)row * EMB + m * DSUB;  // broadcast (uniform addr)
        float s[DSUB];
#pragma unroll
        for (int j = 0; j < 6; ++j) {
            const float4 v = *(const float4*)(sp + j * 4);
            s[j * 4 + 0] = v.x; s[j * 4 + 1] = v.y;
            s[j * 4 + 2] = v.z; s[j * 4 + 3] = v.w;
        }
        unsigned best = 0xFFFFFFFFu;
#pragma unroll
        for (int kk = 0; kk < 4; ++kk) {
            float ip = 0.f;
#pragma unroll
            for (int j = 0; j < DSUB; ++j) ip = fmaf(c[kk][j], s[j], ip);
            const float dv = bias[kk] - ip;
            unsigned u = __float_as_uint(dv);
            u ^= (unsigned)((int)u >> 31) | 0x80000000u;      // monotonic float->uint
            const unsigned key = (u & 0xFFFFFF00u) | (unsigned)(kk * 64 + lane);
            best = min(best, key);
        }
#pragma unroll
        for (int off = 32; off >= 1; off >>= 1)
            best = min(best, (unsigned)__shfl_xor((int)best, off));
        if (lane == 0) codes[(size_t)row * MSUB + m] = (unsigned char)(best & 0xFFu);
    }
}

// ================= PQ reconstruct: out_bf16 = cb[m][k] + center =================
__global__ __launch_bounds__(256) void pq_recon_kernel(
    const unsigned char* __restrict__ codes, const float* __restrict__ cb,
    const unsigned short* __restrict__ ccb, unsigned short* __restrict__ outb)
{
    const int idx = blockIdx.x * 256 + threadIdx.x;  // n*32+m
    const int n = idx >> 5, m = idx & 31;
    const int k = codes[idx];
    const float* cp = cb + ((size_t)m * KCODE + k) * DSUB;
    const unsigned short* ccp = ccb + (size_t)n * EMB + m * DSUB;
    unsigned short* op = outb + (size_t)n * EMB + m * DSUB;
#pragma unroll
    for (int j = 0; j < 6; ++j) {
        const float4 a = *(const float4*)(cp + j * 4);
        const ushort4 cc = ((const ushort4*)ccp)[j];
        ushort4 o;
        o.x = f2bf(a.x + bf2f(cc.x)); o.y = f2bf(a.y + bf2f(cc.y));
        o.z = f2bf(a.z + bf2f(cc.z)); o.w = f2bf(a.w + bf2f(cc.w));
        ((ushort4*)op)[j] = o;
    }
}

// ================= softmax stats (one pass, online max/sum) =================
__device__ __forceinline__ void ms_combine(float& m, float& s, float m2, float s2)
{
    const float M = fmaxf(m, m2);
    s = s * expf(m - M) + s2 * expf(m2 - M);
    m = M;
}

__global__ __launch_bounds__(256) void tstats_kernel(const float* __restrict__ T,
                                                     float* __restrict__ tst)
{
    __shared__ float redm[256], reds[256];
    const int i = blockIdx.x, t = threadIdx.x;
    const float4* t4 = (const float4*)(T + (size_t)i * NCOLS);
    float m = -3.4e38f, s = 0.f;
    for (int c = t; c < NCOLS / 4; c += 256) {
        const float4 v = t4[c];
        const float mx = fmaxf(fmaxf(v.x, v.y), fmaxf(v.z, v.w));
        const float M = fmaxf(m, mx);
        s = s * expf(m - M) + expf(v.x - M) + expf(v.y - M) + expf(v.z - M) + expf(v.w - M);
        m = M;
    }
    redm[t] = m; reds[t] = s;
    __syncthreads();
#pragma unroll
    for (int st = 128; st > 0; st >>= 1) {
        if (t < st) {
            float mm = redm[t], ss = reds[t];
            ms_combine(mm, ss, redm[t + st], reds[t + st]);
            redm[t] = mm; reds[t] = ss;
        }
        __syncthreads();
    }
    if (t == 0) { tst[i * 2] = redm[0]; tst[i * 2 + 1] = reds[0]; }
}

// ================= distill loss: stats(S) online + CE pass =================
__global__ __launch_bounds__(256) void loss_kernel(
    const float* __restrict__ T, const float* __restrict__ S,
    const float* __restrict__ tst, float* __restrict__ out, float scale)
{
    __shared__ float redm[256], reds[256];
    const int i = blockIdx.x, t = threadIdx.x;
    const float4* s4 = (const float4*)(S + (size_t)i * NCOLS);
    const float4* t4 = (const float4*)(T + (size_t)i * NCOLS);

    float m = -3.4e38f, s = 0.f;
    for (int c = t; c < NCOLS / 4; c += 256) {
        const float4 v = s4[c];
        const float mx = fmaxf(fmaxf(v.x, v.y), fmaxf(v.z, v.w));
        const float M = fmaxf(m, mx);
        s = s * expf(m - M) + expf(v.x - M) + expf(v.y - M) + expf(v.z - M) + expf(v.w - M);
        m = M;
    }
    redm[t] = m; reds[t] = s;
    __syncthreads();
#pragma unroll
    for (int st = 128; st > 0; st >>= 1) {
        if (t < st) {
            float mm = redm[t], ss = reds[t];
            ms_combine(mm, ss, redm[t + st], reds[t + st]);
            redm[t] = mm; reds[t] = ss;
        }
        __syncthreads();
    }
    const float smax = redm[0];
    const float inv_ssum = 1.f / reds[0];
    __syncthreads();
    const float tmax = tst[i * 2];
    const float inv_tsum = 1.f / tst[i * 2 + 1];

    float loss = 0.f;
    for (int c = t; c < NCOLS / 4; c += 256) {
        const float4 sv = s4[c];
        const float4 tv = t4[c];
        loss -= expf(tv.x - tmax) * inv_tsum * logf(expf(sv.x - smax) * inv_ssum + 1e-6f);
        loss -= expf(tv.y - tmax) * inv_tsum * logf(expf(sv.y - smax) * inv_ssum + 1e-6f);
        loss -= expf(tv.z - tmax) * inv_tsum * logf(expf(sv.z - smax) * inv_ssum + 1e-6f);
        loss -= expf(tv.w - tmax) * inv_tsum * logf(expf(sv.w - smax) * inv_ssum + 1e-6f);
    }
    redm[t] = loss;
    __syncthreads();
#pragma unroll
    for (int st = 128; st > 0; st >>= 1) {
        if (t < st) redm[t] += redm[t + st];
        __syncthreads();
    }
    if (t == 0) atomicAdd(out, redm[0] * scale);
}

__global__ void zero_out_kernel(float* __restrict__ out, int n)
{
    if ((int)threadIdx.x < n) out[threadIdx.x] = 0.f;
}

// ================= launch =================
extern "C" void kernel_launch(void* const* d_in, const int* in_sizes, int n_in,
                              void* d_out, int out_size, void* d_ws, size_t ws_size,
                              hipStream_t stream)
{
    const float* q    = (const float*)d_in[0];
    const float* dpos = (const float*)d_in[1];
    const float* nneg = (const float*)d_in[2];
    const float* rot  = (const float*)d_in[3];
    const float* cb   = (const float*)d_in[4];
    const float* ivf  = (const float*)d_in[5];
    const int* doc_ids = (const int*)d_in[6];
    const int* neg_ids = (const int*)d_in[7];
    float* out = (float*)d_out;

    // ---- workspace (256B-aligned), ~86 MB ----
    char* p = (char*)d_ws;
    auto take = [&](size_t bytes) { char* r = p; p += (bytes + 255) & ~(size_t)255; return r; };
    unsigned short* qdnb  = (unsigned short*)take((size_t)(NQ + NTOT) * EMB * 2); // q rows 0..1023, dn rows 1024..6143
    unsigned short* rqdnb = (unsigned short*)take((size_t)(NQ + NTOT) * EMB * 2); // rotated
    unsigned short* rotb  = (unsigned short*)take((size_t)EMB * EMB * 2);
    unsigned short* ccb   = (unsigned short*)take((size_t)NTOT * EMB * 2);
    float*          sub32 = (float*)take((size_t)NTOT * EMB * 4);
    float*          teacher = (float*)take((size_t)NQ * NCOLS * 4);
    float*          student = (float*)take((size_t)NQ * NCOLS * 4);
    unsigned char*  codes   = (unsigned char*)take((size_t)NTOT * MSUB);
    float*          tst     = (float*)take((size_t)NQ * 2 * 4);

    unsigned short* dnb  = qdnb + (size_t)NQ * EMB;
    unsigned short* rdnb = rqdnb + (size_t)NQ * EMB;

    const float scale = 1.f / NQ;
    zero_out_kernel<<<1, 64, 0, stream>>>(out, out_size);

    // 1) bf16 conversions (q,d,n -> qdnb; rot -> rotb)
    const int cvt4 = (NQ * EMB + NQ * EMB + 4096 * EMB + EMB * EMB) / 4;
    cvt_all_kernel<<<(cvt4 + 255) / 256, 256, 0, stream>>>(q, dpos, nneg, rot, qdnb, rotb);

    // 2) IVF gather -> ccb (bf16)
    gather_kernel<<<NTOT, EMB / 4, 0, stream>>>(ivf, doc_ids, neg_ids, ccb);

    // 3) rotation: [q;d;n] @ rot^T -> rqdnb (bf16); rows>=1024 also sub32 = acc - center
    mfma_gemm_nt<<<dim3(EMB / BN, (NQ + NTOT) / BM), 256, 0, stream>>>(
        qdnb, rotb, sub32, rqdnb, ccb, EMB, EMB, EMB, EMB, EMB, NQ);

    // 4) teacher = q @ [d|n]^T (fp32) + stats
    mfma_gemm_nt<<<dim3(NTOT / BN, NQ / BM), 256, 0, stream>>>(
        qdnb, dnb, teacher, nullptr, nullptr, EMB, EMB, EMB, NCOLS, 0, 0);
    tstats_kernel<<<NQ, 256, 0, stream>>>(teacher, tst);

    // 5) dense score + loss
    mfma_gemm_nt<<<dim3(NTOT / BN, NQ / BM), 256, 0, stream>>>(
        rqdnb, rdnb, student, nullptr, nullptr, EMB, EMB, EMB, NCOLS, 0, 0);
    loss_kernel<<<NQ, 256, 0, stream>>>(teacher, student, tst, out + 0, scale);

    // 6) ivf score + loss
    mfma_gemm_nt<<<dim3(NTOT / BN, NQ / BM), 256, 0, stream>>>(
        rqdnb, ccb, student, nullptr, nullptr, EMB, EMB, EMB, NCOLS, 0, 0);
    loss_kernel<<<NQ, 256, 0, stream>>>(teacher, student, tst, out + 1, scale);

    // 7) PQ: argmin codes, then reconstruct into qdnb's dn region (teacher done with it)
    pq_argmin_kernel<<<dim3(NTOT / 256, MSUB), 256, 0, stream>>>(sub32, cb, codes);
    pq_recon_kernel<<<(NTOT * MSUB) / 256, 256, 0, stream>>>(codes, cb, ccb, dnb);

    // 8) pq score + loss
    mfma_gemm_nt<<<dim3(NTOT / BN, NQ / BM), 256, 0, stream>>>(
        rqdnb, dnb, student, nullptr, nullptr, EMB, EMB, EMB, NCOLS, 0, 0);
    loss_kernel<<<NQ, 256, 0, stream>>>(teacher, student, tst, out + 2, scale);
}

// Round 4
// 298.284 us; speedup vs baseline: 3.3660x; 1.0014x over previous
//
#include <hip/hip_runtime.h>
#include <math.h>

#define EMB 768
#define MSUB 32
#define KCODE 256
#define DSUB 24
#define NQ 1024
#define NTOT 5120    // 1024 docs + 4096 negs
#define NCOLS 5120

typedef __attribute__((ext_vector_type(8))) short short8;
typedef __attribute__((ext_vector_type(4))) float floatx4;

__device__ __forceinline__ unsigned short f2bf(float f) {
    unsigned int u = __float_as_uint(f);
    unsigned int r = (u + 0x7FFFu + ((u >> 16) & 1u)) >> 16;   // RNE
    return (unsigned short)r;
}
__device__ __forceinline__ float bf2f(unsigned short h) {
    return __uint_as_float((unsigned int)h << 16);
}

__device__ __forceinline__ void gload16(const void* g, void* l) {
    __builtin_amdgcn_global_load_lds(
        (const __attribute__((address_space(1))) void*)g,
        (__attribute__((address_space(3))) void*)l, 16, 0, 0);
}

// ============ rotation GEMM: BM=64 x BN=128, bf16 out + residual fp32 out ============
// C[i,j] = sum_k A[i,k]*B[j,k].  Cb=bf16(acc); for rr>=row_off: Cf = acc - bf16dec(subC).
#define BMR 64
#define BNR 128
#define BKG 32
__global__ __launch_bounds__(256) void gemm_rot(
    const unsigned short* __restrict__ A, const unsigned short* __restrict__ B,
    float* __restrict__ Cf, unsigned short* __restrict__ Cb,
    const unsigned short* __restrict__ subC,
    int K, int lda, int ldb, int ldcf, int ldcb, int row_off)
{
    __shared__ __align__(16) unsigned short As[BMR * BKG];   // 4 KB
    __shared__ __align__(16) unsigned short Bs[BNR * BKG];   // 8 KB
    const int tid  = threadIdx.x;
    const int wave = tid >> 6;
    const int lane = tid & 63;
    const int wr = wave >> 1, wc = wave & 1;
    const int row0 = blockIdx.y * BMR;
    const int col0 = blockIdx.x * BNR;

    const int ar  = tid >> 2, aks  = (tid & 3) ^ ((ar >> 1) & 3);
    const unsigned short* Ap = A + (size_t)(row0 + ar) * lda + aks * 8;
    unsigned short* Al = &As[tid * 8];
    const int br0 = tid >> 2,        bks0 = (tid & 3) ^ ((br0 >> 1) & 3);
    const int br1 = 64 + (tid >> 2), bks1 = (tid & 3) ^ ((br1 >> 1) & 3);
    const unsigned short* Bp0 = B + (size_t)(col0 + br0) * ldb + bks0 * 8;
    const unsigned short* Bp1 = B + (size_t)(col0 + br1) * ldb + bks1 * 8;
    unsigned short* Bl0 = &Bs[tid * 8];
    unsigned short* Bl1 = &Bs[(tid + 256) * 8];

    const int frow = lane & 15;
    const int kblk = lane >> 4;
    int aoff[2], boff[4];
#pragma unroll
    for (int m = 0; m < 2; ++m) {
        const int r = wr * 32 + m * 16 + frow;
        aoff[m] = (r * 4 + (kblk ^ ((r >> 1) & 3))) * 8;
    }
#pragma unroll
    for (int n = 0; n < 4; ++n) {
        const int c = wc * 64 + n * 16 + frow;
        boff[n] = (c * 4 + (kblk ^ ((c >> 1) & 3))) * 8;
    }

    floatx4 acc[2][4];
#pragma unroll
    for (int m = 0; m < 2; ++m)
#pragma unroll
        for (int n = 0; n < 4; ++n)
            acc[m][n] = (floatx4){0.f, 0.f, 0.f, 0.f};

    for (int k0 = 0; k0 < K; k0 += BKG) {
        gload16(Ap + k0, Al);
        gload16(Bp0 + k0, Bl0);
        gload16(Bp1 + k0, Bl1);
        __syncthreads();
        short8 af[2], bf[4];
#pragma unroll
        for (int m = 0; m < 2; ++m) af[m] = *(const short8*)&As[aoff[m]];
#pragma unroll
        for (int n = 0; n < 4; ++n) bf[n] = *(const short8*)&Bs[boff[n]];
#pragma unroll
        for (int m = 0; m < 2; ++m)
#pragma unroll
            for (int n = 0; n < 4; ++n)
                acc[m][n] = __builtin_amdgcn_mfma_f32_16x16x32_bf16(
                    af[m], bf[n], acc[m][n], 0, 0, 0);
        __syncthreads();
    }

    const int crow = row0 + wr * 32 + (lane >> 4) * 4;
    const int ccol = col0 + wc * 64 + (lane & 15);
#pragma unroll
    for (int m = 0; m < 2; ++m)
#pragma unroll
        for (int n = 0; n < 4; ++n)
#pragma unroll
            for (int r = 0; r < 4; ++r) {
                const int rr = crow + m * 16 + r;
                const int cc = ccol + n * 16;
                const float v = acc[m][n][r];
                Cb[(size_t)rr * ldcb + cc] = f2bf(v);
                if (rr >= row_off) {
                    const size_t idx = (size_t)(rr - row_off) * ldcf + cc;
                    Cf[idx] = v - bf2f(subC[idx]);
                }
            }
}

// ============ batched score GEMM: BM=128 x BN=128, fp32 out, z selects A/B/C ========
#define BMS 128
#define BNS 128
__global__ __launch_bounds__(256) void gemm_score(
    const unsigned short* __restrict__ A0, const unsigned short* __restrict__ B0,
    float* __restrict__ C0,
    const unsigned short* __restrict__ A1, const unsigned short* __restrict__ B1,
    float* __restrict__ C1)
{
    const unsigned short* A = blockIdx.z ? A1 : A0;
    const unsigned short* B = blockIdx.z ? B1 : B0;
    float* C = blockIdx.z ? C1 : C0;

    __shared__ __align__(16) unsigned short As[BMS * BKG];   // 8 KB
    __shared__ __align__(16) unsigned short Bs[BNS * BKG];   // 8 KB
    const int tid  = threadIdx.x;
    const int wave = tid >> 6;
    const int lane = tid & 63;
    const int wr = wave >> 1, wc = wave & 1;
    const int row0 = blockIdx.y * BMS;
    const int col0 = blockIdx.x * BNS;

    const int g0 = tid, g1 = tid + 256;
    const int ar0 = g0 >> 2, as0 = (g0 & 3) ^ ((ar0 >> 1) & 3);
    const int ar1 = g1 >> 2, as1 = (g1 & 3) ^ ((ar1 >> 1) & 3);
    const unsigned short* Ap0 = A + (size_t)(row0 + ar0) * EMB + as0 * 8;
    const unsigned short* Ap1 = A + (size_t)(row0 + ar1) * EMB + as1 * 8;
    const unsigned short* Bp0 = B + (size_t)(col0 + ar0) * EMB + as0 * 8;
    const unsigned short* Bp1 = B + (size_t)(col0 + ar1) * EMB + as1 * 8;
    unsigned short* Al0 = &As[g0 * 8];
    unsigned short* Al1 = &As[g1 * 8];
    unsigned short* Bl0 = &Bs[g0 * 8];
    unsigned short* Bl1 = &Bs[g1 * 8];

    const int frow = lane & 15;
    const int kblk = lane >> 4;
    int aoff[4], boff[4];
#pragma unroll
    for (int m = 0; m < 4; ++m) {
        const int r = wr * 64 + m * 16 + frow;
        aoff[m] = (r * 4 + (kblk ^ ((r >> 1) & 3))) * 8;
        const int c = wc * 64 + m * 16 + frow;
        boff[m] = (c * 4 + (kblk ^ ((c >> 1) & 3))) * 8;
    }

    floatx4 acc[4][4];
#pragma unroll
    for (int m = 0; m < 4; ++m)
#pragma unroll
        for (int n = 0; n < 4; ++n)
            acc[m][n] = (floatx4){0.f, 0.f, 0.f, 0.f};

    for (int k0 = 0; k0 < EMB; k0 += BKG) {
        gload16(Ap0 + k0, Al0);
        gload16(Ap1 + k0, Al1);
        gload16(Bp0 + k0, Bl0);
        gload16(Bp1 + k0, Bl1);
        __syncthreads();
        short8 af[4], bf[4];
#pragma unroll
        for (int m = 0; m < 4; ++m) af[m] = *(const short8*)&As[aoff[m]];
#pragma unroll
        for (int n = 0; n < 4; ++n) bf[n] = *(const short8*)&Bs[boff[n]];
#pragma unroll
        for (int m = 0; m < 4; ++m)
#pragma unroll
            for (int n = 0; n < 4; ++n)
                acc[m][n] = __builtin_amdgcn_mfma_f32_16x16x32_bf16(
                    af[m], bf[n], acc[m][n], 0, 0, 0);
        __syncthreads();
    }

    const int crow = row0 + wr * 64 + (lane >> 4) * 4;
    const int ccol = col0 + wc * 64 + (lane & 15);
#pragma unroll
    for (int m = 0; m < 4; ++m)
#pragma unroll
        for (int n = 0; n < 4; ++n)
#pragma unroll
            for (int r = 0; r < 4; ++r)
                C[(size_t)(crow + m * 16 + r) * NCOLS + ccol + n * 16] = acc[m][n][r];
}

// ============ fused fp32 -> bf16 conversion ============
__global__ __launch_bounds__(256) void cvt_all_kernel(
    const float* __restrict__ q, const float* __restrict__ d,
    const float* __restrict__ n, const float* __restrict__ rot,
    unsigned short* __restrict__ qdnb, unsigned short* __restrict__ rotb)
{
    const int i = blockIdx.x * 256 + threadIdx.x;  // float4 index
    const int S1 = NQ * EMB / 4;
    const int S2 = S1 + NQ * EMB / 4;
    const int S3 = S2 + 4096 * EMB / 4;
    const int S4 = S3 + EMB * EMB / 4;
    const float* src; unsigned short* dst; int off;
    if (i < S1)      { src = q;   dst = qdnb;                          off = i; }
    else if (i < S2) { src = d;   dst = qdnb + (size_t)NQ * EMB;       off = i - S1; }
    else if (i < S3) { src = n;   dst = qdnb + (size_t)2 * NQ * EMB;   off = i - S2; }
    else if (i < S4) { src = rot; dst = rotb;                          off = i - S3; }
    else return;
    const float4 v = ((const float4*)src)[off];
    ushort4 b;
    b.x = f2bf(v.x); b.y = f2bf(v.y); b.z = f2bf(v.z); b.w = f2bf(v.w);
    ((ushort4*)dst)[off] = b;
}

// ============ IVF gather (bf16) ============
__global__ void gather_kernel(const float* __restrict__ centers,
                              const int* __restrict__ doc_ids,
                              const int* __restrict__ neg_ids,
                              unsigned short* __restrict__ outb)
{
    const int i = blockIdx.x;
    const int id = (i < NQ) ? doc_ids[i] : neg_ids[i - NQ];
    const int t = threadIdx.x;
    const float4 v = ((const float4*)(centers + (size_t)id * EMB))[t];
    ushort4 b;
    b.x = f2bf(v.x); b.y = f2bf(v.y); b.z = f2bf(v.z); b.w = f2bf(v.w);
    ((ushort4*)(outb + (size_t)i * EMB))[t] = b;
}

// ============ PQ argmin: 4 codewords/lane in REGISTERS, 2 rows per iter ============
// argmin_k ||sub - c_k||^2 == argmin_k (0.5*||c_k||^2 - <sub, c_k>)
__global__ __launch_bounds__(256, 1) void pq_argmin_kernel(
    const float* __restrict__ sub32, const float* __restrict__ cb,
    unsigned char* __restrict__ codes)
{
    const int m = blockIdx.y;
    const int wave = threadIdx.x >> 6, lane = threadIdx.x & 63;
    const int row0 = (blockIdx.x * 4 + wave) * 64;

    float c[4][DSUB];
    float bias[4];
#pragma unroll
    for (int kk = 0; kk < 4; ++kk) {
        const float* cp = cb + ((size_t)m * KCODE + kk * 64 + lane) * DSUB;
        float ss = 0.f;
#pragma unroll
        for (int j = 0; j < 6; ++j) {
            const float4 v = *(const float4*)(cp + j * 4);
            c[kk][j * 4 + 0] = v.x; c[kk][j * 4 + 1] = v.y;
            c[kk][j * 4 + 2] = v.z; c[kk][j * 4 + 3] = v.w;
            ss = fmaf(v.x, v.x, ss); ss = fmaf(v.y, v.y, ss);
            ss = fmaf(v.z, v.z, ss); ss = fmaf(v.w, v.w, ss);
        }
        bias[kk] = 0.5f * ss;
    }

    for (int rr = 0; rr < 64; rr += 2) {
        const int row = row0 + rr;
        const float* sp0 = sub32 + (size_t)row * EMB + m * DSUB;  // wave-uniform addr
        const float* sp1 = sp0 + EMB;
        float s0[DSUB], s1[DSUB];
#pragma unroll
        for (int j = 0; j < 6; ++j) {
            const float4 v0 = *(const float4*)(sp0 + j * 4);
            const float4 v1 = *(const float4*)(sp1 + j * 4);
            s0[j * 4 + 0] = v0.x; s0[j * 4 + 1] = v0.y;
            s0[j * 4 + 2] = v0.z; s0[j * 4 + 3] = v0.w;
            s1[j * 4 + 0] = v1.x; s1[j * 4 + 1] = v1.y;
            s1[j * 4 + 2] = v1.z; s1[j * 4 + 3] = v1.w;
        }
        unsigned best0 = 0xFFFFFFFFu, best1 = 0xFFFFFFFFu;
#pragma unroll
        for (int kk = 0; kk < 4; ++kk) {
            float ip0 = 0.f, ip1 = 0.f;
#pragma unroll
            for (int j = 0; j < DSUB; ++j) {
                ip0 = fmaf(c[kk][j], s0[j], ip0);
                ip1 = fmaf(c[kk][j], s1[j], ip1);
            }
            const float d0 = bias[kk] - ip0;
            const float d1 = bias[kk] - ip1;
            unsigned u0 = __float_as_uint(d0);
            unsigned u1 = __float_as_uint(d1);
            u0 ^= (unsigned)((int)u0 >> 31) | 0x80000000u;
            u1 ^= (unsigned)((int)u1 >> 31) | 0x80000000u;
            const unsigned kid = (unsigned)(kk * 64 + lane);
            best0 = min(best0, (u0 & 0xFFFFFF00u) | kid);
            best1 = min(best1, (u1 & 0xFFFFFF00u) | kid);
        }
#pragma unroll
        for (int off = 32; off >= 1; off >>= 1) {
            best0 = min(best0, (unsigned)__shfl_xor((int)best0, off));
            best1 = min(best1, (unsigned)__shfl_xor((int)best1, off));
        }
        if (lane == 0) {
            codes[(size_t)row * MSUB + m] = (unsigned char)(best0 & 0xFFu);
            codes[(size_t)(row + 1) * MSUB + m] = (unsigned char)(best1 & 0xFFu);
        }
    }
}

// ============ PQ reconstruct: out_bf16 = cb[m][k] + center ============
__global__ __launch_bounds__(256) void pq_recon_kernel(
    const unsigned char* __restrict__ codes, const float* __restrict__ cb,
    const unsigned short* __restrict__ ccb, unsigned short* __restrict__ outb)
{
    const int idx = blockIdx.x * 256 + threadIdx.x;  // n*32+m
    const int n = idx >> 5, m = idx & 31;
    const int k = codes[idx];
    const float* cp = cb + ((size_t)m * KCODE + k) * DSUB;
    const unsigned short* ccp = ccb + (size_t)n * EMB + m * DSUB;
    unsigned short* op = outb + (size_t)n * EMB + m * DSUB;
#pragma unroll
    for (int j = 0; j < 6; ++j) {
        const float4 a = *(const float4*)(cp + j * 4);
        const ushort4 cc = ((const ushort4*)ccp)[j];
        ushort4 o;
        o.x = f2bf(a.x + bf2f(cc.x)); o.y = f2bf(a.y + bf2f(cc.y));
        o.z = f2bf(a.z + bf2f(cc.z)); o.w = f2bf(a.w + bf2f(cc.w));
        ((ushort4*)op)[j] = o;
    }
}

// ============ softmax helpers ============
__device__ __forceinline__ void ms_combine(float& m, float& s, float m2, float s2)
{
    const float M = fmaxf(m, m2);
    s = s * expf(m - M) + s2 * expf(m2 - M);
    m = M;
}

__global__ __launch_bounds__(256) void tstats_kernel(const float* __restrict__ T,
                                                     float* __restrict__ tst)
{
    __shared__ float redm[256], reds[256];
    const int i = blockIdx.x, t = threadIdx.x;
    const float4* t4 = (const float4*)(T + (size_t)i * NCOLS);
    float m = -3.4e38f, s = 0.f;
    for (int c = t; c < NCOLS / 4; c += 256) {
        const float4 v = t4[c];
        const float mx = fmaxf(fmaxf(v.x, v.y), fmaxf(v.z, v.w));
        const float M = fmaxf(m, mx);
        s = s * expf(m - M) + expf(v.x - M) + expf(v.y - M) + expf(v.z - M) + expf(v.w - M);
        m = M;
    }
    redm[t] = m; reds[t] = s;
    __syncthreads();
#pragma unroll
    for (int st = 128; st > 0; st >>= 1) {
        if (t < st) {
            float mm = redm[t], ss = reds[t];
            ms_combine(mm, ss, redm[t + st], reds[t + st]);
            redm[t] = mm; reds[t] = ss;
        }
        __syncthreads();
    }
    if (t == 0) { tst[i * 2] = redm[0]; tst[i * 2 + 1] = reds[0]; }
}

__device__ __forceinline__ void loss_body(
    const float* __restrict__ T, const float* __restrict__ S,
    const float* __restrict__ tst, float* __restrict__ o, float scale,
    int i, int t, float* redm, float* reds)
{
    const float4* s4 = (const float4*)(S + (size_t)i * NCOLS);
    const float4* t4 = (const float4*)(T + (size_t)i * NCOLS);

    float m = -3.4e38f, s = 0.f;
    for (int c = t; c < NCOLS / 4; c += 256) {
        const float4 v = s4[c];
        const float mx = fmaxf(fmaxf(v.x, v.y), fmaxf(v.z, v.w));
        const float M = fmaxf(m, mx);
        s = s * expf(m - M) + expf(v.x - M) + expf(v.y - M) + expf(v.z - M) + expf(v.w - M);
        m = M;
    }
    redm[t] = m; reds[t] = s;
    __syncthreads();
#pragma unroll
    for (int st = 128; st > 0; st >>= 1) {
        if (t < st) {
            float mm = redm[t], ss = reds[t];
            ms_combine(mm, ss, redm[t + st], reds[t + st]);
            redm[t] = mm; reds[t] = ss;
        }
        __syncthreads();
    }
    const float smax = redm[0];
    const float inv_ssum = 1.f / reds[0];
    __syncthreads();
    const float tmax = tst[i * 2];
    const float inv_tsum = 1.f / tst[i * 2 + 1];

    float loss = 0.f;
    for (int c = t; c < NCOLS / 4; c += 256) {
        const float4 sv = s4[c];
        const float4 tv = t4[c];
        loss -= expf(tv.x - tmax) * inv_tsum * logf(expf(sv.x - smax) * inv_ssum + 1e-6f);
        loss -= expf(tv.y - tmax) * inv_tsum * logf(expf(sv.y - smax) * inv_ssum + 1e-6f);
        loss -= expf(tv.z - tmax) * inv_tsum * logf(expf(sv.z - smax) * inv_ssum + 1e-6f);
        loss -= expf(tv.w - tmax) * inv_tsum * logf(expf(sv.w - smax) * inv_ssum + 1e-6f);
    }
    redm[t] = loss;
    __syncthreads();
#pragma unroll
    for (int st = 128; st > 0; st >>= 1) {
        if (t < st) redm[t] += redm[t + st];
        __syncthreads();
    }
    if (t == 0) atomicAdd(o, redm[0] * scale);
}

__global__ __launch_bounds__(256) void loss_kernel(
    const float* __restrict__ T, const float* __restrict__ S,
    const float* __restrict__ tst, float* __restrict__ out, float scale)
{
    __shared__ float redm[256], reds[256];
    loss_body(T, S, tst, out, scale, blockIdx.x, threadIdx.x, redm, reds);
}

__global__ __launch_bounds__(256) void loss2_kernel(
    const float* __restrict__ T, const float* __restrict__ S0,
    const float* __restrict__ S1, const float* __restrict__ tst,
    float* __restrict__ out, float scale)
{
    __shared__ float redm[256], reds[256];
    const float* S = blockIdx.y ? S1 : S0;
    loss_body(T, S, tst, out + 1 + blockIdx.y, scale, blockIdx.x, threadIdx.x, redm, reds);
}

__global__ void zero_out_kernel(float* __restrict__ out, int n)
{
    if ((int)threadIdx.x < n) out[threadIdx.x] = 0.f;
}

// ============ launch ============
extern "C" void kernel_launch(void* const* d_in, const int* in_sizes, int n_in,
                              void* d_out, int out_size, void* d_ws, size_t ws_size,
                              hipStream_t stream)
{
    const float* q    = (const float*)d_in[0];
    const float* dpos = (const float*)d_in[1];
    const float* nneg = (const float*)d_in[2];
    const float* rot  = (const float*)d_in[3];
    const float* cb   = (const float*)d_in[4];
    const float* ivf  = (const float*)d_in[5];
    const int* doc_ids = (const int*)d_in[6];
    const int* neg_ids = (const int*)d_in[7];
    float* out = (float*)d_out;

    // ---- workspace (256B-aligned), ~98 MB ----
    char* p = (char*)d_ws;
    auto take = [&](size_t bytes) { char* r = p; p += (bytes + 255) & ~(size_t)255; return r; };
    unsigned short* qdnb  = (unsigned short*)take((size_t)(NQ + NTOT) * EMB * 2);
    unsigned short* rqdnb = (unsigned short*)take((size_t)(NQ + NTOT) * EMB * 2);
    unsigned short* rotb  = (unsigned short*)take((size_t)EMB * EMB * 2);
    unsigned short* ccb   = (unsigned short*)take((size_t)NTOT * EMB * 2);
    unsigned short* pqb   = (unsigned short*)take((size_t)NTOT * EMB * 2);
    float*          T     = (float*)take((size_t)NQ * NCOLS * 4);
    float*          S0    = (float*)take((size_t)NQ * NCOLS * 4);
    float*          S1    = (float*)take((size_t)NQ * NCOLS * 4);  // also sub32 (dead by then)
    unsigned char*  codes = (unsigned char*)take((size_t)NTOT * MSUB);
    float*          tst   = (float*)take((size_t)NQ * 2 * 4);

    float* sub32 = S1;   // alias: sub32 consumed by pq_argmin before S1 is written
    unsigned short* qb   = qdnb;
    unsigned short* dnb  = qdnb + (size_t)NQ * EMB;
    unsigned short* rqb  = rqdnb;
    unsigned short* rdnb = rqdnb + (size_t)NQ * EMB;

    const float scale = 1.f / NQ;
    zero_out_kernel<<<1, 64, 0, stream>>>(out, out_size);

    // 1) fp32 -> bf16
    const int cvt4 = (NQ * EMB + NQ * EMB + 4096 * EMB + EMB * EMB) / 4;
    cvt_all_kernel<<<(cvt4 + 255) / 256, 256, 0, stream>>>(q, dpos, nneg, rot, qdnb, rotb);

    // 2) IVF gather -> ccb
    gather_kernel<<<NTOT, EMB / 4, 0, stream>>>(ivf, doc_ids, neg_ids, ccb);

    // 3) rotation: [q;d;n] @ rot^T -> rqdnb bf16; rows >= NQ also sub32 = acc - center
    gemm_rot<<<dim3(EMB / BNR, (NQ + NTOT) / BMR), 256, 0, stream>>>(
        qdnb, rotb, sub32, rqdnb, ccb, EMB, EMB, EMB, EMB, EMB, NQ);

    // 4) PQ argmin + reconstruct -> pqb
    pq_argmin_kernel<<<dim3(NTOT / 256, MSUB), 256, 0, stream>>>(sub32, cb, codes);
    pq_recon_kernel<<<(NTOT * MSUB) / 256, 256, 0, stream>>>(codes, cb, ccb, pqb);

    // 5) batched GEMM: z0 teacher = qb@dnb^T -> T; z1 dense = rqb@rdnb^T -> S0
    gemm_score<<<dim3(NTOT / BNS, NQ / BMS, 2), 256, 0, stream>>>(
        qb, dnb, T, rqb, rdnb, S0);

    // 6) teacher stats + dense loss
    tstats_kernel<<<NQ, 256, 0, stream>>>(T, tst);
    loss_kernel<<<NQ, 256, 0, stream>>>(T, S0, tst, out + 0, scale);

    // 7) batched GEMM: z0 ivf = rqb@ccb^T -> S0; z1 pq = rqb@pqb^T -> S1
    gemm_score<<<dim3(NTOT / BNS, NQ / BMS, 2), 256, 0, stream>>>(
        rqb, ccb, S0, rqb, pqb, S1);

    // 8) ivf + pq losses
    loss2_kernel<<<dim3(NQ, 2), 256, 0, stream>>>(T, S0, S1, tst, out, scale);
}

// Round 5
// 297.590 us; speedup vs baseline: 3.3739x; 1.0023x over previous
//
#include <hip/hip_runtime.h>
#include <math.h>

#define EMB 768
#define MSUB 32
#define KCODE 256
#define DSUB 24
#define NQ 1024
#define NTOT 5120    // 1024 docs + 4096 negs
#define NCOLS 5120

typedef __attribute__((ext_vector_type(8))) short short8;
typedef __attribute__((ext_vector_type(4))) float floatx4;

__device__ __forceinline__ unsigned short f2bf(float f) {
    unsigned int u = __float_as_uint(f);
    unsigned int r = (u + 0x7FFFu + ((u >> 16) & 1u)) >> 16;   // RNE
    return (unsigned short)r;
}
__device__ __forceinline__ float bf2f(unsigned short h) {
    return __uint_as_float((unsigned int)h << 16);
}

__device__ __forceinline__ void gload16(const void* g, void* l) {
    __builtin_amdgcn_global_load_lds(
        (const __attribute__((address_space(1))) void*)g,
        (__attribute__((address_space(3))) void*)l, 16, 0, 0);
}

// ============ rotation GEMM: BM=64 x BN=128, bf16 out + residual fp32 out ============
// C[i,j] = sum_k A[i,k]*B[j,k].  Cb=bf16(acc); for rr>=row_off: Cf = acc - bf16dec(subC).
#define BMR 64
#define BNR 128
#define BKG 32
__global__ __launch_bounds__(256) void gemm_rot(
    const unsigned short* __restrict__ A, const unsigned short* __restrict__ B,
    float* __restrict__ Cf, unsigned short* __restrict__ Cb,
    const unsigned short* __restrict__ subC,
    int K, int lda, int ldb, int ldcf, int ldcb, int row_off)
{
    __shared__ __align__(16) unsigned short As[BMR * BKG];   // 4 KB
    __shared__ __align__(16) unsigned short Bs[BNR * BKG];   // 8 KB
    const int tid  = threadIdx.x;
    const int wave = tid >> 6;
    const int lane = tid & 63;
    const int wr = wave >> 1, wc = wave & 1;
    const int row0 = blockIdx.y * BMR;
    const int col0 = blockIdx.x * BNR;

    const int ar  = tid >> 2, aks  = (tid & 3) ^ ((ar >> 1) & 3);
    const unsigned short* Ap = A + (size_t)(row0 + ar) * lda + aks * 8;
    unsigned short* Al = &As[tid * 8];
    const int br0 = tid >> 2,        bks0 = (tid & 3) ^ ((br0 >> 1) & 3);
    const int br1 = 64 + (tid >> 2), bks1 = (tid & 3) ^ ((br1 >> 1) & 3);
    const unsigned short* Bp0 = B + (size_t)(col0 + br0) * ldb + bks0 * 8;
    const unsigned short* Bp1 = B + (size_t)(col0 + br1) * ldb + bks1 * 8;
    unsigned short* Bl0 = &Bs[tid * 8];
    unsigned short* Bl1 = &Bs[(tid + 256) * 8];

    const int frow = lane & 15;
    const int kblk = lane >> 4;
    int aoff[2], boff[4];
#pragma unroll
    for (int m = 0; m < 2; ++m) {
        const int r = wr * 32 + m * 16 + frow;
        aoff[m] = (r * 4 + (kblk ^ ((r >> 1) & 3))) * 8;
    }
#pragma unroll
    for (int n = 0; n < 4; ++n) {
        const int c = wc * 64 + n * 16 + frow;
        boff[n] = (c * 4 + (kblk ^ ((c >> 1) & 3))) * 8;
    }

    floatx4 acc[2][4];
#pragma unroll
    for (int m = 0; m < 2; ++m)
#pragma unroll
        for (int n = 0; n < 4; ++n)
            acc[m][n] = (floatx4){0.f, 0.f, 0.f, 0.f};

    for (int k0 = 0; k0 < K; k0 += BKG) {
        gload16(Ap + k0, Al);
        gload16(Bp0 + k0, Bl0);
        gload16(Bp1 + k0, Bl1);
        __syncthreads();
        short8 af[2], bf[4];
#pragma unroll
        for (int m = 0; m < 2; ++m) af[m] = *(const short8*)&As[aoff[m]];
#pragma unroll
        for (int n = 0; n < 4; ++n) bf[n] = *(const short8*)&Bs[boff[n]];
#pragma unroll
        for (int m = 0; m < 2; ++m)
#pragma unroll
            for (int n = 0; n < 4; ++n)
                acc[m][n] = __builtin_amdgcn_mfma_f32_16x16x32_bf16(
                    af[m], bf[n], acc[m][n], 0, 0, 0);
        __syncthreads();
    }

    const int crow = row0 + wr * 32 + (lane >> 4) * 4;
    const int ccol = col0 + wc * 64 + (lane & 15);
#pragma unroll
    for (int m = 0; m < 2; ++m)
#pragma unroll
        for (int n = 0; n < 4; ++n)
#pragma unroll
            for (int r = 0; r < 4; ++r) {
                const int rr = crow + m * 16 + r;
                const int cc = ccol + n * 16;
                const float v = acc[m][n][r];
                Cb[(size_t)rr * ldcb + cc] = f2bf(v);
                if (rr >= row_off) {
                    const size_t idx = (size_t)(rr - row_off) * ldcf + cc;
                    Cf[idx] = v - bf2f(subC[idx]);
                }
            }
}

// ============ batched score GEMM: BM=128 x BN=128, fp32 out, z selects A/B/C ========
#define BMS 128
#define BNS 128
__global__ __launch_bounds__(256) void gemm_score(
    const unsigned short* __restrict__ A0, const unsigned short* __restrict__ B0,
    float* __restrict__ C0,
    const unsigned short* __restrict__ A1, const unsigned short* __restrict__ B1,
    float* __restrict__ C1)
{
    const unsigned short* A = blockIdx.z ? A1 : A0;
    const unsigned short* B = blockIdx.z ? B1 : B0;
    float* C = blockIdx.z ? C1 : C0;

    __shared__ __align__(16) unsigned short As[BMS * BKG];   // 8 KB
    __shared__ __align__(16) unsigned short Bs[BNS * BKG];   // 8 KB
    const int tid  = threadIdx.x;
    const int wave = tid >> 6;
    const int lane = tid & 63;
    const int wr = wave >> 1, wc = wave & 1;
    const int row0 = blockIdx.y * BMS;
    const int col0 = blockIdx.x * BNS;

    const int g0 = tid, g1 = tid + 256;
    const int ar0 = g0 >> 2, as0 = (g0 & 3) ^ ((ar0 >> 1) & 3);
    const int ar1 = g1 >> 2, as1 = (g1 & 3) ^ ((ar1 >> 1) & 3);
    const unsigned short* Ap0 = A + (size_t)(row0 + ar0) * EMB + as0 * 8;
    const unsigned short* Ap1 = A + (size_t)(row0 + ar1) * EMB + as1 * 8;
    const unsigned short* Bp0 = B + (size_t)(col0 + ar0) * EMB + as0 * 8;
    const unsigned short* Bp1 = B + (size_t)(col0 + ar1) * EMB + as1 * 8;
    unsigned short* Al0 = &As[g0 * 8];
    unsigned short* Al1 = &As[g1 * 8];
    unsigned short* Bl0 = &Bs[g0 * 8];
    unsigned short* Bl1 = &Bs[g1 * 8];

    const int frow = lane & 15;
    const int kblk = lane >> 4;
    int aoff[4], boff[4];
#pragma unroll
    for (int m = 0; m < 4; ++m) {
        const int r = wr * 64 + m * 16 + frow;
        aoff[m] = (r * 4 + (kblk ^ ((r >> 1) & 3))) * 8;
        const int c = wc * 64 + m * 16 + frow;
        boff[m] = (c * 4 + (kblk ^ ((c >> 1) & 3))) * 8;
    }

    floatx4 acc[4][4];
#pragma unroll
    for (int m = 0; m < 4; ++m)
#pragma unroll
        for (int n = 0; n < 4; ++n)
            acc[m][n] = (floatx4){0.f, 0.f, 0.f, 0.f};

    for (int k0 = 0; k0 < EMB; k0 += BKG) {
        gload16(Ap0 + k0, Al0);
        gload16(Ap1 + k0, Al1);
        gload16(Bp0 + k0, Bl0);
        gload16(Bp1 + k0, Bl1);
        __syncthreads();
        short8 af[4], bf[4];
#pragma unroll
        for (int m = 0; m < 4; ++m) af[m] = *(const short8*)&As[aoff[m]];
#pragma unroll
        for (int n = 0; n < 4; ++n) bf[n] = *(const short8*)&Bs[boff[n]];
#pragma unroll
        for (int m = 0; m < 4; ++m)
#pragma unroll
            for (int n = 0; n < 4; ++n)
                acc[m][n] = __builtin_amdgcn_mfma_f32_16x16x32_bf16(
                    af[m], bf[n], acc[m][n], 0, 0, 0);
        __syncthreads();
    }

    const int crow = row0 + wr * 64 + (lane >> 4) * 4;
    const int ccol = col0 + wc * 64 + (lane & 15);
#pragma unroll
    for (int m = 0; m < 4; ++m)
#pragma unroll
        for (int n = 0; n < 4; ++n)
#pragma unroll
            for (int r = 0; r < 4; ++r)
                C[(size_t)(crow + m * 16 + r) * NCOLS + ccol + n * 16] = acc[m][n][r];
}

// ============ fused fp32 -> bf16 conversion ============
__global__ __launch_bounds__(256) void cvt_all_kernel(
    const float* __restrict__ q, const float* __restrict__ d,
    const float* __restrict__ n, const float* __restrict__ rot,
    unsigned short* __restrict__ qdnb, unsigned short* __restrict__ rotb)
{
    const int i = blockIdx.x * 256 + threadIdx.x;  // float4 index
    const int S1 = NQ * EMB / 4;
    const int S2 = S1 + NQ * EMB / 4;
    const int S3 = S2 + 4096 * EMB / 4;
    const int S4 = S3 + EMB * EMB / 4;
    const float* src; unsigned short* dst; int off;
    if (i < S1)      { src = q;   dst = qdnb;                          off = i; }
    else if (i < S2) { src = d;   dst = qdnb + (size_t)NQ * EMB;       off = i - S1; }
    else if (i < S3) { src = n;   dst = qdnb + (size_t)2 * NQ * EMB;   off = i - S2; }
    else if (i < S4) { src = rot; dst = rotb;                          off = i - S3; }
    else return;
    const float4 v = ((const float4*)src)[off];
    ushort4 b;
    b.x = f2bf(v.x); b.y = f2bf(v.y); b.z = f2bf(v.z); b.w = f2bf(v.w);
    ((ushort4*)dst)[off] = b;
}

// ============ IVF gather (bf16) ============
__global__ void gather_kernel(const float* __restrict__ centers,
                              const int* __restrict__ doc_ids,
                              const int* __restrict__ neg_ids,
                              unsigned short* __restrict__ outb)
{
    const int i = blockIdx.x;
    const int id = (i < NQ) ? doc_ids[i] : neg_ids[i - NQ];
    const int t = threadIdx.x;
    const float4 v = ((const float4*)(centers + (size_t)id * EMB))[t];
    ushort4 b;
    b.x = f2bf(v.x); b.y = f2bf(v.y); b.z = f2bf(v.z); b.w = f2bf(v.w);
    ((ushort4*)(outb + (size_t)i * EMB))[t] = b;
}

// ============ PQ argmin: 4 codewords/lane PINNED in registers, 2 rows per iter ======
// argmin_k ||sub - c_k||^2 == argmin_k (0.5*||c_k||^2 - <sub, c_k>)
__global__ __launch_bounds__(256, 1) void pq_argmin_kernel(
    const float* __restrict__ sub32, const float* __restrict__ cb,
    unsigned char* __restrict__ codes)
{
    const int m = blockIdx.y;
    const int wave = threadIdx.x >> 6, lane = threadIdx.x & 63;
    const int row0 = (blockIdx.x * 4 + wave) * 64;

    float c[4][DSUB];
    float bias[4];
#pragma unroll
    for (int kk = 0; kk < 4; ++kk) {
        const float* cp = cb + ((size_t)m * KCODE + kk * 64 + lane) * DSUB;
        float ss = 0.f;
#pragma unroll
        for (int j = 0; j < 6; ++j) {
            const float4 v = *(const float4*)(cp + j * 4);
            c[kk][j * 4 + 0] = v.x; c[kk][j * 4 + 1] = v.y;
            c[kk][j * 4 + 2] = v.z; c[kk][j * 4 + 3] = v.w;
            ss = fmaf(v.x, v.x, ss); ss = fmaf(v.y, v.y, ss);
            ss = fmaf(v.z, v.z, ss); ss = fmaf(v.w, v.w, ss);
        }
        bias[kk] = 0.5f * ss;
    }
    // Pin codewords + bias into VGPRs: the empty asm is opaque, so the register
    // allocator cannot rematerialize the global loads inside the row loop.
    // (Round-3/4 evidence: without this, VGPR_Count=64-68 -> codebook reloaded
    // per row, kernel latency-bound at 89-110us.)
#pragma unroll
    for (int kk = 0; kk < 4; ++kk) {
#pragma unroll
        for (int j = 0; j < DSUB; ++j) asm volatile("" : "+v"(c[kk][j]));
        asm volatile("" : "+v"(bias[kk]));
    }

    for (int rr = 0; rr < 64; rr += 2) {
        const int row = row0 + rr;
        const float* sp0 = sub32 + (size_t)row * EMB + m * DSUB;  // wave-uniform addr
        const float* sp1 = sp0 + EMB;
        float s0[DSUB], s1[DSUB];
#pragma unroll
        for (int j = 0; j < 6; ++j) {
            const float4 v0 = *(const float4*)(sp0 + j * 4);
            const float4 v1 = *(const float4*)(sp1 + j * 4);
            s0[j * 4 + 0] = v0.x; s0[j * 4 + 1] = v0.y;
            s0[j * 4 + 2] = v0.z; s0[j * 4 + 3] = v0.w;
            s1[j * 4 + 0] = v1.x; s1[j * 4 + 1] = v1.y;
            s1[j * 4 + 2] = v1.z; s1[j * 4 + 3] = v1.w;
        }
        unsigned best0 = 0xFFFFFFFFu, best1 = 0xFFFFFFFFu;
#pragma unroll
        for (int kk = 0; kk < 4; ++kk) {
            float ip0 = 0.f, ip1 = 0.f;
#pragma unroll
            for (int j = 0; j < DSUB; ++j) {
                ip0 = fmaf(c[kk][j], s0[j], ip0);
                ip1 = fmaf(c[kk][j], s1[j], ip1);
            }
            const float d0 = bias[kk] - ip0;
            const float d1 = bias[kk] - ip1;
            unsigned u0 = __float_as_uint(d0);
            unsigned u1 = __float_as_uint(d1);
            u0 ^= (unsigned)((int)u0 >> 31) | 0x80000000u;
            u1 ^= (unsigned)((int)u1 >> 31) | 0x80000000u;
            const unsigned kid = (unsigned)(kk * 64 + lane);
            best0 = min(best0, (u0 & 0xFFFFFF00u) | kid);
            best1 = min(best1, (u1 & 0xFFFFFF00u) | kid);
        }
#pragma unroll
        for (int off = 32; off >= 1; off >>= 1) {
            best0 = min(best0, (unsigned)__shfl_xor((int)best0, off));
            best1 = min(best1, (unsigned)__shfl_xor((int)best1, off));
        }
        if (lane == 0) {
            codes[(size_t)row * MSUB + m] = (unsigned char)(best0 & 0xFFu);
            codes[(size_t)(row + 1) * MSUB + m] = (unsigned char)(best1 & 0xFFu);
        }
    }
}

// ============ PQ reconstruct: out_bf16 = cb[m][k] + center ============
__global__ __launch_bounds__(256) void pq_recon_kernel(
    const unsigned char* __restrict__ codes, const float* __restrict__ cb,
    const unsigned short* __restrict__ ccb, unsigned short* __restrict__ outb)
{
    const int idx = blockIdx.x * 256 + threadIdx.x;  // n*32+m
    const int n = idx >> 5, m = idx & 31;
    const int k = codes[idx];
    const float* cp = cb + ((size_t)m * KCODE + k) * DSUB;
    const unsigned short* ccp = ccb + (size_t)n * EMB + m * DSUB;
    unsigned short* op = outb + (size_t)n * EMB + m * DSUB;
#pragma unroll
    for (int j = 0; j < 6; ++j) {
        const float4 a = *(const float4*)(cp + j * 4);
        const ushort4 cc = ((const ushort4*)ccp)[j];
        ushort4 o;
        o.x = f2bf(a.x + bf2f(cc.x)); o.y = f2bf(a.y + bf2f(cc.y));
        o.z = f2bf(a.z + bf2f(cc.z)); o.w = f2bf(a.w + bf2f(cc.w));
        ((ushort4*)op)[j] = o;
    }
}

// ============ softmax helpers ============
__device__ __forceinline__ void ms_combine(float& m, float& s, float m2, float s2)
{
    const float M = fmaxf(m, m2);
    s = s * expf(m - M) + s2 * expf(m2 - M);
    m = M;
}

__global__ __launch_bounds__(256) void tstats_kernel(const float* __restrict__ T,
                                                     float* __restrict__ tst)
{
    __shared__ float redm[256], reds[256];
    const int i = blockIdx.x, t = threadIdx.x;
    const float4* t4 = (const float4*)(T + (size_t)i * NCOLS);
    float m = -3.4e38f, s = 0.f;
    for (int c = t; c < NCOLS / 4; c += 256) {
        const float4 v = t4[c];
        const float mx = fmaxf(fmaxf(v.x, v.y), fmaxf(v.z, v.w));
        const float M = fmaxf(m, mx);
        s = s * expf(m - M) + expf(v.x - M) + expf(v.y - M) + expf(v.z - M) + expf(v.w - M);
        m = M;
    }
    redm[t] = m; reds[t] = s;
    __syncthreads();
#pragma unroll
    for (int st = 128; st > 0; st >>= 1) {
        if (t < st) {
            float mm = redm[t], ss = reds[t];
            ms_combine(mm, ss, redm[t + st], reds[t + st]);
            redm[t] = mm; reds[t] = ss;
        }
        __syncthreads();
    }
    if (t == 0) { tst[i * 2] = redm[0]; tst[i * 2 + 1] = reds[0]; }
}

__device__ __forceinline__ void loss_body(
    const float* __restrict__ T, const float* __restrict__ S,
    const float* __restrict__ tst, float* __restrict__ o, float scale,
    int i, int t, float* redm, float* reds)
{
    const float4* s4 = (const float4*)(S + (size_t)i * NCOLS);
    const float4* t4 = (const float4*)(T + (size_t)i * NCOLS);

    float m = -3.4e38f, s = 0.f;
    for (int c = t; c < NCOLS / 4; c += 256) {
        const float4 v = s4[c];
        const float mx = fmaxf(fmaxf(v.x, v.y), fmaxf(v.z, v.w));
        const float M = fmaxf(m, mx);
        s = s * expf(m - M) + expf(v.x - M) + expf(v.y - M) + expf(v.z - M) + expf(v.w - M);
        m = M;
    }
    redm[t] = m; reds[t] = s;
    __syncthreads();
#pragma unroll
    for (int st = 128; st > 0; st >>= 1) {
        if (t < st) {
            float mm = redm[t], ss = reds[t];
            ms_combine(mm, ss, redm[t + st], reds[t + st]);
            redm[t] = mm; reds[t] = ss;
        }
        __syncthreads();
    }
    const float smax = redm[0];
    const float inv_ssum = 1.f / reds[0];
    __syncthreads();
    const float tmax = tst[i * 2];
    const float inv_tsum = 1.f / tst[i * 2 + 1];

    float loss = 0.f;
    for (int c = t; c < NCOLS / 4; c += 256) {
        const float4 sv = s4[c];
        const float4 tv = t4[c];
        loss -= expf(tv.x - tmax) * inv_tsum * logf(expf(sv.x - smax) * inv_ssum + 1e-6f);
        loss -= expf(tv.y - tmax) * inv_tsum * logf(expf(sv.y - smax) * inv_ssum + 1e-6f);
        loss -= expf(tv.z - tmax) * inv_tsum * logf(expf(sv.z - smax) * inv_ssum + 1e-6f);
        loss -= expf(tv.w - tmax) * inv_tsum * logf(expf(sv.w - smax) * inv_ssum + 1e-6f);
    }
    redm[t] = loss;
    __syncthreads();
#pragma unroll
    for (int st = 128; st > 0; st >>= 1) {
        if (t < st) redm[t] += redm[t + st];
        __syncthreads();
    }
    if (t == 0) atomicAdd(o, redm[0] * scale);
}

__global__ __launch_bounds__(256) void loss_kernel(
    const float* __restrict__ T, const float* __restrict__ S,
    const float* __restrict__ tst, float* __restrict__ out, float scale)
{
    __shared__ float redm[256], reds[256];
    loss_body(T, S, tst, out, scale, blockIdx.x, threadIdx.x, redm, reds);
}

__global__ __launch_bounds__(256) void loss2_kernel(
    const float* __restrict__ T, const float* __restrict__ S0,
    const float* __restrict__ S1, const float* __restrict__ tst,
    float* __restrict__ out, float scale)
{
    __shared__ float redm[256], reds[256];
    const float* S = blockIdx.y ? S1 : S0;
    loss_body(T, S, tst, out + 1 + blockIdx.y, scale, blockIdx.x, threadIdx.x, redm, reds);
}

__global__ void zero_out_kernel(float* __restrict__ out, int n)
{
    if ((int)threadIdx.x < n) out[threadIdx.x] = 0.f;
}

// ============ launch ============
extern "C" void kernel_launch(void* const* d_in, const int* in_sizes, int n_in,
                              void* d_out, int out_size, void* d_ws, size_t ws_size,
                              hipStream_t stream)
{
    const float* q    = (const float*)d_in[0];
    const float* dpos = (const float*)d_in[1];
    const float* nneg = (const float*)d_in[2];
    const float* rot  = (const float*)d_in[3];
    const float* cb   = (const float*)d_in[4];
    const float* ivf  = (const float*)d_in[5];
    const int* doc_ids = (const int*)d_in[6];
    const int* neg_ids = (const int*)d_in[7];
    float* out = (float*)d_out;

    // ---- workspace (256B-aligned), ~98 MB ----
    char* p = (char*)d_ws;
    auto take = [&](size_t bytes) { char* r = p; p += (bytes + 255) & ~(size_t)255; return r; };
    unsigned short* qdnb  = (unsigned short*)take((size_t)(NQ + NTOT) * EMB * 2);
    unsigned short* rqdnb = (unsigned short*)take((size_t)(NQ + NTOT) * EMB * 2);
    unsigned short* rotb  = (unsigned short*)take((size_t)EMB * EMB * 2);
    unsigned short* ccb   = (unsigned short*)take((size_t)NTOT * EMB * 2);
    unsigned short* pqb   = (unsigned short*)take((size_t)NTOT * EMB * 2);
    float*          T     = (float*)take((size_t)NQ * NCOLS * 4);
    float*          S0    = (float*)take((size_t)NQ * NCOLS * 4);
    float*          S1    = (float*)take((size_t)NQ * NCOLS * 4);  // also sub32 (dead by then)
    unsigned char*  codes = (unsigned char*)take((size_t)NTOT * MSUB);
    float*          tst   = (float*)take((size_t)NQ * 2 * 4);

    float* sub32 = S1;   // alias: sub32 consumed by pq_argmin before S1 is written
    unsigned short* qb   = qdnb;
    unsigned short* dnb  = qdnb + (size_t)NQ * EMB;
    unsigned short* rqb  = rqdnb;
    unsigned short* rdnb = rqdnb + (size_t)NQ * EMB;

    const float scale = 1.f / NQ;
    zero_out_kernel<<<1, 64, 0, stream>>>(out, out_size);

    // 1) fp32 -> bf16
    const int cvt4 = (NQ * EMB + NQ * EMB + 4096 * EMB + EMB * EMB) / 4;
    cvt_all_kernel<<<(cvt4 + 255) / 256, 256, 0, stream>>>(q, dpos, nneg, rot, qdnb, rotb);

    // 2) IVF gather -> ccb
    gather_kernel<<<NTOT, EMB / 4, 0, stream>>>(ivf, doc_ids, neg_ids, ccb);

    // 3) rotation: [q;d;n] @ rot^T -> rqdnb bf16; rows >= NQ also sub32 = acc - center
    gemm_rot<<<dim3(EMB / BNR, (NQ + NTOT) / BMR), 256, 0, stream>>>(
        qdnb, rotb, sub32, rqdnb, ccb, EMB, EMB, EMB, EMB, EMB, NQ);

    // 4) PQ argmin + reconstruct -> pqb
    pq_argmin_kernel<<<dim3(NTOT / 256, MSUB), 256, 0, stream>>>(sub32, cb, codes);
    pq_recon_kernel<<<(NTOT * MSUB) / 256, 256, 0, stream>>>(codes, cb, ccb, pqb);

    // 5) batched GEMM: z0 teacher = qb@dnb^T -> T; z1 dense = rqb@rdnb^T -> S0
    gemm_score<<<dim3(NTOT / BNS, NQ / BMS, 2), 256, 0, stream>>>(
        qb, dnb, T, rqb, rdnb, S0);

    // 6) teacher stats + dense loss
    tstats_kernel<<<NQ, 256, 0, stream>>>(T, tst);
    loss_kernel<<<NQ, 256, 0, stream>>>(T, S0, tst, out + 0, scale);

    // 7) batched GEMM: z0 ivf = rqb@ccb^T -> S0; z1 pq = rqb@pqb^T -> S1
    gemm_score<<<dim3(NTOT / BNS, NQ / BMS, 2), 256, 0, stream>>>(
        rqb, ccb, S0, rqb, pqb, S1);

    // 8) ivf + pq losses
    loss2_kernel<<<dim3(NQ, 2), 256, 0, stream>>>(T, S0, S1, tst, out, scale);
}

// Round 6
// 210.168 us; speedup vs baseline: 4.7772x; 1.4160x over previous
//
#include <hip/hip_runtime.h>
#include <math.h>

#define EMB 768
#define MSUB 32
#define KCODE 256
#define DSUB 24
#define NQ 1024
#define NTOT 5120    // 1024 docs + 4096 negs
#define NCOLS 5120
#define DPAD 32      // padded subvector dim for MFMA (K=32)

typedef __attribute__((ext_vector_type(8))) short short8;
typedef __attribute__((ext_vector_type(4))) float floatx4;

__device__ __forceinline__ unsigned short f2bf(float f) {
    unsigned int u = __float_as_uint(f);
    unsigned int r = (u + 0x7FFFu + ((u >> 16) & 1u)) >> 16;   // RNE
    return (unsigned short)r;
}
__device__ __forceinline__ float bf2f(unsigned short h) {
    return __uint_as_float((unsigned int)h << 16);
}

__device__ __forceinline__ void gload16(const void* g, void* l) {
    __builtin_amdgcn_global_load_lds(
        (const __attribute__((address_space(1))) void*)g,
        (__attribute__((address_space(3))) void*)l, 16, 0, 0);
}

// ============ rotation GEMM: BM=64 x BN=128; bf16 out + padded bf16 residual ========
// C[i,j] = sum_k A[i,k]*B[j,k].  Cb = bf16(acc).
// For rr >= NQ: subp[(rr-NQ)][ (cc/24)*32 + cc%24 ] = bf16(acc - bf16dec(ccb[rr-NQ][cc])).
#define BMR 64
#define BNR 128
#define BKG 32
__global__ __launch_bounds__(256) void gemm_rot(
    const unsigned short* __restrict__ A, const unsigned short* __restrict__ B,
    unsigned short* __restrict__ Cb, const unsigned short* __restrict__ ccb,
    unsigned short* __restrict__ subp, int K, int lda, int ldb, int ldcb)
{
    __shared__ __align__(16) unsigned short As[BMR * BKG];   // 4 KB
    __shared__ __align__(16) unsigned short Bs[BNR * BKG];   // 8 KB
    const int tid  = threadIdx.x;
    const int wave = tid >> 6;
    const int lane = tid & 63;
    const int wr = wave >> 1, wc = wave & 1;
    const int row0 = blockIdx.y * BMR;
    const int col0 = blockIdx.x * BNR;

    const int ar  = tid >> 2, aks  = (tid & 3) ^ ((ar >> 1) & 3);
    const unsigned short* Ap = A + (size_t)(row0 + ar) * lda + aks * 8;
    unsigned short* Al = &As[tid * 8];
    const int br0 = tid >> 2,        bks0 = (tid & 3) ^ ((br0 >> 1) & 3);
    const int br1 = 64 + (tid >> 2), bks1 = (tid & 3) ^ ((br1 >> 1) & 3);
    const unsigned short* Bp0 = B + (size_t)(col0 + br0) * ldb + bks0 * 8;
    const unsigned short* Bp1 = B + (size_t)(col0 + br1) * ldb + bks1 * 8;
    unsigned short* Bl0 = &Bs[tid * 8];
    unsigned short* Bl1 = &Bs[(tid + 256) * 8];

    const int frow = lane & 15;
    const int kblk = lane >> 4;
    int aoff[2], boff[4];
#pragma unroll
    for (int m = 0; m < 2; ++m) {
        const int r = wr * 32 + m * 16 + frow;
        aoff[m] = (r * 4 + (kblk ^ ((r >> 1) & 3))) * 8;
    }
#pragma unroll
    for (int n = 0; n < 4; ++n) {
        const int c = wc * 64 + n * 16 + frow;
        boff[n] = (c * 4 + (kblk ^ ((c >> 1) & 3))) * 8;
    }

    floatx4 acc[2][4];
#pragma unroll
    for (int m = 0; m < 2; ++m)
#pragma unroll
        for (int n = 0; n < 4; ++n)
            acc[m][n] = (floatx4){0.f, 0.f, 0.f, 0.f};

    for (int k0 = 0; k0 < K; k0 += BKG) {
        gload16(Ap + k0, Al);
        gload16(Bp0 + k0, Bl0);
        gload16(Bp1 + k0, Bl1);
        __syncthreads();
        short8 af[2], bf[4];
#pragma unroll
        for (int m = 0; m < 2; ++m) af[m] = *(const short8*)&As[aoff[m]];
#pragma unroll
        for (int n = 0; n < 4; ++n) bf[n] = *(const short8*)&Bs[boff[n]];
#pragma unroll
        for (int m = 0; m < 2; ++m)
#pragma unroll
            for (int n = 0; n < 4; ++n)
                acc[m][n] = __builtin_amdgcn_mfma_f32_16x16x32_bf16(
                    af[m], bf[n], acc[m][n], 0, 0, 0);
        __syncthreads();
    }

    const int crow = row0 + wr * 32 + (lane >> 4) * 4;
    const int ccol = col0 + wc * 64 + (lane & 15);
#pragma unroll
    for (int m = 0; m < 2; ++m)
#pragma unroll
        for (int n = 0; n < 4; ++n)
#pragma unroll
            for (int r = 0; r < 4; ++r) {
                const int rr = crow + m * 16 + r;
                const int cc = ccol + n * 16;
                const float v = acc[m][n][r];
                Cb[(size_t)rr * ldcb + cc] = f2bf(v);
                if (rr >= NQ) {
                    const int nn = rr - NQ;
                    const float cen = bf2f(ccb[(size_t)nn * EMB + cc]);
                    const unsigned mm = (unsigned)cc / 24u;
                    const unsigned jj = (unsigned)cc - mm * 24u;
                    subp[(size_t)nn * (MSUB * DPAD) + mm * DPAD + jj] = f2bf(v - cen);
                }
            }
}

// ============ batched score GEMM: BM=128 x BN=128, fp32 out, z selects A/B/C ========
#define BMS 128
#define BNS 128
__global__ __launch_bounds__(256) void gemm_score(
    const unsigned short* __restrict__ A0, const unsigned short* __restrict__ B0,
    float* __restrict__ C0,
    const unsigned short* __restrict__ A1, const unsigned short* __restrict__ B1,
    float* __restrict__ C1)
{
    const unsigned short* A = blockIdx.z ? A1 : A0;
    const unsigned short* B = blockIdx.z ? B1 : B0;
    float* C = blockIdx.z ? C1 : C0;

    __shared__ __align__(16) unsigned short As[BMS * BKG];   // 8 KB
    __shared__ __align__(16) unsigned short Bs[BNS * BKG];   // 8 KB
    const int tid  = threadIdx.x;
    const int wave = tid >> 6;
    const int lane = tid & 63;
    const int wr = wave >> 1, wc = wave & 1;
    const int row0 = blockIdx.y * BMS;
    const int col0 = blockIdx.x * BNS;

    const int g0 = tid, g1 = tid + 256;
    const int ar0 = g0 >> 2, as0 = (g0 & 3) ^ ((ar0 >> 1) & 3);
    const int ar1 = g1 >> 2, as1 = (g1 & 3) ^ ((ar1 >> 1) & 3);
    const unsigned short* Ap0 = A + (size_t)(row0 + ar0) * EMB + as0 * 8;
    const unsigned short* Ap1 = A + (size_t)(row0 + ar1) * EMB + as1 * 8;
    const unsigned short* Bp0 = B + (size_t)(col0 + ar0) * EMB + as0 * 8;
    const unsigned short* Bp1 = B + (size_t)(col0 + ar1) * EMB + as1 * 8;
    unsigned short* Al0 = &As[g0 * 8];
    unsigned short* Al1 = &As[g1 * 8];
    unsigned short* Bl0 = &Bs[g0 * 8];
    unsigned short* Bl1 = &Bs[g1 * 8];

    const int frow = lane & 15;
    const int kblk = lane >> 4;
    int aoff[4], boff[4];
#pragma unroll
    for (int m = 0; m < 4; ++m) {
        const int r = wr * 64 + m * 16 + frow;
        aoff[m] = (r * 4 + (kblk ^ ((r >> 1) & 3))) * 8;
        const int c = wc * 64 + m * 16 + frow;
        boff[m] = (c * 4 + (kblk ^ ((c >> 1) & 3))) * 8;
    }

    floatx4 acc[4][4];
#pragma unroll
    for (int m = 0; m < 4; ++m)
#pragma unroll
        for (int n = 0; n < 4; ++n)
            acc[m][n] = (floatx4){0.f, 0.f, 0.f, 0.f};

    for (int k0 = 0; k0 < EMB; k0 += BKG) {
        gload16(Ap0 + k0, Al0);
        gload16(Ap1 + k0, Al1);
        gload16(Bp0 + k0, Bl0);
        gload16(Bp1 + k0, Bl1);
        __syncthreads();
        short8 af[4], bf[4];
#pragma unroll
        for (int m = 0; m < 4; ++m) af[m] = *(const short8*)&As[aoff[m]];
#pragma unroll
        for (int n = 0; n < 4; ++n) bf[n] = *(const short8*)&Bs[boff[n]];
#pragma unroll
        for (int m = 0; m < 4; ++m)
#pragma unroll
            for (int n = 0; n < 4; ++n)
                acc[m][n] = __builtin_amdgcn_mfma_f32_16x16x32_bf16(
                    af[m], bf[n], acc[m][n], 0, 0, 0);
        __syncthreads();
    }

    const int crow = row0 + wr * 64 + (lane >> 4) * 4;
    const int ccol = col0 + wc * 64 + (lane & 15);
#pragma unroll
    for (int m = 0; m < 4; ++m)
#pragma unroll
        for (int n = 0; n < 4; ++n)
#pragma unroll
            for (int r = 0; r < 4; ++r)
                C[(size_t)(crow + m * 16 + r) * NCOLS + ccol + n * 16] = acc[m][n][r];
}

// ============ fused fp32 -> bf16 conversion ============
__global__ __launch_bounds__(256) void cvt_all_kernel(
    const float* __restrict__ q, const float* __restrict__ d,
    const float* __restrict__ n, const float* __restrict__ rot,
    unsigned short* __restrict__ qdnb, unsigned short* __restrict__ rotb)
{
    const int i = blockIdx.x * 256 + threadIdx.x;  // float4 index
    const int S1 = NQ * EMB / 4;
    const int S2 = S1 + NQ * EMB / 4;
    const int S3 = S2 + 4096 * EMB / 4;
    const int S4 = S3 + EMB * EMB / 4;
    const float* src; unsigned short* dst; int off;
    if (i < S1)      { src = q;   dst = qdnb;                          off = i; }
    else if (i < S2) { src = d;   dst = qdnb + (size_t)NQ * EMB;       off = i - S1; }
    else if (i < S3) { src = n;   dst = qdnb + (size_t)2 * NQ * EMB;   off = i - S2; }
    else if (i < S4) { src = rot; dst = rotb;                          off = i - S3; }
    else return;
    const float4 v = ((const float4*)src)[off];
    ushort4 b;
    b.x = f2bf(v.x); b.y = f2bf(v.y); b.z = f2bf(v.z); b.w = f2bf(v.w);
    ((ushort4*)dst)[off] = b;
}

// ============ IVF gather (bf16) ============
__global__ void gather_kernel(const float* __restrict__ centers,
                              const int* __restrict__ doc_ids,
                              const int* __restrict__ neg_ids,
                              unsigned short* __restrict__ outb)
{
    const int i = blockIdx.x;
    const int id = (i < NQ) ? doc_ids[i] : neg_ids[i - NQ];
    const int t = threadIdx.x;
    const float4 v = ((const float4*)(centers + (size_t)id * EMB))[t];
    ushort4 b;
    b.x = f2bf(v.x); b.y = f2bf(v.y); b.z = f2bf(v.z); b.w = f2bf(v.w);
    ((ushort4*)(outb + (size_t)i * EMB))[t] = b;
}

// ============ zero helper (pad columns of subp) ============
__global__ __launch_bounds__(256) void zero16_kernel(uint4* __restrict__ p, int n)
{
    const int i = blockIdx.x * 256 + threadIdx.x;
    if (i < n) p[i] = make_uint4(0u, 0u, 0u, 0u);
}

// ============ codebook prep: padded bf16 + 0.5*||c||^2 bias ============
__global__ __launch_bounds__(256) void cbprep_kernel(
    const float* __restrict__ cb, unsigned short* __restrict__ cbb,
    float* __restrict__ bias)
{
    const int idx = blockIdx.x * 256 + threadIdx.x;  // m*256 + k  (8192 total)
    const float* cp = cb + (size_t)idx * DSUB;
    unsigned short o[DPAD];
    float ss = 0.f;
#pragma unroll
    for (int j = 0; j < 6; ++j) {
        const float4 v = *(const float4*)(cp + j * 4);
        o[j * 4 + 0] = f2bf(v.x); o[j * 4 + 1] = f2bf(v.y);
        o[j * 4 + 2] = f2bf(v.z); o[j * 4 + 3] = f2bf(v.w);
        ss = fmaf(v.x, v.x, ss); ss = fmaf(v.y, v.y, ss);
        ss = fmaf(v.z, v.z, ss); ss = fmaf(v.w, v.w, ss);
    }
#pragma unroll
    for (int j = DSUB; j < DPAD; ++j) o[j] = 0;
    unsigned short* op = cbb + (size_t)idx * DPAD;
#pragma unroll
    for (int j = 0; j < DPAD / 4; ++j)
        ((ushort4*)op)[j] = make_ushort4(o[j*4], o[j*4+1], o[j*4+2], o[j*4+3]);
    bias[idx] = 0.5f * ss;
}

// ============ PQ argmin via MFMA: block = 128 rows x 256 codewords x one m ==========
// dist(n,k) = 0.5||c_k||^2 - <sub_n, c_k>;  single 16x16x32 MFMA per tile (K=32).
__global__ __launch_bounds__(256) void pq_mfma_argmin(
    const unsigned short* __restrict__ subp,   // [NTOT][MSUB*DPAD]
    const unsigned short* __restrict__ cbb,    // [MSUB][KCODE][DPAD]
    const float* __restrict__ bias,            // [MSUB][KCODE]
    unsigned char* __restrict__ codes)         // [NTOT][MSUB]
{
    const int m = blockIdx.y;
    const int row0 = blockIdx.x * 128;
    __shared__ __align__(16) unsigned short As[128 * DPAD];   // 8 KB
    __shared__ __align__(16) unsigned short Bs[KCODE * DPAD]; // 16 KB
    __shared__ __align__(16) float bs[KCODE];                 // 1 KB
    const int tid = threadIdx.x;
    const int wave = tid >> 6, lane = tid & 63;

    // stage A (512 granules, 2/thread), XOR-swizzled source, linear LDS dest
    {
        const int g = tid;
        const int r = g >> 2, kc = (g & 3) ^ ((r >> 1) & 3);
        gload16(subp + (size_t)(row0 + r) * (MSUB * DPAD) + m * DPAD + kc * 8, &As[g * 8]);
    }
    {
        const int g = tid + 256;
        const int r = g >> 2, kc = (g & 3) ^ ((r >> 1) & 3);
        gload16(subp + (size_t)(row0 + r) * (MSUB * DPAD) + m * DPAD + kc * 8, &As[g * 8]);
    }
    // stage B (1024 granules, 4/thread)
#pragma unroll
    for (int i = 0; i < 4; ++i) {
        const int g = tid + i * 256;
        const int r = g >> 2, kc = (g & 3) ^ ((r >> 1) & 3);
        gload16(cbb + (size_t)m * (KCODE * DPAD) + r * DPAD + kc * 8, &Bs[g * 8]);
    }
    if (tid < 64) gload16(bias + m * KCODE + tid * 4, &bs[tid * 4]);
    __syncthreads();

    const int frow = lane & 15, kblk = lane >> 4;
    short8 af[2];
#pragma unroll
    for (int t = 0; t < 2; ++t) {
        const int r = wave * 32 + t * 16 + frow;
        af[t] = *(const short8*)&As[(r * 4 + (kblk ^ ((r >> 1) & 3))) * 8];
    }
    unsigned best[2][4];
#pragma unroll
    for (int t = 0; t < 2; ++t)
#pragma unroll
        for (int r = 0; r < 4; ++r) best[t][r] = 0xFFFFFFFFu;

#pragma unroll
    for (int n = 0; n < 16; ++n) {
        const int br = n * 16 + frow;                 // codeword index for this lane
        const short8 bf = *(const short8*)&Bs[(br * 4 + (kblk ^ ((br >> 1) & 3))) * 8];
        const float bv = bs[br];
        const unsigned kid = (unsigned)br;
        floatx4 a0 = __builtin_amdgcn_mfma_f32_16x16x32_bf16(
            af[0], bf, (floatx4){0.f, 0.f, 0.f, 0.f}, 0, 0, 0);
        floatx4 a1 = __builtin_amdgcn_mfma_f32_16x16x32_bf16(
            af[1], bf, (floatx4){0.f, 0.f, 0.f, 0.f}, 0, 0, 0);
#pragma unroll
        for (int r = 0; r < 4; ++r) {
            const float d0 = bv - a0[r];
            const float d1 = bv - a1[r];
            unsigned u0 = __float_as_uint(d0); u0 ^= (unsigned)((int)u0 >> 31) | 0x80000000u;
            unsigned u1 = __float_as_uint(d1); u1 ^= (unsigned)((int)u1 >> 31) | 0x80000000u;
            best[0][r] = min(best[0][r], (u0 & 0xFFFFFF00u) | kid);
            best[1][r] = min(best[1][r], (u1 & 0xFFFFFF00u) | kid);
        }
    }
    // reduce over the 16 lanes sharing each output row (C col = lane&15)
#pragma unroll
    for (int off = 1; off <= 8; off <<= 1)
#pragma unroll
        for (int t = 0; t < 2; ++t)
#pragma unroll
            for (int r = 0; r < 4; ++r)
                best[t][r] = min(best[t][r], (unsigned)__shfl_xor((int)best[t][r], off));
    if (frow == 0) {
        const int rbase = row0 + wave * 32 + kblk * 4;   // C row = (lane>>4)*4 + reg
#pragma unroll
        for (int t = 0; t < 2; ++t)
#pragma unroll
            for (int r = 0; r < 4; ++r)
                codes[(size_t)(rbase + t * 16 + r) * MSUB + m] =
                    (unsigned char)(best[t][r] & 0xFFu);
    }
}

// ============ PQ reconstruct: out_bf16 = cb[m][k] + center ============
__global__ __launch_bounds__(256) void pq_recon_kernel(
    const unsigned char* __restrict__ codes, const float* __restrict__ cb,
    const unsigned short* __restrict__ ccb, unsigned short* __restrict__ outb)
{
    const int idx = blockIdx.x * 256 + threadIdx.x;  // n*32+m
    const int n = idx >> 5, m = idx & 31;
    const int k = codes[idx];
    const float* cp = cb + ((size_t)m * KCODE + k) * DSUB;
    const unsigned short* ccp = ccb + (size_t)n * EMB + m * DSUB;
    unsigned short* op = outb + (size_t)n * EMB + m * DSUB;
#pragma unroll
    for (int j = 0; j < 6; ++j) {
        const float4 a = *(const float4*)(cp + j * 4);
        const ushort4 cc = ((const ushort4*)ccp)[j];
        ushort4 o;
        o.x = f2bf(a.x + bf2f(cc.x)); o.y = f2bf(a.y + bf2f(cc.y));
        o.z = f2bf(a.z + bf2f(cc.z)); o.w = f2bf(a.w + bf2f(cc.w));
        ((ushort4*)op)[j] = o;
    }
}

// ============ softmax helpers ============
__device__ __forceinline__ void ms_combine(float& m, float& s, float m2, float s2)
{
    const float M = fmaxf(m, m2);
    s = s * expf(m - M) + s2 * expf(m2 - M);
    m = M;
}

__global__ __launch_bounds__(256) void tstats_kernel(const float* __restrict__ T,
                                                     float* __restrict__ tst)
{
    __shared__ float redm[256], reds[256];
    const int i = blockIdx.x, t = threadIdx.x;
    const float4* t4 = (const float4*)(T + (size_t)i * NCOLS);
    float m = -3.4e38f, s = 0.f;
    for (int c = t; c < NCOLS / 4; c += 256) {
        const float4 v = t4[c];
        const float mx = fmaxf(fmaxf(v.x, v.y), fmaxf(v.z, v.w));
        const float M = fmaxf(m, mx);
        s = s * expf(m - M) + expf(v.x - M) + expf(v.y - M) + expf(v.z - M) + expf(v.w - M);
        m = M;
    }
    redm[t] = m; reds[t] = s;
    __syncthreads();
#pragma unroll
    for (int st = 128; st > 0; st >>= 1) {
        if (t < st) {
            float mm = redm[t], ss = reds[t];
            ms_combine(mm, ss, redm[t + st], reds[t + st]);
            redm[t] = mm; reds[t] = ss;
        }
        __syncthreads();
    }
    if (t == 0) { tst[i * 2] = redm[0]; tst[i * 2 + 1] = reds[0]; }
}

__device__ __forceinline__ void loss_body(
    const float* __restrict__ T, const float* __restrict__ S,
    const float* __restrict__ tst, float* __restrict__ o, float scale,
    int i, int t, float* redm, float* reds)
{
    const float4* s4 = (const float4*)(S + (size_t)i * NCOLS);
    const float4* t4 = (const float4*)(T + (size_t)i * NCOLS);

    float m = -3.4e38f, s = 0.f;
    for (int c = t; c < NCOLS / 4; c += 256) {
        const float4 v = s4[c];
        const float mx = fmaxf(fmaxf(v.x, v.y), fmaxf(v.z, v.w));
        const float M = fmaxf(m, mx);
        s = s * expf(m - M) + expf(v.x - M) + expf(v.y - M) + expf(v.z - M) + expf(v.w - M);
        m = M;
    }
    redm[t] = m; reds[t] = s;
    __syncthreads();
#pragma unroll
    for (int st = 128; st > 0; st >>= 1) {
        if (t < st) {
            float mm = redm[t], ss = reds[t];
            ms_combine(mm, ss, redm[t + st], reds[t + st]);
            redm[t] = mm; reds[t] = ss;
        }
        __syncthreads();
    }
    const float smax = redm[0];
    const float inv_ssum = 1.f / reds[0];
    __syncthreads();
    const float tmax = tst[i * 2];
    const float inv_tsum = 1.f / tst[i * 2 + 1];

    float loss = 0.f;
    for (int c = t; c < NCOLS / 4; c += 256) {
        const float4 sv = s4[c];
        const float4 tv = t4[c];
        loss -= expf(tv.x - tmax) * inv_tsum * logf(expf(sv.x - smax) * inv_ssum + 1e-6f);
        loss -= expf(tv.y - tmax) * inv_tsum * logf(expf(sv.y - smax) * inv_ssum + 1e-6f);
        loss -= expf(tv.z - tmax) * inv_tsum * logf(expf(sv.z - smax) * inv_ssum + 1e-6f);
        loss -= expf(tv.w - tmax) * inv_tsum * logf(expf(sv.w - smax) * inv_ssum + 1e-6f);
    }
    redm[t] = loss;
    __syncthreads();
#pragma unroll
    for (int st = 128; st > 0; st >>= 1) {
        if (t < st) redm[t] += redm[t + st];
        __syncthreads();
    }
    if (t == 0) atomicAdd(o, redm[0] * scale);
}

__global__ __launch_bounds__(256) void loss_kernel(
    const float* __restrict__ T, const float* __restrict__ S,
    const float* __restrict__ tst, float* __restrict__ out, float scale)
{
    __shared__ float redm[256], reds[256];
    loss_body(T, S, tst, out, scale, blockIdx.x, threadIdx.x, redm, reds);
}

__global__ __launch_bounds__(256) void loss2_kernel(
    const float* __restrict__ T, const float* __restrict__ S0,
    const float* __restrict__ S1, const float* __restrict__ tst,
    float* __restrict__ out, float scale)
{
    __shared__ float redm[256], reds[256];
    const float* S = blockIdx.y ? S1 : S0;
    loss_body(T, S, tst, out + 1 + blockIdx.y, scale, blockIdx.x, threadIdx.x, redm, reds);
}

__global__ void zero_out_kernel(float* __restrict__ out, int n)
{
    if ((int)threadIdx.x < n) out[threadIdx.x] = 0.f;
}

// ============ launch ============
extern "C" void kernel_launch(void* const* d_in, const int* in_sizes, int n_in,
                              void* d_out, int out_size, void* d_ws, size_t ws_size,
                              hipStream_t stream)
{
    const float* q    = (const float*)d_in[0];
    const float* dpos = (const float*)d_in[1];
    const float* nneg = (const float*)d_in[2];
    const float* rot  = (const float*)d_in[3];
    const float* cb   = (const float*)d_in[4];
    const float* ivf  = (const float*)d_in[5];
    const int* doc_ids = (const int*)d_in[6];
    const int* neg_ids = (const int*)d_in[7];
    float* out = (float*)d_out;

    // ---- workspace (256B-aligned), ~105 MB ----
    char* p = (char*)d_ws;
    auto take = [&](size_t bytes) { char* r = p; p += (bytes + 255) & ~(size_t)255; return r; };
    unsigned short* qdnb  = (unsigned short*)take((size_t)(NQ + NTOT) * EMB * 2);
    unsigned short* rqdnb = (unsigned short*)take((size_t)(NQ + NTOT) * EMB * 2);
    unsigned short* rotb  = (unsigned short*)take((size_t)EMB * EMB * 2);
    unsigned short* ccb   = (unsigned short*)take((size_t)NTOT * EMB * 2);
    unsigned short* pqb   = (unsigned short*)take((size_t)NTOT * EMB * 2);
    float*          T     = (float*)take((size_t)NQ * NCOLS * 4);
    float*          S0    = (float*)take((size_t)NQ * NCOLS * 4);
    float*          S1    = (float*)take((size_t)NQ * NCOLS * 4);
    unsigned char*  codes = (unsigned char*)take((size_t)NTOT * MSUB);
    float*          tst   = (float*)take((size_t)NQ * 2 * 4);

    // aliases: consumed before their host buffer is first written
    unsigned short* subp = (unsigned short*)S1;                 // 10.5 MB < 21 MB; dead before step 7
    unsigned short* cbb  = (unsigned short*)S0;                 // 512 KB; dead before step 5
    float*          bias = (float*)((char*)S0 + (size_t)MSUB * KCODE * DPAD * 2);

    unsigned short* qb   = qdnb;
    unsigned short* dnb  = qdnb + (size_t)NQ * EMB;
    unsigned short* rqb  = rqdnb;
    unsigned short* rdnb = rqdnb + (size_t)NQ * EMB;

    const float scale = 1.f / NQ;
    zero_out_kernel<<<1, 64, 0, stream>>>(out, out_size);

    // 1) fp32 -> bf16
    const int cvt4 = (NQ * EMB + NQ * EMB + 4096 * EMB + EMB * EMB) / 4;
    cvt_all_kernel<<<(cvt4 + 255) / 256, 256, 0, stream>>>(q, dpos, nneg, rot, qdnb, rotb);

    // 2) IVF gather -> ccb; zero subp (pad cols); codebook prep
    gather_kernel<<<NTOT, EMB / 4, 0, stream>>>(ivf, doc_ids, neg_ids, ccb);
    const int z16 = (int)((size_t)NTOT * MSUB * DPAD * 2 / 16);
    zero16_kernel<<<(z16 + 255) / 256, 256, 0, stream>>>((uint4*)subp, z16);
    cbprep_kernel<<<MSUB * KCODE / 256, 256, 0, stream>>>(cb, cbb, bias);

    // 3) rotation: [q;d;n] @ rot^T -> rqdnb bf16; rows >= NQ also subp = bf16(acc - center)
    gemm_rot<<<dim3(EMB / BNR, (NQ + NTOT) / BMR), 256, 0, stream>>>(
        qdnb, rotb, rqdnb, ccb, subp, EMB, EMB, EMB, EMB);

    // 4) PQ argmin (MFMA) + reconstruct -> pqb
    pq_mfma_argmin<<<dim3(NTOT / 128, MSUB), 256, 0, stream>>>(subp, cbb, bias, codes);
    pq_recon_kernel<<<(NTOT * MSUB) / 256, 256, 0, stream>>>(codes, cb, ccb, pqb);

    // 5) batched GEMM: z0 teacher = qb@dnb^T -> T; z1 dense = rqb@rdnb^T -> S0
    gemm_score<<<dim3(NTOT / BNS, NQ / BMS, 2), 256, 0, stream>>>(
        qb, dnb, T, rqb, rdnb, S0);

    // 6) teacher stats + dense loss
    tstats_kernel<<<NQ, 256, 0, stream>>>(T, tst);
    loss_kernel<<<NQ, 256, 0, stream>>>(T, S0, tst, out + 0, scale);

    // 7) batched GEMM: z0 ivf = rqb@ccb^T -> S0; z1 pq = rqb@pqb^T -> S1
    gemm_score<<<dim3(NTOT / BNS, NQ / BMS, 2), 256, 0, stream>>>(
        rqb, ccb, S0, rqb, pqb, S1);

    // 8) ivf + pq losses
    loss2_kernel<<<dim3(NQ, 2), 256, 0, stream>>>(T, S0, S1, tst, out, scale);
}

// Round 7
// 192.098 us; speedup vs baseline: 5.2266x; 1.0941x over previous
//
#include <hip/hip_runtime.h>
#include <math.h>

#define EMB 768
#define MSUB 32
#define KCODE 256
#define DSUB 24
#define NQ 1024
#define NTOT 5120    // 1024 docs + 4096 negs
#define NCOLS 5120
#define DPAD 32      // padded subvector dim for MFMA (K=32)

typedef __attribute__((ext_vector_type(8))) short short8;
typedef __attribute__((ext_vector_type(4))) float floatx4;

__device__ __forceinline__ unsigned short f2bf(float f) {
    unsigned int u = __float_as_uint(f);
    unsigned int r = (u + 0x7FFFu + ((u >> 16) & 1u)) >> 16;   // RNE
    return (unsigned short)r;
}
__device__ __forceinline__ float bf2f(unsigned short h) {
    return __uint_as_float((unsigned int)h << 16);
}

__device__ __forceinline__ void gload16(const void* g, void* l) {
    __builtin_amdgcn_global_load_lds(
        (const __attribute__((address_space(1))) void*)g,
        (__attribute__((address_space(3))) void*)l, 16, 0, 0);
}

// ============ rotation GEMM: BM=64 x BN=128; bf16 out + padded bf16 residual ========
#define BMR 64
#define BNR 128
#define BKG 32
__global__ __launch_bounds__(256) void gemm_rot(
    const unsigned short* __restrict__ A, const unsigned short* __restrict__ B,
    unsigned short* __restrict__ Cb, const unsigned short* __restrict__ ccb,
    unsigned short* __restrict__ subp, int K, int lda, int ldb, int ldcb)
{
    __shared__ __align__(16) unsigned short As[BMR * BKG];   // 4 KB
    __shared__ __align__(16) unsigned short Bs[BNR * BKG];   // 8 KB
    const int tid  = threadIdx.x;
    const int wave = tid >> 6;
    const int lane = tid & 63;
    const int wr = wave >> 1, wc = wave & 1;
    const int row0 = blockIdx.y * BMR;
    const int col0 = blockIdx.x * BNR;

    const int ar  = tid >> 2, aks  = (tid & 3) ^ ((ar >> 1) & 3);
    const unsigned short* Ap = A + (size_t)(row0 + ar) * lda + aks * 8;
    unsigned short* Al = &As[tid * 8];
    const int br0 = tid >> 2,        bks0 = (tid & 3) ^ ((br0 >> 1) & 3);
    const int br1 = 64 + (tid >> 2), bks1 = (tid & 3) ^ ((br1 >> 1) & 3);
    const unsigned short* Bp0 = B + (size_t)(col0 + br0) * ldb + bks0 * 8;
    const unsigned short* Bp1 = B + (size_t)(col0 + br1) * ldb + bks1 * 8;
    unsigned short* Bl0 = &Bs[tid * 8];
    unsigned short* Bl1 = &Bs[(tid + 256) * 8];

    const int frow = lane & 15;
    const int kblk = lane >> 4;
    int aoff[2], boff[4];
#pragma unroll
    for (int m = 0; m < 2; ++m) {
        const int r = wr * 32 + m * 16 + frow;
        aoff[m] = (r * 4 + (kblk ^ ((r >> 1) & 3))) * 8;
    }
#pragma unroll
    for (int n = 0; n < 4; ++n) {
        const int c = wc * 64 + n * 16 + frow;
        boff[n] = (c * 4 + (kblk ^ ((c >> 1) & 3))) * 8;
    }

    floatx4 acc[2][4];
#pragma unroll
    for (int m = 0; m < 2; ++m)
#pragma unroll
        for (int n = 0; n < 4; ++n)
            acc[m][n] = (floatx4){0.f, 0.f, 0.f, 0.f};

    for (int k0 = 0; k0 < K; k0 += BKG) {
        gload16(Ap + k0, Al);
        gload16(Bp0 + k0, Bl0);
        gload16(Bp1 + k0, Bl1);
        __syncthreads();
        short8 af[2], bf[4];
#pragma unroll
        for (int m = 0; m < 2; ++m) af[m] = *(const short8*)&As[aoff[m]];
#pragma unroll
        for (int n = 0; n < 4; ++n) bf[n] = *(const short8*)&Bs[boff[n]];
#pragma unroll
        for (int m = 0; m < 2; ++m)
#pragma unroll
            for (int n = 0; n < 4; ++n)
                acc[m][n] = __builtin_amdgcn_mfma_f32_16x16x32_bf16(
                    af[m], bf[n], acc[m][n], 0, 0, 0);
        __syncthreads();
    }

    const int crow = row0 + wr * 32 + (lane >> 4) * 4;
    const int ccol = col0 + wc * 64 + (lane & 15);
#pragma unroll
    for (int m = 0; m < 2; ++m)
#pragma unroll
        for (int n = 0; n < 4; ++n)
#pragma unroll
            for (int r = 0; r < 4; ++r) {
                const int rr = crow + m * 16 + r;
                const int cc = ccol + n * 16;
                const float v = acc[m][n][r];
                Cb[(size_t)rr * ldcb + cc] = f2bf(v);
                if (rr >= NQ) {
                    const int nn = rr - NQ;
                    const float cen = bf2f(ccb[(size_t)nn * EMB + cc]);
                    const unsigned mm = (unsigned)cc / 24u;
                    const unsigned jj = (unsigned)cc - mm * 24u;
                    subp[(size_t)nn * (MSUB * DPAD) + mm * DPAD + jj] = f2bf(v - cen);
                }
            }
}

// ============ z-batched score GEMM: BM=128 x BN=128, fp32 out, up to 4 triples ======
#define BMS 128
#define BNS 128
__global__ __launch_bounds__(256) void gemm_score4(
    const unsigned short* __restrict__ A0, const unsigned short* __restrict__ B0, float* __restrict__ C0,
    const unsigned short* __restrict__ A1, const unsigned short* __restrict__ B1, float* __restrict__ C1,
    const unsigned short* __restrict__ A2, const unsigned short* __restrict__ B2, float* __restrict__ C2,
    const unsigned short* __restrict__ A3, const unsigned short* __restrict__ B3, float* __restrict__ C3)
{
    const unsigned short* A; const unsigned short* B; float* C;
    switch (blockIdx.z) {
        case 0:  A = A0; B = B0; C = C0; break;
        case 1:  A = A1; B = B1; C = C1; break;
        case 2:  A = A2; B = B2; C = C2; break;
        default: A = A3; B = B3; C = C3; break;
    }

    __shared__ __align__(16) unsigned short As[BMS * BKG];   // 8 KB
    __shared__ __align__(16) unsigned short Bs[BNS * BKG];   // 8 KB
    const int tid  = threadIdx.x;
    const int wave = tid >> 6;
    const int lane = tid & 63;
    const int wr = wave >> 1, wc = wave & 1;
    const int row0 = blockIdx.y * BMS;
    const int col0 = blockIdx.x * BNS;

    const int g0 = tid, g1 = tid + 256;
    const int ar0 = g0 >> 2, as0 = (g0 & 3) ^ ((ar0 >> 1) & 3);
    const int ar1 = g1 >> 2, as1 = (g1 & 3) ^ ((ar1 >> 1) & 3);
    const unsigned short* Ap0 = A + (size_t)(row0 + ar0) * EMB + as0 * 8;
    const unsigned short* Ap1 = A + (size_t)(row0 + ar1) * EMB + as1 * 8;
    const unsigned short* Bp0 = B + (size_t)(col0 + ar0) * EMB + as0 * 8;
    const unsigned short* Bp1 = B + (size_t)(col0 + ar1) * EMB + as1 * 8;
    unsigned short* Al0 = &As[g0 * 8];
    unsigned short* Al1 = &As[g1 * 8];
    unsigned short* Bl0 = &Bs[g0 * 8];
    unsigned short* Bl1 = &Bs[g1 * 8];

    const int frow = lane & 15;
    const int kblk = lane >> 4;
    int aoff[4], boff[4];
#pragma unroll
    for (int m = 0; m < 4; ++m) {
        const int r = wr * 64 + m * 16 + frow;
        aoff[m] = (r * 4 + (kblk ^ ((r >> 1) & 3))) * 8;
        const int c = wc * 64 + m * 16 + frow;
        boff[m] = (c * 4 + (kblk ^ ((c >> 1) & 3))) * 8;
    }

    floatx4 acc[4][4];
#pragma unroll
    for (int m = 0; m < 4; ++m)
#pragma unroll
        for (int n = 0; n < 4; ++n)
            acc[m][n] = (floatx4){0.f, 0.f, 0.f, 0.f};

    for (int k0 = 0; k0 < EMB; k0 += BKG) {
        gload16(Ap0 + k0, Al0);
        gload16(Ap1 + k0, Al1);
        gload16(Bp0 + k0, Bl0);
        gload16(Bp1 + k0, Bl1);
        __syncthreads();
        short8 af[4], bf[4];
#pragma unroll
        for (int m = 0; m < 4; ++m) af[m] = *(const short8*)&As[aoff[m]];
#pragma unroll
        for (int n = 0; n < 4; ++n) bf[n] = *(const short8*)&Bs[boff[n]];
#pragma unroll
        for (int m = 0; m < 4; ++m)
#pragma unroll
            for (int n = 0; n < 4; ++n)
                acc[m][n] = __builtin_amdgcn_mfma_f32_16x16x32_bf16(
                    af[m], bf[n], acc[m][n], 0, 0, 0);
        __syncthreads();
    }

    const int crow = row0 + wr * 64 + (lane >> 4) * 4;
    const int ccol = col0 + wc * 64 + (lane & 15);
#pragma unroll
    for (int m = 0; m < 4; ++m)
#pragma unroll
        for (int n = 0; n < 4; ++n)
#pragma unroll
            for (int r = 0; r < 4; ++r)
                C[(size_t)(crow + m * 16 + r) * NCOLS + ccol + n * 16] = acc[m][n][r];
}

// ============ fused fp32 -> bf16 conversion + subp pad zeroing ============
__global__ __launch_bounds__(256) void cvt_all_kernel(
    const float* __restrict__ q, const float* __restrict__ d,
    const float* __restrict__ n, const float* __restrict__ rot,
    unsigned short* __restrict__ qdnb, unsigned short* __restrict__ rotb,
    uint4* __restrict__ zdst, int zcount)
{
    const int i = blockIdx.x * 256 + threadIdx.x;  // 16B work-item index
    const int S1 = NQ * EMB / 4;
    const int S2 = S1 + NQ * EMB / 4;
    const int S3 = S2 + 4096 * EMB / 4;
    const int S4 = S3 + EMB * EMB / 4;
    if (i >= S4) {
        const int z = i - S4;
        if (z < zcount) zdst[z] = make_uint4(0u, 0u, 0u, 0u);
        return;
    }
    const float* src; unsigned short* dst; int off;
    if (i < S1)      { src = q;   dst = qdnb;                          off = i; }
    else if (i < S2) { src = d;   dst = qdnb + (size_t)NQ * EMB;       off = i - S1; }
    else if (i < S3) { src = n;   dst = qdnb + (size_t)2 * NQ * EMB;   off = i - S2; }
    else             { src = rot; dst = rotb;                          off = i - S3; }
    const float4 v = ((const float4*)src)[off];
    ushort4 b;
    b.x = f2bf(v.x); b.y = f2bf(v.y); b.z = f2bf(v.z); b.w = f2bf(v.w);
    ((ushort4*)dst)[off] = b;
}

// ============ IVF gather (bf16) ============
__global__ void gather_kernel(const float* __restrict__ centers,
                              const int* __restrict__ doc_ids,
                              const int* __restrict__ neg_ids,
                              unsigned short* __restrict__ outb)
{
    const int i = blockIdx.x;
    const int id = (i < NQ) ? doc_ids[i] : neg_ids[i - NQ];
    const int t = threadIdx.x;
    const float4 v = ((const float4*)(centers + (size_t)id * EMB))[t];
    ushort4 b;
    b.x = f2bf(v.x); b.y = f2bf(v.y); b.z = f2bf(v.z); b.w = f2bf(v.w);
    ((ushort4*)(outb + (size_t)i * EMB))[t] = b;
}

// ============ codebook prep: padded bf16 + 0.5*||c||^2 bias ============
__global__ __launch_bounds__(256) void cbprep_kernel(
    const float* __restrict__ cb, unsigned short* __restrict__ cbb,
    float* __restrict__ bias)
{
    const int idx = blockIdx.x * 256 + threadIdx.x;  // m*256 + k  (8192 total)
    const float* cp = cb + (size_t)idx * DSUB;
    unsigned short o[DPAD];
    float ss = 0.f;
#pragma unroll
    for (int j = 0; j < 6; ++j) {
        const float4 v = *(const float4*)(cp + j * 4);
        o[j * 4 + 0] = f2bf(v.x); o[j * 4 + 1] = f2bf(v.y);
        o[j * 4 + 2] = f2bf(v.z); o[j * 4 + 3] = f2bf(v.w);
        ss = fmaf(v.x, v.x, ss); ss = fmaf(v.y, v.y, ss);
        ss = fmaf(v.z, v.z, ss); ss = fmaf(v.w, v.w, ss);
    }
#pragma unroll
    for (int j = DSUB; j < DPAD; ++j) o[j] = 0;
    unsigned short* op = cbb + (size_t)idx * DPAD;
#pragma unroll
    for (int j = 0; j < DPAD / 4; ++j)
        ((ushort4*)op)[j] = make_ushort4(o[j*4], o[j*4+1], o[j*4+2], o[j*4+3]);
    bias[idx] = 0.5f * ss;
}

// ============ PQ argmin via MFMA: block = 128 rows x 256 codewords x one m ==========
__global__ __launch_bounds__(256) void pq_mfma_argmin(
    const unsigned short* __restrict__ subp,   // [NTOT][MSUB*DPAD]
    const unsigned short* __restrict__ cbb,    // [MSUB][KCODE][DPAD]
    const float* __restrict__ bias,            // [MSUB][KCODE]
    unsigned char* __restrict__ codes)         // [NTOT][MSUB]
{
    const int m = blockIdx.y;
    const int row0 = blockIdx.x * 128;
    __shared__ __align__(16) unsigned short As[128 * DPAD];   // 8 KB
    __shared__ __align__(16) unsigned short Bs[KCODE * DPAD]; // 16 KB
    __shared__ __align__(16) float bs[KCODE];                 // 1 KB
    const int tid = threadIdx.x;
    const int wave = tid >> 6, lane = tid & 63;

    {
        const int g = tid;
        const int r = g >> 2, kc = (g & 3) ^ ((r >> 1) & 3);
        gload16(subp + (size_t)(row0 + r) * (MSUB * DPAD) + m * DPAD + kc * 8, &As[g * 8]);
    }
    {
        const int g = tid + 256;
        const int r = g >> 2, kc = (g & 3) ^ ((r >> 1) & 3);
        gload16(subp + (size_t)(row0 + r) * (MSUB * DPAD) + m * DPAD + kc * 8, &As[g * 8]);
    }
#pragma unroll
    for (int i = 0; i < 4; ++i) {
        const int g = tid + i * 256;
        const int r = g >> 2, kc = (g & 3) ^ ((r >> 1) & 3);
        gload16(cbb + (size_t)m * (KCODE * DPAD) + r * DPAD + kc * 8, &Bs[g * 8]);
    }
    if (tid < 64) gload16(bias + m * KCODE + tid * 4, &bs[tid * 4]);
    __syncthreads();

    const int frow = lane & 15, kblk = lane >> 4;
    short8 af[2];
#pragma unroll
    for (int t = 0; t < 2; ++t) {
        const int r = wave * 32 + t * 16 + frow;
        af[t] = *(const short8*)&As[(r * 4 + (kblk ^ ((r >> 1) & 3))) * 8];
    }
    unsigned best[2][4];
#pragma unroll
    for (int t = 0; t < 2; ++t)
#pragma unroll
        for (int r = 0; r < 4; ++r) best[t][r] = 0xFFFFFFFFu;

#pragma unroll
    for (int n = 0; n < 16; ++n) {
        const int br = n * 16 + frow;                 // codeword index for this lane
        const short8 bf = *(const short8*)&Bs[(br * 4 + (kblk ^ ((br >> 1) & 3))) * 8];
        const float bv = bs[br];
        const unsigned kid = (unsigned)br;
        floatx4 a0 = __builtin_amdgcn_mfma_f32_16x16x32_bf16(
            af[0], bf, (floatx4){0.f, 0.f, 0.f, 0.f}, 0, 0, 0);
        floatx4 a1 = __builtin_amdgcn_mfma_f32_16x16x32_bf16(
            af[1], bf, (floatx4){0.f, 0.f, 0.f, 0.f}, 0, 0, 0);
#pragma unroll
        for (int r = 0; r < 4; ++r) {
            const float d0 = bv - a0[r];
            const float d1 = bv - a1[r];
            unsigned u0 = __float_as_uint(d0); u0 ^= (unsigned)((int)u0 >> 31) | 0x80000000u;
            unsigned u1 = __float_as_uint(d1); u1 ^= (unsigned)((int)u1 >> 31) | 0x80000000u;
            best[0][r] = min(best[0][r], (u0 & 0xFFFFFF00u) | kid);
            best[1][r] = min(best[1][r], (u1 & 0xFFFFFF00u) | kid);
        }
    }
#pragma unroll
    for (int off = 1; off <= 8; off <<= 1)
#pragma unroll
        for (int t = 0; t < 2; ++t)
#pragma unroll
            for (int r = 0; r < 4; ++r)
                best[t][r] = min(best[t][r], (unsigned)__shfl_xor((int)best[t][r], off));
    if (frow == 0) {
        const int rbase = row0 + wave * 32 + kblk * 4;
#pragma unroll
        for (int t = 0; t < 2; ++t)
#pragma unroll
            for (int r = 0; r < 4; ++r)
                codes[(size_t)(rbase + t * 16 + r) * MSUB + m] =
                    (unsigned char)(best[t][r] & 0xFFu);
    }
}

// ============ PQ reconstruct: out_bf16 = cb[m][k] + center ============
__global__ __launch_bounds__(256) void pq_recon_kernel(
    const unsigned char* __restrict__ codes, const float* __restrict__ cb,
    const unsigned short* __restrict__ ccb, unsigned short* __restrict__ outb)
{
    const int idx = blockIdx.x * 256 + threadIdx.x;  // n*32+m
    const int n = idx >> 5, m = idx & 31;
    const int k = codes[idx];
    const float* cp = cb + ((size_t)m * KCODE + k) * DSUB;
    const unsigned short* ccp = ccb + (size_t)n * EMB + m * DSUB;
    unsigned short* op = outb + (size_t)n * EMB + m * DSUB;
#pragma unroll
    for (int j = 0; j < 6; ++j) {
        const float4 a = *(const float4*)(cp + j * 4);
        const ushort4 cc = ((const ushort4*)ccp)[j];
        ushort4 o;
        o.x = f2bf(a.x + bf2f(cc.x)); o.y = f2bf(a.y + bf2f(cc.y));
        o.z = f2bf(a.z + bf2f(cc.z)); o.w = f2bf(a.w + bf2f(cc.w));
        ((ushort4*)op)[j] = o;
    }
}

// ============ fused distill loss: ONE WAVE per (row, loss); no barriers ============
__device__ __forceinline__ void ms_combine(float& m, float& s, float m2, float s2)
{
    const float M = fmaxf(m, m2);
    s = s * expf(m - M) + s2 * expf(m2 - M);
    m = M;
}

__global__ __launch_bounds__(256) void loss_fused_kernel(
    const float* __restrict__ T, const float* __restrict__ Sa,
    const float* __restrict__ Sb, const float* __restrict__ Sc,
    int nS, float* __restrict__ out, int outoff, float scale)
{
    const int w = blockIdx.x * 4 + (threadIdx.x >> 6);
    const int lane = threadIdx.x & 63;
    const int row = w & (NQ - 1);
    const int ls = w >> 10;
    if (ls >= nS) return;
    const float* S = (ls == 0) ? Sa : ((ls == 1) ? Sb : Sc);
    const float4* t4 = (const float4*)(T + (size_t)row * NCOLS);
    const float4* s4 = (const float4*)(S + (size_t)row * NCOLS);

    float tm = -3.4e38f, ts = 0.f, sm = -3.4e38f, ss = 0.f;
    for (int c = lane; c < NCOLS / 4; c += 64) {
        const float4 tv = t4[c];
        const float4 sv = s4[c];
        float mx = fmaxf(fmaxf(tv.x, tv.y), fmaxf(tv.z, tv.w));
        float M = fmaxf(tm, mx);
        ts = ts * expf(tm - M) + expf(tv.x - M) + expf(tv.y - M) + expf(tv.z - M) + expf(tv.w - M);
        tm = M;
        mx = fmaxf(fmaxf(sv.x, sv.y), fmaxf(sv.z, sv.w));
        M = fmaxf(sm, mx);
        ss = ss * expf(sm - M) + expf(sv.x - M) + expf(sv.y - M) + expf(sv.z - M) + expf(sv.w - M);
        sm = M;
    }
#pragma unroll
    for (int off = 32; off >= 1; off >>= 1) {
        const float tm2 = __shfl_xor(tm, off), ts2 = __shfl_xor(ts, off);
        ms_combine(tm, ts, tm2, ts2);
        const float sm2 = __shfl_xor(sm, off), ss2 = __shfl_xor(ss, off);
        ms_combine(sm, ss, sm2, ss2);
    }
    const float inv_t = 1.f / ts;
    const float inv_s = 1.f / ss;

    float loss = 0.f;
    for (int c = lane; c < NCOLS / 4; c += 64) {
        const float4 tv = t4[c];
        const float4 sv = s4[c];
        loss -= expf(tv.x - tm) * inv_t * logf(expf(sv.x - sm) * inv_s + 1e-6f);
        loss -= expf(tv.y - tm) * inv_t * logf(expf(sv.y - sm) * inv_s + 1e-6f);
        loss -= expf(tv.z - tm) * inv_t * logf(expf(sv.z - sm) * inv_s + 1e-6f);
        loss -= expf(tv.w - tm) * inv_t * logf(expf(sv.w - sm) * inv_s + 1e-6f);
    }
#pragma unroll
    for (int off = 32; off >= 1; off >>= 1) loss += __shfl_xor(loss, off);
    if (lane == 0) atomicAdd(out + outoff + ls, loss * scale);
}

__global__ void zero_out_kernel(float* __restrict__ out, int n)
{
    if ((int)threadIdx.x < n) out[threadIdx.x] = 0.f;
}

// ============ launch ============
extern "C" void kernel_launch(void* const* d_in, const int* in_sizes, int n_in,
                              void* d_out, int out_size, void* d_ws, size_t ws_size,
                              hipStream_t stream)
{
    const float* q    = (const float*)d_in[0];
    const float* dpos = (const float*)d_in[1];
    const float* nneg = (const float*)d_in[2];
    const float* rot  = (const float*)d_in[3];
    const float* cb   = (const float*)d_in[4];
    const float* ivf  = (const float*)d_in[5];
    const int* doc_ids = (const int*)d_in[6];
    const int* neg_ids = (const int*)d_in[7];
    float* out = (float*)d_out;

    char* p = (char*)d_ws;
    auto take = [&](size_t bytes) { char* r = p; p += (bytes + 255) & ~(size_t)255; return r; };
    unsigned short* qdnb  = (unsigned short*)take((size_t)(NQ + NTOT) * EMB * 2);
    unsigned short* rqdnb = (unsigned short*)take((size_t)(NQ + NTOT) * EMB * 2);
    unsigned short* rotb  = (unsigned short*)take((size_t)EMB * EMB * 2);
    unsigned short* ccb   = (unsigned short*)take((size_t)NTOT * EMB * 2);
    unsigned short* pqb   = (unsigned short*)take((size_t)NTOT * EMB * 2);
    unsigned short* cbb   = (unsigned short*)take((size_t)MSUB * KCODE * DPAD * 2);
    float*          bias  = (float*)take((size_t)MSUB * KCODE * 4);
    unsigned char*  codes = (unsigned char*)take((size_t)NTOT * MSUB);
    float*          T     = (float*)take((size_t)NQ * NCOLS * 4);
    float*          S0    = (float*)take((size_t)NQ * NCOLS * 4);
    float*          S1    = (float*)take((size_t)NQ * NCOLS * 4);
    const size_t used3 = (size_t)(p - (char*)d_ws);
    const bool big = ws_size >= used3 + (size_t)NQ * NCOLS * 4 + 256;
    float* S2 = big ? (float*)take((size_t)NQ * NCOLS * 4) : nullptr;

    // subp (10.5 MB) aliases the last S buffer: consumed by pq_mfma_argmin before
    // any score GEMM writes it.
    unsigned short* subp = (unsigned short*)(big ? (void*)S2 : (void*)S1);

    unsigned short* qb   = qdnb;
    unsigned short* dnb  = qdnb + (size_t)NQ * EMB;
    unsigned short* rqb  = rqdnb;
    unsigned short* rdnb = rqdnb + (size_t)NQ * EMB;

    const float scale = 1.f / NQ;
    zero_out_kernel<<<1, 64, 0, stream>>>(out, out_size);

    // 1) fp32 -> bf16 (+ zero subp pad columns)
    const int cvt4 = (NQ * EMB + NQ * EMB + 4096 * EMB + EMB * EMB) / 4;
    const int z16 = (int)((size_t)NTOT * MSUB * DPAD * 2 / 16);
    cvt_all_kernel<<<(cvt4 + z16 + 255) / 256, 256, 0, stream>>>(
        q, dpos, nneg, rot, qdnb, rotb, (uint4*)subp, z16);

    // 2) IVF gather + codebook prep
    gather_kernel<<<NTOT, EMB / 4, 0, stream>>>(ivf, doc_ids, neg_ids, ccb);
    cbprep_kernel<<<MSUB * KCODE / 256, 256, 0, stream>>>(cb, cbb, bias);

    // 3) rotation: [q;d;n] @ rot^T -> rqdnb bf16; rows >= NQ also subp residual
    gemm_rot<<<dim3(EMB / BNR, (NQ + NTOT) / BMR), 256, 0, stream>>>(
        qdnb, rotb, rqdnb, ccb, subp, EMB, EMB, EMB, EMB);

    // 4) PQ argmin (MFMA) + reconstruct -> pqb
    pq_mfma_argmin<<<dim3(NTOT / 128, MSUB), 256, 0, stream>>>(subp, cbb, bias, codes);
    pq_recon_kernel<<<(NTOT * MSUB) / 256, 256, 0, stream>>>(codes, cb, ccb, pqb);

    if (big) {
        // 5) all four score GEMMs in one z=4 dispatch (1280 blocks, ~5/CU)
        gemm_score4<<<dim3(NTOT / BNS, NQ / BMS, 4), 256, 0, stream>>>(
            qb, dnb, T,  rqb, rdnb, S0,  rqb, ccb, S1,  rqb, pqb, S2);
        // 6) all three losses, one barrier-free kernel
        loss_fused_kernel<<<NQ * 3 / 4, 256, 0, stream>>>(
            T, S0, S1, S2, 3, out, 0, scale);
    } else {
        // fallback: round-6 ordering within the smaller footprint
        gemm_score4<<<dim3(NTOT / BNS, NQ / BMS, 2), 256, 0, stream>>>(
            qb, dnb, T,  rqb, rdnb, S0,  nullptr, nullptr, nullptr,
            nullptr, nullptr, nullptr);
        loss_fused_kernel<<<NQ / 4, 256, 0, stream>>>(
            T, S0, nullptr, nullptr, 1, out, 0, scale);
        gemm_score4<<<dim3(NTOT / BNS, NQ / BMS, 2), 256, 0, stream>>>(
            rqb, ccb, S0,  rqb, pqb, S1,  nullptr, nullptr, nullptr,
            nullptr, nullptr, nullptr);
        loss_fused_kernel<<<NQ * 2 / 4, 256, 0, stream>>>(
            T, S0, S1, nullptr, 2, out, 1, scale);
    }
}

// Round 8
// 177.876 us; speedup vs baseline: 5.6445x; 1.0800x over previous
//
#include <hip/hip_runtime.h>
#include <math.h>

#define EMB 768
#define MSUB 32
#define KCODE 256
#define DSUB 24
#define NQ 1024
#define NTOT 5120    // 1024 docs + 4096 negs
#define NCOLS 5120
#define DPAD 32      // padded subvector dim for MFMA (K=32)
#define L2E 1.4426950408889634f
#define LN2 0.6931471805599453f

typedef __attribute__((ext_vector_type(8))) short short8;
typedef __attribute__((ext_vector_type(4))) float floatx4;

__device__ __forceinline__ unsigned short f2bf(float f) {
    unsigned int u = __float_as_uint(f);
    unsigned int r = (u + 0x7FFFu + ((u >> 16) & 1u)) >> 16;   // RNE
    return (unsigned short)r;
}
__device__ __forceinline__ float bf2f(unsigned short h) {
    return __uint_as_float((unsigned int)h << 16);
}

__device__ __forceinline__ void gload16(const void* g, void* l) {
    __builtin_amdgcn_global_load_lds(
        (const __attribute__((address_space(1))) void*)g,
        (__attribute__((address_space(3))) void*)l, 16, 0, 0);
}

// ============ rotation GEMM: BM=64 x BN=128; bf16 out + padded bf16 residual ========
#define BMR 64
#define BNR 128
#define BKG 32
__global__ __launch_bounds__(256) void gemm_rot(
    const unsigned short* __restrict__ A, const unsigned short* __restrict__ B,
    unsigned short* __restrict__ Cb, const unsigned short* __restrict__ ccb,
    unsigned short* __restrict__ subp, int K, int lda, int ldb, int ldcb)
{
    __shared__ __align__(16) unsigned short As[BMR * BKG];   // 4 KB
    __shared__ __align__(16) unsigned short Bs[BNR * BKG];   // 8 KB
    const int tid  = threadIdx.x;
    const int wave = tid >> 6;
    const int lane = tid & 63;
    const int wr = wave >> 1, wc = wave & 1;
    const int row0 = blockIdx.y * BMR;
    const int col0 = blockIdx.x * BNR;

    const int ar  = tid >> 2, aks  = (tid & 3) ^ ((ar >> 1) & 3);
    const unsigned short* Ap = A + (size_t)(row0 + ar) * lda + aks * 8;
    unsigned short* Al = &As[tid * 8];
    const int br0 = tid >> 2,        bks0 = (tid & 3) ^ ((br0 >> 1) & 3);
    const int br1 = 64 + (tid >> 2), bks1 = (tid & 3) ^ ((br1 >> 1) & 3);
    const unsigned short* Bp0 = B + (size_t)(col0 + br0) * ldb + bks0 * 8;
    const unsigned short* Bp1 = B + (size_t)(col0 + br1) * ldb + bks1 * 8;
    unsigned short* Bl0 = &Bs[tid * 8];
    unsigned short* Bl1 = &Bs[(tid + 256) * 8];

    const int frow = lane & 15;
    const int kblk = lane >> 4;
    int aoff[2], boff[4];
#pragma unroll
    for (int m = 0; m < 2; ++m) {
        const int r = wr * 32 + m * 16 + frow;
        aoff[m] = (r * 4 + (kblk ^ ((r >> 1) & 3))) * 8;
    }
#pragma unroll
    for (int n = 0; n < 4; ++n) {
        const int c = wc * 64 + n * 16 + frow;
        boff[n] = (c * 4 + (kblk ^ ((c >> 1) & 3))) * 8;
    }

    floatx4 acc[2][4];
#pragma unroll
    for (int m = 0; m < 2; ++m)
#pragma unroll
        for (int n = 0; n < 4; ++n)
            acc[m][n] = (floatx4){0.f, 0.f, 0.f, 0.f};

    for (int k0 = 0; k0 < K; k0 += BKG) {
        gload16(Ap + k0, Al);
        gload16(Bp0 + k0, Bl0);
        gload16(Bp1 + k0, Bl1);
        __syncthreads();
        short8 af[2], bf[4];
#pragma unroll
        for (int m = 0; m < 2; ++m) af[m] = *(const short8*)&As[aoff[m]];
#pragma unroll
        for (int n = 0; n < 4; ++n) bf[n] = *(const short8*)&Bs[boff[n]];
#pragma unroll
        for (int m = 0; m < 2; ++m)
#pragma unroll
            for (int n = 0; n < 4; ++n)
                acc[m][n] = __builtin_amdgcn_mfma_f32_16x16x32_bf16(
                    af[m], bf[n], acc[m][n], 0, 0, 0);
        __syncthreads();
    }

    const int crow = row0 + wr * 32 + (lane >> 4) * 4;
    const int ccol = col0 + wc * 64 + (lane & 15);
#pragma unroll
    for (int m = 0; m < 2; ++m)
#pragma unroll
        for (int n = 0; n < 4; ++n)
#pragma unroll
            for (int r = 0; r < 4; ++r) {
                const int rr = crow + m * 16 + r;
                const int cc = ccol + n * 16;
                const float v = acc[m][n][r];
                Cb[(size_t)rr * ldcb + cc] = f2bf(v);
                if (rr >= NQ) {
                    const int nn = rr - NQ;
                    const float cen = bf2f(ccb[(size_t)nn * EMB + cc]);
                    const unsigned mm = (unsigned)cc / 24u;
                    const unsigned jj = (unsigned)cc - mm * 24u;
                    subp[(size_t)nn * (MSUB * DPAD) + mm * DPAD + jj] = f2bf(v - cen);
                }
            }
}

// ============ z-batched score GEMM: BM=128 x BN=128, fp32 out, up to 4 triples ======
#define BMS 128
#define BNS 128
__global__ __launch_bounds__(256) void gemm_score4(
    const unsigned short* __restrict__ A0, const unsigned short* __restrict__ B0, float* __restrict__ C0,
    const unsigned short* __restrict__ A1, const unsigned short* __restrict__ B1, float* __restrict__ C1,
    const unsigned short* __restrict__ A2, const unsigned short* __restrict__ B2, float* __restrict__ C2,
    const unsigned short* __restrict__ A3, const unsigned short* __restrict__ B3, float* __restrict__ C3)
{
    const unsigned short* A; const unsigned short* B; float* C;
    switch (blockIdx.z) {
        case 0:  A = A0; B = B0; C = C0; break;
        case 1:  A = A1; B = B1; C = C1; break;
        case 2:  A = A2; B = B2; C = C2; break;
        default: A = A3; B = B3; C = C3; break;
    }

    __shared__ __align__(16) unsigned short As[BMS * BKG];   // 8 KB
    __shared__ __align__(16) unsigned short Bs[BNS * BKG];   // 8 KB
    const int tid  = threadIdx.x;
    const int wave = tid >> 6;
    const int lane = tid & 63;
    const int wr = wave >> 1, wc = wave & 1;
    const int row0 = blockIdx.y * BMS;
    const int col0 = blockIdx.x * BNS;

    const int g0 = tid, g1 = tid + 256;
    const int ar0 = g0 >> 2, as0 = (g0 & 3) ^ ((ar0 >> 1) & 3);
    const int ar1 = g1 >> 2, as1 = (g1 & 3) ^ ((ar1 >> 1) & 3);
    const unsigned short* Ap0 = A + (size_t)(row0 + ar0) * EMB + as0 * 8;
    const unsigned short* Ap1 = A + (size_t)(row0 + ar1) * EMB + as1 * 8;
    const unsigned short* Bp0 = B + (size_t)(col0 + ar0) * EMB + as0 * 8;
    const unsigned short* Bp1 = B + (size_t)(col0 + ar1) * EMB + as1 * 8;
    unsigned short* Al0 = &As[g0 * 8];
    unsigned short* Al1 = &As[g1 * 8];
    unsigned short* Bl0 = &Bs[g0 * 8];
    unsigned short* Bl1 = &Bs[g1 * 8];

    const int frow = lane & 15;
    const int kblk = lane >> 4;
    int aoff[4], boff[4];
#pragma unroll
    for (int m = 0; m < 4; ++m) {
        const int r = wr * 64 + m * 16 + frow;
        aoff[m] = (r * 4 + (kblk ^ ((r >> 1) & 3))) * 8;
        const int c = wc * 64 + m * 16 + frow;
        boff[m] = (c * 4 + (kblk ^ ((c >> 1) & 3))) * 8;
    }

    floatx4 acc[4][4];
#pragma unroll
    for (int m = 0; m < 4; ++m)
#pragma unroll
        for (int n = 0; n < 4; ++n)
            acc[m][n] = (floatx4){0.f, 0.f, 0.f, 0.f};

    for (int k0 = 0; k0 < EMB; k0 += BKG) {
        gload16(Ap0 + k0, Al0);
        gload16(Ap1 + k0, Al1);
        gload16(Bp0 + k0, Bl0);
        gload16(Bp1 + k0, Bl1);
        __syncthreads();
        short8 af[4], bf[4];
#pragma unroll
        for (int m = 0; m < 4; ++m) af[m] = *(const short8*)&As[aoff[m]];
#pragma unroll
        for (int n = 0; n < 4; ++n) bf[n] = *(const short8*)&Bs[boff[n]];
#pragma unroll
        for (int m = 0; m < 4; ++m)
#pragma unroll
            for (int n = 0; n < 4; ++n)
                acc[m][n] = __builtin_amdgcn_mfma_f32_16x16x32_bf16(
                    af[m], bf[n], acc[m][n], 0, 0, 0);
        __syncthreads();
    }

    const int crow = row0 + wr * 64 + (lane >> 4) * 4;
    const int ccol = col0 + wc * 64 + (lane & 15);
#pragma unroll
    for (int m = 0; m < 4; ++m)
#pragma unroll
        for (int n = 0; n < 4; ++n)
#pragma unroll
            for (int r = 0; r < 4; ++r)
                C[(size_t)(crow + m * 16 + r) * NCOLS + ccol + n * 16] = acc[m][n][r];
}

// ============ fused fp32 -> bf16 conversion + subp pad zeroing ============
__global__ __launch_bounds__(256) void cvt_all_kernel(
    const float* __restrict__ q, const float* __restrict__ d,
    const float* __restrict__ n, const float* __restrict__ rot,
    unsigned short* __restrict__ qdnb, unsigned short* __restrict__ rotb,
    uint4* __restrict__ zdst, int zcount)
{
    const int i = blockIdx.x * 256 + threadIdx.x;  // 16B work-item index
    const int S1 = NQ * EMB / 4;
    const int S2 = S1 + NQ * EMB / 4;
    const int S3 = S2 + 4096 * EMB / 4;
    const int S4 = S3 + EMB * EMB / 4;
    if (i >= S4) {
        const int z = i - S4;
        if (z < zcount) zdst[z] = make_uint4(0u, 0u, 0u, 0u);
        return;
    }
    const float* src; unsigned short* dst; int off;
    if (i < S1)      { src = q;   dst = qdnb;                          off = i; }
    else if (i < S2) { src = d;   dst = qdnb + (size_t)NQ * EMB;       off = i - S1; }
    else if (i < S3) { src = n;   dst = qdnb + (size_t)2 * NQ * EMB;   off = i - S2; }
    else             { src = rot; dst = rotb;                          off = i - S3; }
    const float4 v = ((const float4*)src)[off];
    ushort4 b;
    b.x = f2bf(v.x); b.y = f2bf(v.y); b.z = f2bf(v.z); b.w = f2bf(v.w);
    ((ushort4*)dst)[off] = b;
}

// ============ IVF gather (bf16) ============
__global__ void gather_kernel(const float* __restrict__ centers,
                              const int* __restrict__ doc_ids,
                              const int* __restrict__ neg_ids,
                              unsigned short* __restrict__ outb)
{
    const int i = blockIdx.x;
    const int id = (i < NQ) ? doc_ids[i] : neg_ids[i - NQ];
    const int t = threadIdx.x;
    const float4 v = ((const float4*)(centers + (size_t)id * EMB))[t];
    ushort4 b;
    b.x = f2bf(v.x); b.y = f2bf(v.y); b.z = f2bf(v.z); b.w = f2bf(v.w);
    ((ushort4*)(outb + (size_t)i * EMB))[t] = b;
}

// ============ codebook prep: padded bf16 + 0.5*||c||^2 bias ============
__global__ __launch_bounds__(256) void cbprep_kernel(
    const float* __restrict__ cb, unsigned short* __restrict__ cbb,
    float* __restrict__ bias)
{
    const int idx = blockIdx.x * 256 + threadIdx.x;  // m*256 + k  (8192 total)
    const float* cp = cb + (size_t)idx * DSUB;
    unsigned short o[DPAD];
    float ss = 0.f;
#pragma unroll
    for (int j = 0; j < 6; ++j) {
        const float4 v = *(const float4*)(cp + j * 4);
        o[j * 4 + 0] = f2bf(v.x); o[j * 4 + 1] = f2bf(v.y);
        o[j * 4 + 2] = f2bf(v.z); o[j * 4 + 3] = f2bf(v.w);
        ss = fmaf(v.x, v.x, ss); ss = fmaf(v.y, v.y, ss);
        ss = fmaf(v.z, v.z, ss); ss = fmaf(v.w, v.w, ss);
    }
#pragma unroll
    for (int j = DSUB; j < DPAD; ++j) o[j] = 0;
    unsigned short* op = cbb + (size_t)idx * DPAD;
#pragma unroll
    for (int j = 0; j < DPAD / 4; ++j)
        ((ushort4*)op)[j] = make_ushort4(o[j*4], o[j*4+1], o[j*4+2], o[j*4+3]);
    bias[idx] = 0.5f * ss;
}

// ============ PQ argmin via MFMA: block = 128 rows x 256 codewords x one m ==========
__global__ __launch_bounds__(256) void pq_mfma_argmin(
    const unsigned short* __restrict__ subp,   // [NTOT][MSUB*DPAD]
    const unsigned short* __restrict__ cbb,    // [MSUB][KCODE][DPAD]
    const float* __restrict__ bias,            // [MSUB][KCODE]
    unsigned char* __restrict__ codes)         // [NTOT][MSUB]
{
    const int m = blockIdx.y;
    const int row0 = blockIdx.x * 128;
    __shared__ __align__(16) unsigned short As[128 * DPAD];   // 8 KB
    __shared__ __align__(16) unsigned short Bs[KCODE * DPAD]; // 16 KB
    __shared__ __align__(16) float bs[KCODE];                 // 1 KB
    const int tid = threadIdx.x;
    const int wave = tid >> 6, lane = tid & 63;

    {
        const int g = tid;
        const int r = g >> 2, kc = (g & 3) ^ ((r >> 1) & 3);
        gload16(subp + (size_t)(row0 + r) * (MSUB * DPAD) + m * DPAD + kc * 8, &As[g * 8]);
    }
    {
        const int g = tid + 256;
        const int r = g >> 2, kc = (g & 3) ^ ((r >> 1) & 3);
        gload16(subp + (size_t)(row0 + r) * (MSUB * DPAD) + m * DPAD + kc * 8, &As[g * 8]);
    }
#pragma unroll
    for (int i = 0; i < 4; ++i) {
        const int g = tid + i * 256;
        const int r = g >> 2, kc = (g & 3) ^ ((r >> 1) & 3);
        gload16(cbb + (size_t)m * (KCODE * DPAD) + r * DPAD + kc * 8, &Bs[g * 8]);
    }
    if (tid < 64) gload16(bias + m * KCODE + tid * 4, &bs[tid * 4]);
    __syncthreads();

    const int frow = lane & 15, kblk = lane >> 4;
    short8 af[2];
#pragma unroll
    for (int t = 0; t < 2; ++t) {
        const int r = wave * 32 + t * 16 + frow;
        af[t] = *(const short8*)&As[(r * 4 + (kblk ^ ((r >> 1) & 3))) * 8];
    }
    unsigned best[2][4];
#pragma unroll
    for (int t = 0; t < 2; ++t)
#pragma unroll
        for (int r = 0; r < 4; ++r) best[t][r] = 0xFFFFFFFFu;

#pragma unroll
    for (int n = 0; n < 16; ++n) {
        const int br = n * 16 + frow;                 // codeword index for this lane
        const short8 bf = *(const short8*)&Bs[(br * 4 + (kblk ^ ((br >> 1) & 3))) * 8];
        const float bv = bs[br];
        const unsigned kid = (unsigned)br;
        floatx4 a0 = __builtin_amdgcn_mfma_f32_16x16x32_bf16(
            af[0], bf, (floatx4){0.f, 0.f, 0.f, 0.f}, 0, 0, 0);
        floatx4 a1 = __builtin_amdgcn_mfma_f32_16x16x32_bf16(
            af[1], bf, (floatx4){0.f, 0.f, 0.f, 0.f}, 0, 0, 0);
#pragma unroll
        for (int r = 0; r < 4; ++r) {
            const float d0 = bv - a0[r];
            const float d1 = bv - a1[r];
            unsigned u0 = __float_as_uint(d0); u0 ^= (unsigned)((int)u0 >> 31) | 0x80000000u;
            unsigned u1 = __float_as_uint(d1); u1 ^= (unsigned)((int)u1 >> 31) | 0x80000000u;
            best[0][r] = min(best[0][r], (u0 & 0xFFFFFF00u) | kid);
            best[1][r] = min(best[1][r], (u1 & 0xFFFFFF00u) | kid);
        }
    }
#pragma unroll
    for (int off = 1; off <= 8; off <<= 1)
#pragma unroll
        for (int t = 0; t < 2; ++t)
#pragma unroll
            for (int r = 0; r < 4; ++r)
                best[t][r] = min(best[t][r], (unsigned)__shfl_xor((int)best[t][r], off));
    if (frow == 0) {
        const int rbase = row0 + wave * 32 + kblk * 4;
#pragma unroll
        for (int t = 0; t < 2; ++t)
#pragma unroll
            for (int r = 0; r < 4; ++r)
                codes[(size_t)(rbase + t * 16 + r) * MSUB + m] =
                    (unsigned char)(best[t][r] & 0xFFu);
    }
}

// ============ PQ reconstruct: out_bf16 = cb[m][k] + center ============
__global__ __launch_bounds__(256) void pq_recon_kernel(
    const unsigned char* __restrict__ codes, const float* __restrict__ cb,
    const unsigned short* __restrict__ ccb, unsigned short* __restrict__ outb)
{
    const int idx = blockIdx.x * 256 + threadIdx.x;  // n*32+m
    const int n = idx >> 5, m = idx & 31;
    const int k = codes[idx];
    const float* cp = cb + ((size_t)m * KCODE + k) * DSUB;
    const unsigned short* ccp = ccb + (size_t)n * EMB + m * DSUB;
    unsigned short* op = outb + (size_t)n * EMB + m * DSUB;
#pragma unroll
    for (int j = 0; j < 6; ++j) {
        const float4 a = *(const float4*)(cp + j * 4);
        const ushort4 cc = ((const ushort4*)ccp)[j];
        ushort4 o;
        o.x = f2bf(a.x + bf2f(cc.x)); o.y = f2bf(a.y + bf2f(cc.y));
        o.z = f2bf(a.z + bf2f(cc.z)); o.w = f2bf(a.w + bf2f(cc.w));
        ((ushort4*)op)[j] = o;
    }
}

// ============ teacher softmax in-place: T[row][:] -> softmax probs ============
// Block (4 waves) per row; row held in registers (5 float4/thread); 3 shallow passes.
__global__ __launch_bounds__(256) void tprep_kernel(float* __restrict__ T)
{
    const int row = blockIdx.x;
    const int t = threadIdx.x, wid = t >> 6, lane = t & 63;
    float4* t4 = (float4*)(T + (size_t)row * NCOLS);
    float4 v[5];
#pragma unroll
    for (int i = 0; i < 5; ++i) v[i] = t4[t + i * 256];

    __shared__ float redm[4], reds[4];
    float pm = -3.4e38f;
#pragma unroll
    for (int i = 0; i < 5; ++i)
        pm = fmaxf(pm, fmaxf(fmaxf(v[i].x, v[i].y), fmaxf(v[i].z, v[i].w)));
#pragma unroll
    for (int off = 32; off >= 1; off >>= 1) pm = fmaxf(pm, __shfl_xor(pm, off));
    if (lane == 0) redm[wid] = pm;
    __syncthreads();
    const float tm = fmaxf(fmaxf(redm[0], redm[1]), fmaxf(redm[2], redm[3]));

    float ps = 0.f;
#pragma unroll
    for (int i = 0; i < 5; ++i) {
        ps += __builtin_amdgcn_exp2f((v[i].x - tm) * L2E);
        ps += __builtin_amdgcn_exp2f((v[i].y - tm) * L2E);
        ps += __builtin_amdgcn_exp2f((v[i].z - tm) * L2E);
        ps += __builtin_amdgcn_exp2f((v[i].w - tm) * L2E);
    }
#pragma unroll
    for (int off = 32; off >= 1; off >>= 1) ps += __shfl_xor(ps, off);
    if (lane == 0) reds[wid] = ps;
    __syncthreads();
    const float inv = 1.f / (reds[0] + reds[1] + reds[2] + reds[3]);

#pragma unroll
    for (int i = 0; i < 5; ++i) {
        float4 w;
        w.x = __builtin_amdgcn_exp2f((v[i].x - tm) * L2E) * inv;
        w.y = __builtin_amdgcn_exp2f((v[i].y - tm) * L2E) * inv;
        w.z = __builtin_amdgcn_exp2f((v[i].z - tm) * L2E) * inv;
        w.w = __builtin_amdgcn_exp2f((v[i].w - tm) * L2E) * inv;
        t4[t + i * 256] = w;
    }
}

// ============ distill CE loss: block per (row, loss); S + TP in registers ============
__global__ __launch_bounds__(256) void loss3_kernel(
    const float* __restrict__ TP, const float* __restrict__ Sa,
    const float* __restrict__ Sb, const float* __restrict__ Sc,
    float* __restrict__ out, int outoff, float scale)
{
    const int row = blockIdx.x;
    const int ls = blockIdx.y;
    const float* S = (ls == 0) ? Sa : ((ls == 1) ? Sb : Sc);
    const int t = threadIdx.x, wid = t >> 6, lane = t & 63;
    const float4* s4 = (const float4*)(S + (size_t)row * NCOLS);
    const float4* p4 = (const float4*)(TP + (size_t)row * NCOLS);
    float4 v[5], tp[5];
#pragma unroll
    for (int i = 0; i < 5; ++i) { v[i] = s4[t + i * 256]; tp[i] = p4[t + i * 256]; }

    __shared__ float redm[4], reds[4], redl[4];
    // pass A: row max (pure fmax, no exp)
    float pm = -3.4e38f;
#pragma unroll
    for (int i = 0; i < 5; ++i)
        pm = fmaxf(pm, fmaxf(fmaxf(v[i].x, v[i].y), fmaxf(v[i].z, v[i].w)));
#pragma unroll
    for (int off = 32; off >= 1; off >>= 1) pm = fmaxf(pm, __shfl_xor(pm, off));
    if (lane == 0) redm[wid] = pm;
    __syncthreads();
    const float sm = fmaxf(fmaxf(redm[0], redm[1]), fmaxf(redm[2], redm[3]));

    // pass B: sum of exp (independent accumulation)
    float ps = 0.f;
#pragma unroll
    for (int i = 0; i < 5; ++i) {
        ps += __builtin_amdgcn_exp2f((v[i].x - sm) * L2E);
        ps += __builtin_amdgcn_exp2f((v[i].y - sm) * L2E);
        ps += __builtin_amdgcn_exp2f((v[i].z - sm) * L2E);
        ps += __builtin_amdgcn_exp2f((v[i].w - sm) * L2E);
    }
#pragma unroll
    for (int off = 32; off >= 1; off >>= 1) ps += __shfl_xor(ps, off);
    if (lane == 0) reds[wid] = ps;
    __syncthreads();
    const float inv_s = 1.f / (reds[0] + reds[1] + reds[2] + reds[3]);

    // pass C: acc += tp * log2(softmax + 1e-6); loss = -acc*ln2
    float acc = 0.f;
#pragma unroll
    for (int i = 0; i < 5; ++i) {
        acc += tp[i].x * __builtin_amdgcn_logf(
            __builtin_amdgcn_exp2f((v[i].x - sm) * L2E) * inv_s + 1e-6f);
        acc += tp[i].y * __builtin_amdgcn_logf(
            __builtin_amdgcn_exp2f((v[i].y - sm) * L2E) * inv_s + 1e-6f);
        acc += tp[i].z * __builtin_amdgcn_logf(
            __builtin_amdgcn_exp2f((v[i].z - sm) * L2E) * inv_s + 1e-6f);
        acc += tp[i].w * __builtin_amdgcn_logf(
            __builtin_amdgcn_exp2f((v[i].w - sm) * L2E) * inv_s + 1e-6f);
    }
#pragma unroll
    for (int off = 32; off >= 1; off >>= 1) acc += __shfl_xor(acc, off);
    if (lane == 0) redl[wid] = acc;
    __syncthreads();
    if (t == 0) {
        const float loss = -(redl[0] + redl[1] + redl[2] + redl[3]) * LN2 * scale;
        atomicAdd(out + outoff + ls, loss);
    }
}

__global__ void zero_out_kernel(float* __restrict__ out, int n)
{
    if ((int)threadIdx.x < n) out[threadIdx.x] = 0.f;
}

// ============ launch ============
extern "C" void kernel_launch(void* const* d_in, const int* in_sizes, int n_in,
                              void* d_out, int out_size, void* d_ws, size_t ws_size,
                              hipStream_t stream)
{
    const float* q    = (const float*)d_in[0];
    const float* dpos = (const float*)d_in[1];
    const float* nneg = (const float*)d_in[2];
    const float* rot  = (const float*)d_in[3];
    const float* cb   = (const float*)d_in[4];
    const float* ivf  = (const float*)d_in[5];
    const int* doc_ids = (const int*)d_in[6];
    const int* neg_ids = (const int*)d_in[7];
    float* out = (float*)d_out;

    char* p = (char*)d_ws;
    auto take = [&](size_t bytes) { char* r = p; p += (bytes + 255) & ~(size_t)255; return r; };
    unsigned short* qdnb  = (unsigned short*)take((size_t)(NQ + NTOT) * EMB * 2);
    unsigned short* rqdnb = (unsigned short*)take((size_t)(NQ + NTOT) * EMB * 2);
    unsigned short* rotb  = (unsigned short*)take((size_t)EMB * EMB * 2);
    unsigned short* ccb   = (unsigned short*)take((size_t)NTOT * EMB * 2);
    unsigned short* pqb   = (unsigned short*)take((size_t)NTOT * EMB * 2);
    unsigned short* cbb   = (unsigned short*)take((size_t)MSUB * KCODE * DPAD * 2);
    float*          bias  = (float*)take((size_t)MSUB * KCODE * 4);
    unsigned char*  codes = (unsigned char*)take((size_t)NTOT * MSUB);
    float*          T     = (float*)take((size_t)NQ * NCOLS * 4);
    float*          S0    = (float*)take((size_t)NQ * NCOLS * 4);
    float*          S1    = (float*)take((size_t)NQ * NCOLS * 4);
    const size_t used3 = (size_t)(p - (char*)d_ws);
    const bool big = ws_size >= used3 + (size_t)NQ * NCOLS * 4 + 256;
    float* S2 = big ? (float*)take((size_t)NQ * NCOLS * 4) : nullptr;

    // subp (10.5 MB) aliases the last S buffer: consumed by pq_mfma_argmin before
    // any score GEMM writes it.
    unsigned short* subp = (unsigned short*)(big ? (void*)S2 : (void*)S1);

    unsigned short* qb   = qdnb;
    unsigned short* dnb  = qdnb + (size_t)NQ * EMB;
    unsigned short* rqb  = rqdnb;
    unsigned short* rdnb = rqdnb + (size_t)NQ * EMB;

    const float scale = 1.f / NQ;
    zero_out_kernel<<<1, 64, 0, stream>>>(out, out_size);

    // 1) fp32 -> bf16 (+ zero subp pad columns)
    const int cvt4 = (NQ * EMB + NQ * EMB + 4096 * EMB + EMB * EMB) / 4;
    const int z16 = (int)((size_t)NTOT * MSUB * DPAD * 2 / 16);
    cvt_all_kernel<<<(cvt4 + z16 + 255) / 256, 256, 0, stream>>>(
        q, dpos, nneg, rot, qdnb, rotb, (uint4*)subp, z16);

    // 2) IVF gather + codebook prep
    gather_kernel<<<NTOT, EMB / 4, 0, stream>>>(ivf, doc_ids, neg_ids, ccb);
    cbprep_kernel<<<MSUB * KCODE / 256, 256, 0, stream>>>(cb, cbb, bias);

    // 3) rotation: [q;d;n] @ rot^T -> rqdnb bf16; rows >= NQ also subp residual
    gemm_rot<<<dim3(EMB / BNR, (NQ + NTOT) / BMR), 256, 0, stream>>>(
        qdnb, rotb, rqdnb, ccb, subp, EMB, EMB, EMB, EMB);

    // 4) PQ argmin (MFMA) + reconstruct -> pqb
    pq_mfma_argmin<<<dim3(NTOT / 128, MSUB), 256, 0, stream>>>(subp, cbb, bias, codes);
    pq_recon_kernel<<<(NTOT * MSUB) / 256, 256, 0, stream>>>(codes, cb, ccb, pqb);

    if (big) {
        // 5) all four score GEMMs in one z=4 dispatch (1280 blocks, ~5/CU)
        gemm_score4<<<dim3(NTOT / BNS, NQ / BMS, 4), 256, 0, stream>>>(
            qb, dnb, T,  rqb, rdnb, S0,  rqb, ccb, S1,  rqb, pqb, S2);
        // 6) teacher probs in-place, then all three losses (3072 blocks)
        tprep_kernel<<<NQ, 256, 0, stream>>>(T);
        loss3_kernel<<<dim3(NQ, 3), 256, 0, stream>>>(T, S0, S1, S2, out, 0, scale);
    } else {
        // fallback within smaller footprint: T becomes TP after first GEMM pair
        gemm_score4<<<dim3(NTOT / BNS, NQ / BMS, 2), 256, 0, stream>>>(
            qb, dnb, T,  rqb, rdnb, S0,  nullptr, nullptr, nullptr,
            nullptr, nullptr, nullptr);
        tprep_kernel<<<NQ, 256, 0, stream>>>(T);
        loss3_kernel<<<dim3(NQ, 1), 256, 0, stream>>>(T, S0, nullptr, nullptr, out, 0, scale);
        gemm_score4<<<dim3(NTOT / BNS, NQ / BMS, 2), 256, 0, stream>>>(
            rqb, ccb, S0,  rqb, pqb, S1,  nullptr, nullptr, nullptr,
            nullptr, nullptr, nullptr);
        loss3_kernel<<<dim3(NQ, 2), 256, 0, stream>>>(T, S0, S1, nullptr, out, 1, scale);
    }
}

// Round 9
// 173.805 us; speedup vs baseline: 5.7767x; 1.0234x over previous
//
#include <hip/hip_runtime.h>
#include <math.h>

#define EMB 768
#define MSUB 32
#define KCODE 256
#define DSUB 24
#define NQ 1024
#define NTOT 5120    // 1024 docs + 4096 negs
#define NCOLS 5120
#define DPAD 32      // padded subvector dim for MFMA (K=32)
#define L2E 1.4426950408889634f
#define LN2 0.6931471805599453f

typedef __attribute__((ext_vector_type(8))) short short8;
typedef __attribute__((ext_vector_type(4))) float floatx4;

__device__ __forceinline__ unsigned short f2bf(float f) {
    unsigned int u = __float_as_uint(f);
    unsigned int r = (u + 0x7FFFu + ((u >> 16) & 1u)) >> 16;   // RNE
    return (unsigned short)r;
}
__device__ __forceinline__ float bf2f(unsigned short h) {
    return __uint_as_float((unsigned int)h << 16);
}

__device__ __forceinline__ void gload16(const void* g, void* l) {
    __builtin_amdgcn_global_load_lds(
        (const __attribute__((address_space(1))) void*)g,
        (__attribute__((address_space(3))) void*)l, 16, 0, 0);
}

// ============ rotation GEMM: BM=64 x BN=128; 2-phase dbuf pipeline ============
#define BMR 64
#define BNR 128
#define BKG 32
__global__ __launch_bounds__(256) void gemm_rot(
    const unsigned short* __restrict__ A, const unsigned short* __restrict__ B,
    unsigned short* __restrict__ Cb, const unsigned short* __restrict__ ccb,
    unsigned short* __restrict__ subp, int K, int lda, int ldb, int ldcb)
{
    __shared__ __align__(16) unsigned short As[2][BMR * BKG];   // 2 x 4 KB
    __shared__ __align__(16) unsigned short Bs[2][BNR * BKG];   // 2 x 8 KB
    const int tid  = threadIdx.x;
    const int wave = tid >> 6;
    const int lane = tid & 63;
    const int wr = wave >> 1, wc = wave & 1;
    const int row0 = blockIdx.y * BMR;
    const int col0 = blockIdx.x * BNR;

    const int ar  = tid >> 2, aks  = (tid & 3) ^ ((ar >> 1) & 3);
    const unsigned short* Ap = A + (size_t)(row0 + ar) * lda + aks * 8;
    const int br0 = tid >> 2,        bks0 = (tid & 3) ^ ((br0 >> 1) & 3);
    const int br1 = 64 + (tid >> 2), bks1 = (tid & 3) ^ ((br1 >> 1) & 3);
    const unsigned short* Bp0 = B + (size_t)(col0 + br0) * ldb + bks0 * 8;
    const unsigned short* Bp1 = B + (size_t)(col0 + br1) * ldb + bks1 * 8;

    const int frow = lane & 15;
    const int kblk = lane >> 4;
    int aoff[2], boff[4];
#pragma unroll
    for (int m = 0; m < 2; ++m) {
        const int r = wr * 32 + m * 16 + frow;
        aoff[m] = (r * 4 + (kblk ^ ((r >> 1) & 3))) * 8;
    }
#pragma unroll
    for (int n = 0; n < 4; ++n) {
        const int c = wc * 64 + n * 16 + frow;
        boff[n] = (c * 4 + (kblk ^ ((c >> 1) & 3))) * 8;
    }

    floatx4 acc[2][4];
#pragma unroll
    for (int m = 0; m < 2; ++m)
#pragma unroll
        for (int n = 0; n < 4; ++n)
            acc[m][n] = (floatx4){0.f, 0.f, 0.f, 0.f};

    auto STAGE = [&](int buf, int k0) {
        gload16(Ap + k0, &As[buf][tid * 8]);
        gload16(Bp0 + k0, &Bs[buf][tid * 8]);
        gload16(Bp1 + k0, &Bs[buf][(tid + 256) * 8]);
    };

    STAGE(0, 0);
    __syncthreads();                       // compiler drains vmcnt before barrier
    int cur = 0;
    const int NT = K / BKG;
    for (int it = 0; it < NT; ++it) {
        if (it + 1 < NT) STAGE(cur ^ 1, (it + 1) * BKG);   // loads fly under compute
        short8 af[2], bf[4];
#pragma unroll
        for (int m = 0; m < 2; ++m) af[m] = *(const short8*)&As[cur][aoff[m]];
#pragma unroll
        for (int n = 0; n < 4; ++n) bf[n] = *(const short8*)&Bs[cur][boff[n]];
#pragma unroll
        for (int m = 0; m < 2; ++m)
#pragma unroll
            for (int n = 0; n < 4; ++n)
                acc[m][n] = __builtin_amdgcn_mfma_f32_16x16x32_bf16(
                    af[m], bf[n], acc[m][n], 0, 0, 0);
        __syncthreads();                   // one barrier/iter: drains + publishes
        cur ^= 1;
    }

    const int crow = row0 + wr * 32 + (lane >> 4) * 4;
    const int ccol = col0 + wc * 64 + (lane & 15);
#pragma unroll
    for (int m = 0; m < 2; ++m)
#pragma unroll
        for (int n = 0; n < 4; ++n)
#pragma unroll
            for (int r = 0; r < 4; ++r) {
                const int rr = crow + m * 16 + r;
                const int cc = ccol + n * 16;
                const float v = acc[m][n][r];
                Cb[(size_t)rr * ldcb + cc] = f2bf(v);
                if (rr >= NQ) {
                    const int nn = rr - NQ;
                    const float cen = bf2f(ccb[(size_t)nn * EMB + cc]);
                    const unsigned mm = (unsigned)cc / 24u;
                    const unsigned jj = (unsigned)cc - mm * 24u;
                    subp[(size_t)nn * (MSUB * DPAD) + mm * DPAD + jj] = f2bf(v - cen);
                }
            }
}

// ============ z-batched score GEMM: 128x128, 2-phase dbuf pipeline ============
#define BMS 128
#define BNS 128
__global__ __launch_bounds__(256) void gemm_score4(
    const unsigned short* __restrict__ A0, const unsigned short* __restrict__ B0, float* __restrict__ C0,
    const unsigned short* __restrict__ A1, const unsigned short* __restrict__ B1, float* __restrict__ C1,
    const unsigned short* __restrict__ A2, const unsigned short* __restrict__ B2, float* __restrict__ C2,
    const unsigned short* __restrict__ A3, const unsigned short* __restrict__ B3, float* __restrict__ C3)
{
    const unsigned short* A; const unsigned short* B; float* C;
    switch (blockIdx.z) {
        case 0:  A = A0; B = B0; C = C0; break;
        case 1:  A = A1; B = B1; C = C1; break;
        case 2:  A = A2; B = B2; C = C2; break;
        default: A = A3; B = B3; C = C3; break;
    }

    __shared__ __align__(16) unsigned short As[2][BMS * BKG];   // 2 x 8 KB
    __shared__ __align__(16) unsigned short Bs[2][BNS * BKG];   // 2 x 8 KB
    const int tid  = threadIdx.x;
    const int wave = tid >> 6;
    const int lane = tid & 63;
    const int wr = wave >> 1, wc = wave & 1;
    const int row0 = blockIdx.y * BMS;
    const int col0 = blockIdx.x * BNS;

    const int g0 = tid, g1 = tid + 256;
    const int ar0 = g0 >> 2, as0 = (g0 & 3) ^ ((ar0 >> 1) & 3);
    const int ar1 = g1 >> 2, as1 = (g1 & 3) ^ ((ar1 >> 1) & 3);
    const unsigned short* Ap0 = A + (size_t)(row0 + ar0) * EMB + as0 * 8;
    const unsigned short* Ap1 = A + (size_t)(row0 + ar1) * EMB + as1 * 8;
    const unsigned short* Bp0 = B + (size_t)(col0 + ar0) * EMB + as0 * 8;
    const unsigned short* Bp1 = B + (size_t)(col0 + ar1) * EMB + as1 * 8;

    const int frow = lane & 15;
    const int kblk = lane >> 4;
    int aoff[4], boff[4];
#pragma unroll
    for (int m = 0; m < 4; ++m) {
        const int r = wr * 64 + m * 16 + frow;
        aoff[m] = (r * 4 + (kblk ^ ((r >> 1) & 3))) * 8;
        const int c = wc * 64 + m * 16 + frow;
        boff[m] = (c * 4 + (kblk ^ ((c >> 1) & 3))) * 8;
    }

    floatx4 acc[4][4];
#pragma unroll
    for (int m = 0; m < 4; ++m)
#pragma unroll
        for (int n = 0; n < 4; ++n)
            acc[m][n] = (floatx4){0.f, 0.f, 0.f, 0.f};

    auto STAGE = [&](int buf, int k0) {
        gload16(Ap0 + k0, &As[buf][g0 * 8]);
        gload16(Ap1 + k0, &As[buf][g1 * 8]);
        gload16(Bp0 + k0, &Bs[buf][g0 * 8]);
        gload16(Bp1 + k0, &Bs[buf][g1 * 8]);
    };

    STAGE(0, 0);
    __syncthreads();
    int cur = 0;
    const int NT = EMB / BKG;
    for (int it = 0; it < NT; ++it) {
        if (it + 1 < NT) STAGE(cur ^ 1, (it + 1) * BKG);
        short8 af[4], bf[4];
#pragma unroll
        for (int m = 0; m < 4; ++m) af[m] = *(const short8*)&As[cur][aoff[m]];
#pragma unroll
        for (int n = 0; n < 4; ++n) bf[n] = *(const short8*)&Bs[cur][boff[n]];
#pragma unroll
        for (int m = 0; m < 4; ++m)
#pragma unroll
            for (int n = 0; n < 4; ++n)
                acc[m][n] = __builtin_amdgcn_mfma_f32_16x16x32_bf16(
                    af[m], bf[n], acc[m][n], 0, 0, 0);
        __syncthreads();
        cur ^= 1;
    }

    const int crow = row0 + wr * 64 + (lane >> 4) * 4;
    const int ccol = col0 + wc * 64 + (lane & 15);
#pragma unroll
    for (int m = 0; m < 4; ++m)
#pragma unroll
        for (int n = 0; n < 4; ++n)
#pragma unroll
            for (int r = 0; r < 4; ++r)
                C[(size_t)(crow + m * 16 + r) * NCOLS + ccol + n * 16] = acc[m][n][r];
}

// ============ fused fp32 -> bf16 conversion + subp pad zeroing ============
__global__ __launch_bounds__(256) void cvt_all_kernel(
    const float* __restrict__ q, const float* __restrict__ d,
    const float* __restrict__ n, const float* __restrict__ rot,
    unsigned short* __restrict__ qdnb, unsigned short* __restrict__ rotb,
    uint4* __restrict__ zdst, int zcount)
{
    const int i = blockIdx.x * 256 + threadIdx.x;  // 16B work-item index
    const int S1 = NQ * EMB / 4;
    const int S2 = S1 + NQ * EMB / 4;
    const int S3 = S2 + 4096 * EMB / 4;
    const int S4 = S3 + EMB * EMB / 4;
    if (i >= S4) {
        const int z = i - S4;
        if (z < zcount) zdst[z] = make_uint4(0u, 0u, 0u, 0u);
        return;
    }
    const float* src; unsigned short* dst; int off;
    if (i < S1)      { src = q;   dst = qdnb;                          off = i; }
    else if (i < S2) { src = d;   dst = qdnb + (size_t)NQ * EMB;       off = i - S1; }
    else if (i < S3) { src = n;   dst = qdnb + (size_t)2 * NQ * EMB;   off = i - S2; }
    else             { src = rot; dst = rotb;                          off = i - S3; }
    const float4 v = ((const float4*)src)[off];
    ushort4 b;
    b.x = f2bf(v.x); b.y = f2bf(v.y); b.z = f2bf(v.z); b.w = f2bf(v.w);
    ((ushort4*)dst)[off] = b;
}

// ============ IVF gather (bf16) ============
__global__ void gather_kernel(const float* __restrict__ centers,
                              const int* __restrict__ doc_ids,
                              const int* __restrict__ neg_ids,
                              unsigned short* __restrict__ outb)
{
    const int i = blockIdx.x;
    const int id = (i < NQ) ? doc_ids[i] : neg_ids[i - NQ];
    const int t = threadIdx.x;
    const float4 v = ((const float4*)(centers + (size_t)id * EMB))[t];
    ushort4 b;
    b.x = f2bf(v.x); b.y = f2bf(v.y); b.z = f2bf(v.z); b.w = f2bf(v.w);
    ((ushort4*)(outb + (size_t)i * EMB))[t] = b;
}

// ============ codebook prep: padded bf16 + 0.5*||c||^2 bias ============
__global__ __launch_bounds__(256) void cbprep_kernel(
    const float* __restrict__ cb, unsigned short* __restrict__ cbb,
    float* __restrict__ bias)
{
    const int idx = blockIdx.x * 256 + threadIdx.x;  // m*256 + k  (8192 total)
    const float* cp = cb + (size_t)idx * DSUB;
    unsigned short o[DPAD];
    float ss = 0.f;
#pragma unroll
    for (int j = 0; j < 6; ++j) {
        const float4 v = *(const float4*)(cp + j * 4);
        o[j * 4 + 0] = f2bf(v.x); o[j * 4 + 1] = f2bf(v.y);
        o[j * 4 + 2] = f2bf(v.z); o[j * 4 + 3] = f2bf(v.w);
        ss = fmaf(v.x, v.x, ss); ss = fmaf(v.y, v.y, ss);
        ss = fmaf(v.z, v.z, ss); ss = fmaf(v.w, v.w, ss);
    }
#pragma unroll
    for (int j = DSUB; j < DPAD; ++j) o[j] = 0;
    unsigned short* op = cbb + (size_t)idx * DPAD;
#pragma unroll
    for (int j = 0; j < DPAD / 4; ++j)
        ((ushort4*)op)[j] = make_ushort4(o[j*4], o[j*4+1], o[j*4+2], o[j*4+3]);
    bias[idx] = 0.5f * ss;
}

// ============ PQ argmin via MFMA: block = 128 rows x 256 codewords x one m ==========
__global__ __launch_bounds__(256) void pq_mfma_argmin(
    const unsigned short* __restrict__ subp,   // [NTOT][MSUB*DPAD]
    const unsigned short* __restrict__ cbb,    // [MSUB][KCODE][DPAD]
    const float* __restrict__ bias,            // [MSUB][KCODE]
    unsigned char* __restrict__ codes)         // [NTOT][MSUB]
{
    const int m = blockIdx.y;
    const int row0 = blockIdx.x * 128;
    __shared__ __align__(16) unsigned short As[128 * DPAD];   // 8 KB
    __shared__ __align__(16) unsigned short Bs[KCODE * DPAD]; // 16 KB
    __shared__ __align__(16) float bs[KCODE];                 // 1 KB
    const int tid = threadIdx.x;
    const int wave = tid >> 6, lane = tid & 63;

    {
        const int g = tid;
        const int r = g >> 2, kc = (g & 3) ^ ((r >> 1) & 3);
        gload16(subp + (size_t)(row0 + r) * (MSUB * DPAD) + m * DPAD + kc * 8, &As[g * 8]);
    }
    {
        const int g = tid + 256;
        const int r = g >> 2, kc = (g & 3) ^ ((r >> 1) & 3);
        gload16(subp + (size_t)(row0 + r) * (MSUB * DPAD) + m * DPAD + kc * 8, &As[g * 8]);
    }
#pragma unroll
    for (int i = 0; i < 4; ++i) {
        const int g = tid + i * 256;
        const int r = g >> 2, kc = (g & 3) ^ ((r >> 1) & 3);
        gload16(cbb + (size_t)m * (KCODE * DPAD) + r * DPAD + kc * 8, &Bs[g * 8]);
    }
    if (tid < 64) gload16(bias + m * KCODE + tid * 4, &bs[tid * 4]);
    __syncthreads();

    const int frow = lane & 15, kblk = lane >> 4;
    short8 af[2];
#pragma unroll
    for (int t = 0; t < 2; ++t) {
        const int r = wave * 32 + t * 16 + frow;
        af[t] = *(const short8*)&As[(r * 4 + (kblk ^ ((r >> 1) & 3))) * 8];
    }
    unsigned best[2][4];
#pragma unroll
    for (int t = 0; t < 2; ++t)
#pragma unroll
        for (int r = 0; r < 4; ++r) best[t][r] = 0xFFFFFFFFu;

#pragma unroll
    for (int n = 0; n < 16; ++n) {
        const int br = n * 16 + frow;                 // codeword index for this lane
        const short8 bf = *(const short8*)&Bs[(br * 4 + (kblk ^ ((br >> 1) & 3))) * 8];
        const float bv = bs[br];
        const unsigned kid = (unsigned)br;
        floatx4 a0 = __builtin_amdgcn_mfma_f32_16x16x32_bf16(
            af[0], bf, (floatx4){0.f, 0.f, 0.f, 0.f}, 0, 0, 0);
        floatx4 a1 = __builtin_amdgcn_mfma_f32_16x16x32_bf16(
            af[1], bf, (floatx4){0.f, 0.f, 0.f, 0.f}, 0, 0, 0);
#pragma unroll
        for (int r = 0; r < 4; ++r) {
            const float d0 = bv - a0[r];
            const float d1 = bv - a1[r];
            unsigned u0 = __float_as_uint(d0); u0 ^= (unsigned)((int)u0 >> 31) | 0x80000000u;
            unsigned u1 = __float_as_uint(d1); u1 ^= (unsigned)((int)u1 >> 31) | 0x80000000u;
            best[0][r] = min(best[0][r], (u0 & 0xFFFFFF00u) | kid);
            best[1][r] = min(best[1][r], (u1 & 0xFFFFFF00u) | kid);
        }
    }
#pragma unroll
    for (int off = 1; off <= 8; off <<= 1)
#pragma unroll
        for (int t = 0; t < 2; ++t)
#pragma unroll
            for (int r = 0; r < 4; ++r)
                best[t][r] = min(best[t][r], (unsigned)__shfl_xor((int)best[t][r], off));
    if (frow == 0) {
        const int rbase = row0 + wave * 32 + kblk * 4;
#pragma unroll
        for (int t = 0; t < 2; ++t)
#pragma unroll
            for (int r = 0; r < 4; ++r)
                codes[(size_t)(rbase + t * 16 + r) * MSUB + m] =
                    (unsigned char)(best[t][r] & 0xFFu);
    }
}

// ============ PQ reconstruct: out_bf16 = cb[m][k] + center ============
__global__ __launch_bounds__(256) void pq_recon_kernel(
    const unsigned char* __restrict__ codes, const float* __restrict__ cb,
    const unsigned short* __restrict__ ccb, unsigned short* __restrict__ outb)
{
    const int idx = blockIdx.x * 256 + threadIdx.x;  // n*32+m
    const int n = idx >> 5, m = idx & 31;
    const int k = codes[idx];
    const float* cp = cb + ((size_t)m * KCODE + k) * DSUB;
    const unsigned short* ccp = ccb + (size_t)n * EMB + m * DSUB;
    unsigned short* op = outb + (size_t)n * EMB + m * DSUB;
#pragma unroll
    for (int j = 0; j < 6; ++j) {
        const float4 a = *(const float4*)(cp + j * 4);
        const ushort4 cc = ((const ushort4*)ccp)[j];
        ushort4 o;
        o.x = f2bf(a.x + bf2f(cc.x)); o.y = f2bf(a.y + bf2f(cc.y));
        o.z = f2bf(a.z + bf2f(cc.z)); o.w = f2bf(a.w + bf2f(cc.w));
        ((ushort4*)op)[j] = o;
    }
}

// ============ teacher softmax in-place: T[row][:] -> softmax probs ============
__global__ __launch_bounds__(256) void tprep_kernel(float* __restrict__ T)
{
    const int row = blockIdx.x;
    const int t = threadIdx.x, wid = t >> 6, lane = t & 63;
    float4* t4 = (float4*)(T + (size_t)row * NCOLS);
    float4 v[5];
#pragma unroll
    for (int i = 0; i < 5; ++i) v[i] = t4[t + i * 256];

    __shared__ float redm[4], reds[4];
    float pm = -3.4e38f;
#pragma unroll
    for (int i = 0; i < 5; ++i)
        pm = fmaxf(pm, fmaxf(fmaxf(v[i].x, v[i].y), fmaxf(v[i].z, v[i].w)));
#pragma unroll
    for (int off = 32; off >= 1; off >>= 1) pm = fmaxf(pm, __shfl_xor(pm, off));
    if (lane == 0) redm[wid] = pm;
    __syncthreads();
    const float tm = fmaxf(fmaxf(redm[0], redm[1]), fmaxf(redm[2], redm[3]));

    float ps = 0.f;
#pragma unroll
    for (int i = 0; i < 5; ++i) {
        ps += __builtin_amdgcn_exp2f((v[i].x - tm) * L2E);
        ps += __builtin_amdgcn_exp2f((v[i].y - tm) * L2E);
        ps += __builtin_amdgcn_exp2f((v[i].z - tm) * L2E);
        ps += __builtin_amdgcn_exp2f((v[i].w - tm) * L2E);
    }
#pragma unroll
    for (int off = 32; off >= 1; off >>= 1) ps += __shfl_xor(ps, off);
    if (lane == 0) reds[wid] = ps;
    __syncthreads();
    const float inv = 1.f / (reds[0] + reds[1] + reds[2] + reds[3]);

#pragma unroll
    for (int i = 0; i < 5; ++i) {
        float4 w;
        w.x = __builtin_amdgcn_exp2f((v[i].x - tm) * L2E) * inv;
        w.y = __builtin_amdgcn_exp2f((v[i].y - tm) * L2E) * inv;
        w.z = __builtin_amdgcn_exp2f((v[i].z - tm) * L2E) * inv;
        w.w = __builtin_amdgcn_exp2f((v[i].w - tm) * L2E) * inv;
        t4[t + i * 256] = w;
    }
}

// ============ distill CE loss: block per (row, loss); S + TP in registers ============
__global__ __launch_bounds__(256) void loss3_kernel(
    const float* __restrict__ TP, const float* __restrict__ Sa,
    const float* __restrict__ Sb, const float* __restrict__ Sc,
    float* __restrict__ out, int outoff, float scale)
{
    const int row = blockIdx.x;
    const int ls = blockIdx.y;
    const float* S = (ls == 0) ? Sa : ((ls == 1) ? Sb : Sc);
    const int t = threadIdx.x, wid = t >> 6, lane = t & 63;
    const float4* s4 = (const float4*)(S + (size_t)row * NCOLS);
    const float4* p4 = (const float4*)(TP + (size_t)row * NCOLS);
    float4 v[5], tp[5];
#pragma unroll
    for (int i = 0; i < 5; ++i) { v[i] = s4[t + i * 256]; tp[i] = p4[t + i * 256]; }

    __shared__ float redm[4], reds[4], redl[4];
    float pm = -3.4e38f;
#pragma unroll
    for (int i = 0; i < 5; ++i)
        pm = fmaxf(pm, fmaxf(fmaxf(v[i].x, v[i].y), fmaxf(v[i].z, v[i].w)));
#pragma unroll
    for (int off = 32; off >= 1; off >>= 1) pm = fmaxf(pm, __shfl_xor(pm, off));
    if (lane == 0) redm[wid] = pm;
    __syncthreads();
    const float sm = fmaxf(fmaxf(redm[0], redm[1]), fmaxf(redm[2], redm[3]));

    float ps = 0.f;
#pragma unroll
    for (int i = 0; i < 5; ++i) {
        ps += __builtin_amdgcn_exp2f((v[i].x - sm) * L2E);
        ps += __builtin_amdgcn_exp2f((v[i].y - sm) * L2E);
        ps += __builtin_amdgcn_exp2f((v[i].z - sm) * L2E);
        ps += __builtin_amdgcn_exp2f((v[i].w - sm) * L2E);
    }
#pragma unroll
    for (int off = 32; off >= 1; off >>= 1) ps += __shfl_xor(ps, off);
    if (lane == 0) reds[wid] = ps;
    __syncthreads();
    const float inv_s = 1.f / (reds[0] + reds[1] + reds[2] + reds[3]);

    float acc = 0.f;
#pragma unroll
    for (int i = 0; i < 5; ++i) {
        acc += tp[i].x * __builtin_amdgcn_logf(
            __builtin_amdgcn_exp2f((v[i].x - sm) * L2E) * inv_s + 1e-6f);
        acc += tp[i].y * __builtin_amdgcn_logf(
            __builtin_amdgcn_exp2f((v[i].y - sm) * L2E) * inv_s + 1e-6f);
        acc += tp[i].z * __builtin_amdgcn_logf(
            __builtin_amdgcn_exp2f((v[i].z - sm) * L2E) * inv_s + 1e-6f);
        acc += tp[i].w * __builtin_amdgcn_logf(
            __builtin_amdgcn_exp2f((v[i].w - sm) * L2E) * inv_s + 1e-6f);
    }
#pragma unroll
    for (int off = 32; off >= 1; off >>= 1) acc += __shfl_xor(acc, off);
    if (lane == 0) redl[wid] = acc;
    __syncthreads();
    if (t == 0) {
        const float loss = -(redl[0] + redl[1] + redl[2] + redl[3]) * LN2 * scale;
        atomicAdd(out + outoff + ls, loss);
    }
}

__global__ void zero_out_kernel(float* __restrict__ out, int n)
{
    if ((int)threadIdx.x < n) out[threadIdx.x] = 0.f;
}

// ============ launch ============
extern "C" void kernel_launch(void* const* d_in, const int* in_sizes, int n_in,
                              void* d_out, int out_size, void* d_ws, size_t ws_size,
                              hipStream_t stream)
{
    const float* q    = (const float*)d_in[0];
    const float* dpos = (const float*)d_in[1];
    const float* nneg = (const float*)d_in[2];
    const float* rot  = (const float*)d_in[3];
    const float* cb   = (const float*)d_in[4];
    const float* ivf  = (const float*)d_in[5];
    const int* doc_ids = (const int*)d_in[6];
    const int* neg_ids = (const int*)d_in[7];
    float* out = (float*)d_out;

    char* p = (char*)d_ws;
    auto take = [&](size_t bytes) { char* r = p; p += (bytes + 255) & ~(size_t)255; return r; };
    unsigned short* qdnb  = (unsigned short*)take((size_t)(NQ + NTOT) * EMB * 2);
    unsigned short* rqdnb = (unsigned short*)take((size_t)(NQ + NTOT) * EMB * 2);
    unsigned short* rotb  = (unsigned short*)take((size_t)EMB * EMB * 2);
    unsigned short* ccb   = (unsigned short*)take((size_t)NTOT * EMB * 2);
    unsigned short* pqb   = (unsigned short*)take((size_t)NTOT * EMB * 2);
    unsigned short* cbb   = (unsigned short*)take((size_t)MSUB * KCODE * DPAD * 2);
    float*          bias  = (float*)take((size_t)MSUB * KCODE * 4);
    unsigned char*  codes = (unsigned char*)take((size_t)NTOT * MSUB);
    float*          T     = (float*)take((size_t)NQ * NCOLS * 4);
    float*          S0    = (float*)take((size_t)NQ * NCOLS * 4);
    float*          S1    = (float*)take((size_t)NQ * NCOLS * 4);
    const size_t used3 = (size_t)(p - (char*)d_ws);
    const bool big = ws_size >= used3 + (size_t)NQ * NCOLS * 4 + 256;
    float* S2 = big ? (float*)take((size_t)NQ * NCOLS * 4) : nullptr;

    // subp (10.5 MB) aliases the last S buffer: consumed by pq_mfma_argmin before
    // any score GEMM writes it.
    unsigned short* subp = (unsigned short*)(big ? (void*)S2 : (void*)S1);

    unsigned short* qb   = qdnb;
    unsigned short* dnb  = qdnb + (size_t)NQ * EMB;
    unsigned short* rqb  = rqdnb;
    unsigned short* rdnb = rqdnb + (size_t)NQ * EMB;

    const float scale = 1.f / NQ;
    zero_out_kernel<<<1, 64, 0, stream>>>(out, out_size);

    // 1) fp32 -> bf16 (+ zero subp pad columns)
    const int cvt4 = (NQ * EMB + NQ * EMB + 4096 * EMB + EMB * EMB) / 4;
    const int z16 = (int)((size_t)NTOT * MSUB * DPAD * 2 / 16);
    cvt_all_kernel<<<(cvt4 + z16 + 255) / 256, 256, 0, stream>>>(
        q, dpos, nneg, rot, qdnb, rotb, (uint4*)subp, z16);

    // 2) IVF gather + codebook prep
    gather_kernel<<<NTOT, EMB / 4, 0, stream>>>(ivf, doc_ids, neg_ids, ccb);
    cbprep_kernel<<<MSUB * KCODE / 256, 256, 0, stream>>>(cb, cbb, bias);

    // 3) rotation: [q;d;n] @ rot^T -> rqdnb bf16; rows >= NQ also subp residual
    gemm_rot<<<dim3(EMB / BNR, (NQ + NTOT) / BMR), 256, 0, stream>>>(
        qdnb, rotb, rqdnb, ccb, subp, EMB, EMB, EMB, EMB);

    // 4) PQ argmin (MFMA) + reconstruct -> pqb
    pq_mfma_argmin<<<dim3(NTOT / 128, MSUB), 256, 0, stream>>>(subp, cbb, bias, codes);
    pq_recon_kernel<<<(NTOT * MSUB) / 256, 256, 0, stream>>>(codes, cb, ccb, pqb);

    if (big) {
        // 5) all four score GEMMs in one z=4 dispatch
        gemm_score4<<<dim3(NTOT / BNS, NQ / BMS, 4), 256, 0, stream>>>(
            qb, dnb, T,  rqb, rdnb, S0,  rqb, ccb, S1,  rqb, pqb, S2);
        // 6) teacher probs in-place, then all three losses
        tprep_kernel<<<NQ, 256, 0, stream>>>(T);
        loss3_kernel<<<dim3(NQ, 3), 256, 0, stream>>>(T, S0, S1, S2, out, 0, scale);
    } else {
        gemm_score4<<<dim3(NTOT / BNS, NQ / BMS, 2), 256, 0, stream>>>(
            qb, dnb, T,  rqb, rdnb, S0,  nullptr, nullptr, nullptr,
            nullptr, nullptr, nullptr);
        tprep_kernel<<<NQ, 256, 0, stream>>>(T);
        loss3_kernel<<<dim3(NQ, 1), 256, 0, stream>>>(T, S0, nullptr, nullptr, out, 0, scale);
        gemm_score4<<<dim3(NTOT / BNS, NQ / BMS, 2), 256, 0, stream>>>(
            rqb, ccb, S0,  rqb, pqb, S1,  nullptr, nullptr, nullptr,
            nullptr, nullptr, nullptr);
        loss3_kernel<<<dim3(NQ, 2), 256, 0, stream>>>(T, S0, S1, nullptr, out, 1, scale);
    }
}

// Round 10
// 160.512 us; speedup vs baseline: 6.2551x; 1.0828x over previous
//
#include <hip/hip_runtime.h>
#include <math.h>

#define EMB 768
#define MSUB 32
#define KCODE 256
#define DSUB 24
#define NQ 1024
#define NTOT 5120    // 1024 docs + 4096 negs
#define NCOLS 5120
#define DPAD 32      // padded subvector dim for MFMA (K=32)
#define L2E 1.4426950408889634f
#define LN2 0.6931471805599453f

typedef __attribute__((ext_vector_type(8))) short short8;
typedef __attribute__((ext_vector_type(4))) float floatx4;

__device__ __forceinline__ unsigned short f2bf(float f) {
    unsigned int u = __float_as_uint(f);
    unsigned int r = (u + 0x7FFFu + ((u >> 16) & 1u)) >> 16;   // RNE
    return (unsigned short)r;
}
__device__ __forceinline__ float bf2f(unsigned short h) {
    return __uint_as_float((unsigned int)h << 16);
}

__device__ __forceinline__ void gload16(const void* g, void* l) {
    __builtin_amdgcn_global_load_lds(
        (const __attribute__((address_space(1))) void*)g,
        (__attribute__((address_space(3))) void*)l, 16, 0, 0);
}

// ============ rotation GEMM: BM=64 x BN=128; 3-buffer counted-vmcnt pipeline ========
// Per iter: waitcnt(my 3 loads for cur done) -> raw barrier -> STAGE(cur+2) -> compute.
// Two tiles in flight across barriers (T3+T4 minimum form).
#define BMR 64
#define BNR 128
#define BKG 32
__global__ __launch_bounds__(256) void gemm_rot(
    const unsigned short* __restrict__ A, const unsigned short* __restrict__ B,
    unsigned short* __restrict__ Cb, const unsigned short* __restrict__ ccb,
    unsigned short* __restrict__ subp, int K, int lda, int ldb, int ldcb)
{
    __shared__ __align__(16) unsigned short As[3][BMR * BKG];   // 3 x 4 KB
    __shared__ __align__(16) unsigned short Bs[3][BNR * BKG];   // 3 x 8 KB
    const int tid  = threadIdx.x;
    const int wave = tid >> 6;
    const int lane = tid & 63;
    const int wr = wave >> 1, wc = wave & 1;
    const int row0 = blockIdx.y * BMR;
    const int col0 = blockIdx.x * BNR;

    const int ar  = tid >> 2, aks  = (tid & 3) ^ ((ar >> 1) & 3);
    const unsigned short* Ap = A + (size_t)(row0 + ar) * lda + aks * 8;
    const int br0 = tid >> 2,        bks0 = (tid & 3) ^ ((br0 >> 1) & 3);
    const int br1 = 64 + (tid >> 2), bks1 = (tid & 3) ^ ((br1 >> 1) & 3);
    const unsigned short* Bp0 = B + (size_t)(col0 + br0) * ldb + bks0 * 8;
    const unsigned short* Bp1 = B + (size_t)(col0 + br1) * ldb + bks1 * 8;

    const int frow = lane & 15;
    const int kblk = lane >> 4;
    int aoff[2], boff[4];
#pragma unroll
    for (int m = 0; m < 2; ++m) {
        const int r = wr * 32 + m * 16 + frow;
        aoff[m] = (r * 4 + (kblk ^ ((r >> 1) & 3))) * 8;
    }
#pragma unroll
    for (int n = 0; n < 4; ++n) {
        const int c = wc * 64 + n * 16 + frow;
        boff[n] = (c * 4 + (kblk ^ ((c >> 1) & 3))) * 8;
    }

    floatx4 acc[2][4];
#pragma unroll
    for (int m = 0; m < 2; ++m)
#pragma unroll
        for (int n = 0; n < 4; ++n)
            acc[m][n] = (floatx4){0.f, 0.f, 0.f, 0.f};

    auto STAGE = [&](int buf, int k0) {
        gload16(Ap + k0, &As[buf][tid * 8]);
        gload16(Bp0 + k0, &Bs[buf][tid * 8]);
        gload16(Bp1 + k0, &Bs[buf][(tid + 256) * 8]);
    };

    const int NT = K / BKG;
    STAGE(0, 0);
    STAGE(1, BKG);
    int cur = 0;
    for (int it = 0; it < NT; ++it) {
        if (it < NT - 1) asm volatile("s_waitcnt vmcnt(3)" ::: "memory");
        else             asm volatile("s_waitcnt vmcnt(0)" ::: "memory");
        __builtin_amdgcn_s_barrier();      // raw: does NOT drain in-flight prefetch
        asm volatile("" ::: "memory");
        if (it + 2 < NT) {
            int nb = cur + 2; if (nb >= 3) nb -= 3;
            STAGE(nb, (it + 2) * BKG);     // overwrites buffer read at it-1 (barrier-safe)
        }
        short8 af[2], bf[4];
#pragma unroll
        for (int m = 0; m < 2; ++m) af[m] = *(const short8*)&As[cur][aoff[m]];
#pragma unroll
        for (int n = 0; n < 4; ++n) bf[n] = *(const short8*)&Bs[cur][boff[n]];
#pragma unroll
        for (int m = 0; m < 2; ++m)
#pragma unroll
            for (int n = 0; n < 4; ++n)
                acc[m][n] = __builtin_amdgcn_mfma_f32_16x16x32_bf16(
                    af[m], bf[n], acc[m][n], 0, 0, 0);
        ++cur; if (cur == 3) cur = 0;
    }

    const int crow = row0 + wr * 32 + (lane >> 4) * 4;
    const int ccol = col0 + wc * 64 + (lane & 15);
#pragma unroll
    for (int m = 0; m < 2; ++m)
#pragma unroll
        for (int n = 0; n < 4; ++n)
#pragma unroll
            for (int r = 0; r < 4; ++r) {
                const int rr = crow + m * 16 + r;
                const int cc = ccol + n * 16;
                const float v = acc[m][n][r];
                Cb[(size_t)rr * ldcb + cc] = f2bf(v);
                if (rr >= NQ) {
                    const int nn = rr - NQ;
                    const float cen = bf2f(ccb[(size_t)nn * EMB + cc]);
                    const unsigned mm = (unsigned)cc / 24u;
                    const unsigned jj = (unsigned)cc - mm * 24u;
                    subp[(size_t)nn * (MSUB * DPAD) + mm * DPAD + jj] = f2bf(v - cen);
                }
            }
}

// ============ z-batched score GEMM: 128x128, 3-buffer counted-vmcnt, bf16 out =======
#define BMS 128
#define BNS 128
__global__ __launch_bounds__(256) void gemm_score4(
    const unsigned short* __restrict__ A0, const unsigned short* __restrict__ B0, unsigned short* __restrict__ C0,
    const unsigned short* __restrict__ A1, const unsigned short* __restrict__ B1, unsigned short* __restrict__ C1,
    const unsigned short* __restrict__ A2, const unsigned short* __restrict__ B2, unsigned short* __restrict__ C2,
    const unsigned short* __restrict__ A3, const unsigned short* __restrict__ B3, unsigned short* __restrict__ C3)
{
    const unsigned short* A; const unsigned short* B; unsigned short* C;
    switch (blockIdx.z) {
        case 0:  A = A0; B = B0; C = C0; break;
        case 1:  A = A1; B = B1; C = C1; break;
        case 2:  A = A2; B = B2; C = C2; break;
        default: A = A3; B = B3; C = C3; break;
    }

    __shared__ __align__(16) unsigned short As[3][BMS * BKG];   // 3 x 8 KB
    __shared__ __align__(16) unsigned short Bs[3][BNS * BKG];   // 3 x 8 KB
    const int tid  = threadIdx.x;
    const int wave = tid >> 6;
    const int lane = tid & 63;
    const int wr = wave >> 1, wc = wave & 1;
    const int row0 = blockIdx.y * BMS;
    const int col0 = blockIdx.x * BNS;

    const int g0 = tid, g1 = tid + 256;
    const int ar0 = g0 >> 2, as0 = (g0 & 3) ^ ((ar0 >> 1) & 3);
    const int ar1 = g1 >> 2, as1 = (g1 & 3) ^ ((ar1 >> 1) & 3);
    const unsigned short* Ap0 = A + (size_t)(row0 + ar0) * EMB + as0 * 8;
    const unsigned short* Ap1 = A + (size_t)(row0 + ar1) * EMB + as1 * 8;
    const unsigned short* Bp0 = B + (size_t)(col0 + ar0) * EMB + as0 * 8;
    const unsigned short* Bp1 = B + (size_t)(col0 + ar1) * EMB + as1 * 8;

    const int frow = lane & 15;
    const int kblk = lane >> 4;
    int aoff[4], boff[4];
#pragma unroll
    for (int m = 0; m < 4; ++m) {
        const int r = wr * 64 + m * 16 + frow;
        aoff[m] = (r * 4 + (kblk ^ ((r >> 1) & 3))) * 8;
        const int c = wc * 64 + m * 16 + frow;
        boff[m] = (c * 4 + (kblk ^ ((c >> 1) & 3))) * 8;
    }

    floatx4 acc[4][4];
#pragma unroll
    for (int m = 0; m < 4; ++m)
#pragma unroll
        for (int n = 0; n < 4; ++n)
            acc[m][n] = (floatx4){0.f, 0.f, 0.f, 0.f};

    auto STAGE = [&](int buf, int k0) {
        gload16(Ap0 + k0, &As[buf][g0 * 8]);
        gload16(Ap1 + k0, &As[buf][g1 * 8]);
        gload16(Bp0 + k0, &Bs[buf][g0 * 8]);
        gload16(Bp1 + k0, &Bs[buf][g1 * 8]);
    };

    const int NT = EMB / BKG;
    STAGE(0, 0);
    STAGE(1, BKG);
    int cur = 0;
    for (int it = 0; it < NT; ++it) {
        if (it < NT - 1) asm volatile("s_waitcnt vmcnt(4)" ::: "memory");
        else             asm volatile("s_waitcnt vmcnt(0)" ::: "memory");
        __builtin_amdgcn_s_barrier();
        asm volatile("" ::: "memory");
        if (it + 2 < NT) {
            int nb = cur + 2; if (nb >= 3) nb -= 3;
            STAGE(nb, (it + 2) * BKG);
        }
        short8 af[4], bf[4];
#pragma unroll
        for (int m = 0; m < 4; ++m) af[m] = *(const short8*)&As[cur][aoff[m]];
#pragma unroll
        for (int n = 0; n < 4; ++n) bf[n] = *(const short8*)&Bs[cur][boff[n]];
#pragma unroll
        for (int m = 0; m < 4; ++m)
#pragma unroll
            for (int n = 0; n < 4; ++n)
                acc[m][n] = __builtin_amdgcn_mfma_f32_16x16x32_bf16(
                    af[m], bf[n], acc[m][n], 0, 0, 0);
        ++cur; if (cur == 3) cur = 0;
    }

    const int crow = row0 + wr * 64 + (lane >> 4) * 4;
    const int ccol = col0 + wc * 64 + (lane & 15);
#pragma unroll
    for (int m = 0; m < 4; ++m)
#pragma unroll
        for (int n = 0; n < 4; ++n)
#pragma unroll
            for (int r = 0; r < 4; ++r)
                C[(size_t)(crow + m * 16 + r) * NCOLS + ccol + n * 16] = f2bf(acc[m][n][r]);
}

// ============ fused fp32 -> bf16 conversion + subp pad zeroing ============
__global__ __launch_bounds__(256) void cvt_all_kernel(
    const float* __restrict__ q, const float* __restrict__ d,
    const float* __restrict__ n, const float* __restrict__ rot,
    unsigned short* __restrict__ qdnb, unsigned short* __restrict__ rotb,
    uint4* __restrict__ zdst, int zcount)
{
    const int i = blockIdx.x * 256 + threadIdx.x;  // 16B work-item index
    const int S1 = NQ * EMB / 4;
    const int S2 = S1 + NQ * EMB / 4;
    const int S3 = S2 + 4096 * EMB / 4;
    const int S4 = S3 + EMB * EMB / 4;
    if (i >= S4) {
        const int z = i - S4;
        if (z < zcount) zdst[z] = make_uint4(0u, 0u, 0u, 0u);
        return;
    }
    const float* src; unsigned short* dst; int off;
    if (i < S1)      { src = q;   dst = qdnb;                          off = i; }
    else if (i < S2) { src = d;   dst = qdnb + (size_t)NQ * EMB;       off = i - S1; }
    else if (i < S3) { src = n;   dst = qdnb + (size_t)2 * NQ * EMB;   off = i - S2; }
    else             { src = rot; dst = rotb;                          off = i - S3; }
    const float4 v = ((const float4*)src)[off];
    ushort4 b;
    b.x = f2bf(v.x); b.y = f2bf(v.y); b.z = f2bf(v.z); b.w = f2bf(v.w);
    ((ushort4*)dst)[off] = b;
}

// ============ IVF gather (bf16) ============
__global__ void gather_kernel(const float* __restrict__ centers,
                              const int* __restrict__ doc_ids,
                              const int* __restrict__ neg_ids,
                              unsigned short* __restrict__ outb)
{
    const int i = blockIdx.x;
    const int id = (i < NQ) ? doc_ids[i] : neg_ids[i - NQ];
    const int t = threadIdx.x;
    const float4 v = ((const float4*)(centers + (size_t)id * EMB))[t];
    ushort4 b;
    b.x = f2bf(v.x); b.y = f2bf(v.y); b.z = f2bf(v.z); b.w = f2bf(v.w);
    ((ushort4*)(outb + (size_t)i * EMB))[t] = b;
}

// ============ codebook prep: padded bf16 + 0.5*||c||^2 bias ============
__global__ __launch_bounds__(256) void cbprep_kernel(
    const float* __restrict__ cb, unsigned short* __restrict__ cbb,
    float* __restrict__ bias)
{
    const int idx = blockIdx.x * 256 + threadIdx.x;  // m*256 + k  (8192 total)
    const float* cp = cb + (size_t)idx * DSUB;
    unsigned short o[DPAD];
    float ss = 0.f;
#pragma unroll
    for (int j = 0; j < 6; ++j) {
        const float4 v = *(const float4*)(cp + j * 4);
        o[j * 4 + 0] = f2bf(v.x); o[j * 4 + 1] = f2bf(v.y);
        o[j * 4 + 2] = f2bf(v.z); o[j * 4 + 3] = f2bf(v.w);
        ss = fmaf(v.x, v.x, ss); ss = fmaf(v.y, v.y, ss);
        ss = fmaf(v.z, v.z, ss); ss = fmaf(v.w, v.w, ss);
    }
#pragma unroll
    for (int j = DSUB; j < DPAD; ++j) o[j] = 0;
    unsigned short* op = cbb + (size_t)idx * DPAD;
#pragma unroll
    for (int j = 0; j < DPAD / 4; ++j)
        ((ushort4*)op)[j] = make_ushort4(o[j*4], o[j*4+1], o[j*4+2], o[j*4+3]);
    bias[idx] = 0.5f * ss;
}

// ============ PQ argmin via MFMA: block = 128 rows x 256 codewords x one m ==========
__global__ __launch_bounds__(256) void pq_mfma_argmin(
    const unsigned short* __restrict__ subp,   // [NTOT][MSUB*DPAD]
    const unsigned short* __restrict__ cbb,    // [MSUB][KCODE][DPAD]
    const float* __restrict__ bias,            // [MSUB][KCODE]
    unsigned char* __restrict__ codes)         // [NTOT][MSUB]
{
    const int m = blockIdx.y;
    const int row0 = blockIdx.x * 128;
    __shared__ __align__(16) unsigned short As[128 * DPAD];   // 8 KB
    __shared__ __align__(16) unsigned short Bs[KCODE * DPAD]; // 16 KB
    __shared__ __align__(16) float bs[KCODE];                 // 1 KB
    const int tid = threadIdx.x;
    const int wave = tid >> 6, lane = tid & 63;

    {
        const int g = tid;
        const int r = g >> 2, kc = (g & 3) ^ ((r >> 1) & 3);
        gload16(subp + (size_t)(row0 + r) * (MSUB * DPAD) + m * DPAD + kc * 8, &As[g * 8]);
    }
    {
        const int g = tid + 256;
        const int r = g >> 2, kc = (g & 3) ^ ((r >> 1) & 3);
        gload16(subp + (size_t)(row0 + r) * (MSUB * DPAD) + m * DPAD + kc * 8, &As[g * 8]);
    }
#pragma unroll
    for (int i = 0; i < 4; ++i) {
        const int g = tid + i * 256;
        const int r = g >> 2, kc = (g & 3) ^ ((r >> 1) & 3);
        gload16(cbb + (size_t)m * (KCODE * DPAD) + r * DPAD + kc * 8, &Bs[g * 8]);
    }
    if (tid < 64) gload16(bias + m * KCODE + tid * 4, &bs[tid * 4]);
    __syncthreads();

    const int frow = lane & 15, kblk = lane >> 4;
    short8 af[2];
#pragma unroll
    for (int t = 0; t < 2; ++t) {
        const int r = wave * 32 + t * 16 + frow;
        af[t] = *(const short8*)&As[(r * 4 + (kblk ^ ((r >> 1) & 3))) * 8];
    }
    unsigned best[2][4];
#pragma unroll
    for (int t = 0; t < 2; ++t)
#pragma unroll
        for (int r = 0; r < 4; ++r) best[t][r] = 0xFFFFFFFFu;

#pragma unroll
    for (int n = 0; n < 16; ++n) {
        const int br = n * 16 + frow;                 // codeword index for this lane
        const short8 bf = *(const short8*)&Bs[(br * 4 + (kblk ^ ((br >> 1) & 3))) * 8];
        const float bv = bs[br];
        const unsigned kid = (unsigned)br;
        floatx4 a0 = __builtin_amdgcn_mfma_f32_16x16x32_bf16(
            af[0], bf, (floatx4){0.f, 0.f, 0.f, 0.f}, 0, 0, 0);
        floatx4 a1 = __builtin_amdgcn_mfma_f32_16x16x32_bf16(
            af[1], bf, (floatx4){0.f, 0.f, 0.f, 0.f}, 0, 0, 0);
#pragma unroll
        for (int r = 0; r < 4; ++r) {
            const float d0 = bv - a0[r];
            const float d1 = bv - a1[r];
            unsigned u0 = __float_as_uint(d0); u0 ^= (unsigned)((int)u0 >> 31) | 0x80000000u;
            unsigned u1 = __float_as_uint(d1); u1 ^= (unsigned)((int)u1 >> 31) | 0x80000000u;
            best[0][r] = min(best[0][r], (u0 & 0xFFFFFF00u) | kid);
            best[1][r] = min(best[1][r], (u1 & 0xFFFFFF00u) | kid);
        }
    }
#pragma unroll
    for (int off = 1; off <= 8; off <<= 1)
#pragma unroll
        for (int t = 0; t < 2; ++t)
#pragma unroll
            for (int r = 0; r < 4; ++r)
                best[t][r] = min(best[t][r], (unsigned)__shfl_xor((int)best[t][r], off));
    if (frow == 0) {
        const int rbase = row0 + wave * 32 + kblk * 4;
#pragma unroll
        for (int t = 0; t < 2; ++t)
#pragma unroll
            for (int r = 0; r < 4; ++r)
                codes[(size_t)(rbase + t * 16 + r) * MSUB + m] =
                    (unsigned char)(best[t][r] & 0xFFu);
    }
}

// ============ PQ reconstruct: out_bf16 = cb[m][k] + center ============
__global__ __launch_bounds__(256) void pq_recon_kernel(
    const unsigned char* __restrict__ codes, const float* __restrict__ cb,
    const unsigned short* __restrict__ ccb, unsigned short* __restrict__ outb)
{
    const int idx = blockIdx.x * 256 + threadIdx.x;  // n*32+m
    const int n = idx >> 5, m = idx & 31;
    const int k = codes[idx];
    const float* cp = cb + ((size_t)m * KCODE + k) * DSUB;
    const unsigned short* ccp = ccb + (size_t)n * EMB + m * DSUB;
    unsigned short* op = outb + (size_t)n * EMB + m * DSUB;
#pragma unroll
    for (int j = 0; j < 6; ++j) {
        const float4 a = *(const float4*)(cp + j * 4);
        const ushort4 cc = ((const ushort4*)ccp)[j];
        ushort4 o;
        o.x = f2bf(a.x + bf2f(cc.x)); o.y = f2bf(a.y + bf2f(cc.y));
        o.z = f2bf(a.z + bf2f(cc.z)); o.w = f2bf(a.w + bf2f(cc.w));
        ((ushort4*)op)[j] = o;
    }
}

// ============ fused 3-loss kernel: block per row; teacher probs in registers =======
__global__ __launch_bounds__(256) void loss_all_kernel(
    const unsigned short* __restrict__ Tb, const unsigned short* __restrict__ S0b,
    const unsigned short* __restrict__ S1b, const unsigned short* __restrict__ S2b,
    float* __restrict__ out, float scale)
{
    const int row = blockIdx.x;
    const int t = threadIdx.x, wid = t >> 6, lane = t & 63;
    __shared__ float red[4];

    auto blk_max = [&](float v) -> float {
#pragma unroll
        for (int off = 32; off >= 1; off >>= 1) v = fmaxf(v, __shfl_xor(v, off));
        if (lane == 0) red[wid] = v;
        __syncthreads();
        const float r = fmaxf(fmaxf(red[0], red[1]), fmaxf(red[2], red[3]));
        __syncthreads();
        return r;
    };
    auto blk_sum = [&](float v) -> float {
#pragma unroll
        for (int off = 32; off >= 1; off >>= 1) v += __shfl_xor(v, off);
        if (lane == 0) red[wid] = v;
        __syncthreads();
        const float r = red[0] + red[1] + red[2] + red[3];
        __syncthreads();
        return r;
    };

    // teacher probs -> registers (computed ONCE, reused by 3 losses)
    const ushort4* t4 = (const ushort4*)(Tb + (size_t)row * NCOLS);
    float tv[20];
#pragma unroll
    for (int i = 0; i < 5; ++i) {
        const ushort4 u = t4[t + i * 256];
        tv[i*4+0] = bf2f(u.x); tv[i*4+1] = bf2f(u.y);
        tv[i*4+2] = bf2f(u.z); tv[i*4+3] = bf2f(u.w);
    }
    float pm = -3.4e38f;
#pragma unroll
    for (int j = 0; j < 20; ++j) pm = fmaxf(pm, tv[j]);
    const float tm = blk_max(pm);
    float ps = 0.f;
#pragma unroll
    for (int j = 0; j < 20; ++j) ps += __builtin_amdgcn_exp2f((tv[j] - tm) * L2E);
    const float inv_t = 1.f / blk_sum(ps);
#pragma unroll
    for (int j = 0; j < 20; ++j)
        tv[j] = __builtin_amdgcn_exp2f((tv[j] - tm) * L2E) * inv_t;   // now probs

    auto do_loss = [&](const unsigned short* S, int ls) {
        const ushort4* s4 = (const ushort4*)(S + (size_t)row * NCOLS);
        float sv[20];
#pragma unroll
        for (int i = 0; i < 5; ++i) {
            const ushort4 u = s4[t + i * 256];
            sv[i*4+0] = bf2f(u.x); sv[i*4+1] = bf2f(u.y);
            sv[i*4+2] = bf2f(u.z); sv[i*4+3] = bf2f(u.w);
        }
        float m2 = -3.4e38f;
#pragma unroll
        for (int j = 0; j < 20; ++j) m2 = fmaxf(m2, sv[j]);
        const float sm = blk_max(m2);
        float s2 = 0.f;
#pragma unroll
        for (int j = 0; j < 20; ++j) s2 += __builtin_amdgcn_exp2f((sv[j] - sm) * L2E);
        const float inv_s = 1.f / blk_sum(s2);
        float acc = 0.f;
#pragma unroll
        for (int j = 0; j < 20; ++j)
            acc += tv[j] * __builtin_amdgcn_logf(
                __builtin_amdgcn_exp2f((sv[j] - sm) * L2E) * inv_s + 1e-6f);
        const float tot = blk_sum(acc);
        if (t == 0) atomicAdd(out + ls, -tot * LN2 * scale);
    };
    do_loss(S0b, 0);
    do_loss(S1b, 1);
    do_loss(S2b, 2);
}

__global__ void zero_out_kernel(float* __restrict__ out, int n)
{
    if ((int)threadIdx.x < n) out[threadIdx.x] = 0.f;
}

// ============ launch ============
extern "C" void kernel_launch(void* const* d_in, const int* in_sizes, int n_in,
                              void* d_out, int out_size, void* d_ws, size_t ws_size,
                              hipStream_t stream)
{
    const float* q    = (const float*)d_in[0];
    const float* dpos = (const float*)d_in[1];
    const float* nneg = (const float*)d_in[2];
    const float* rot  = (const float*)d_in[3];
    const float* cb   = (const float*)d_in[4];
    const float* ivf  = (const float*)d_in[5];
    const int* doc_ids = (const int*)d_in[6];
    const int* neg_ids = (const int*)d_in[7];
    float* out = (float*)d_out;

    // ---- workspace (~89 MB; ws proven >= ~124 MB by rounds 7-9) ----
    char* p = (char*)d_ws;
    auto take = [&](size_t bytes) { char* r = p; p += (bytes + 255) & ~(size_t)255; return r; };
    unsigned short* qdnb  = (unsigned short*)take((size_t)(NQ + NTOT) * EMB * 2);
    unsigned short* rqdnb = (unsigned short*)take((size_t)(NQ + NTOT) * EMB * 2);
    unsigned short* rotb  = (unsigned short*)take((size_t)EMB * EMB * 2);
    unsigned short* ccb   = (unsigned short*)take((size_t)NTOT * EMB * 2);
    unsigned short* pqb   = (unsigned short*)take((size_t)NTOT * EMB * 2);
    unsigned short* cbb   = (unsigned short*)take((size_t)MSUB * KCODE * DPAD * 2);
    float*          bias  = (float*)take((size_t)MSUB * KCODE * 4);
    unsigned char*  codes = (unsigned char*)take((size_t)NTOT * MSUB);
    unsigned short* subp  = (unsigned short*)take((size_t)NTOT * MSUB * DPAD * 2);
    unsigned short* Tb    = (unsigned short*)take((size_t)NQ * NCOLS * 2);
    unsigned short* S0b   = (unsigned short*)take((size_t)NQ * NCOLS * 2);
    unsigned short* S1b   = (unsigned short*)take((size_t)NQ * NCOLS * 2);
    unsigned short* S2b   = (unsigned short*)take((size_t)NQ * NCOLS * 2);

    unsigned short* qb   = qdnb;
    unsigned short* dnb  = qdnb + (size_t)NQ * EMB;
    unsigned short* rqb  = rqdnb;
    unsigned short* rdnb = rqdnb + (size_t)NQ * EMB;

    const float scale = 1.f / NQ;
    zero_out_kernel<<<1, 64, 0, stream>>>(out, out_size);

    // 1) fp32 -> bf16 (+ zero subp pad columns)
    const int cvt4 = (NQ * EMB + NQ * EMB + 4096 * EMB + EMB * EMB) / 4;
    const int z16 = (int)((size_t)NTOT * MSUB * DPAD * 2 / 16);
    cvt_all_kernel<<<(cvt4 + z16 + 255) / 256, 256, 0, stream>>>(
        q, dpos, nneg, rot, qdnb, rotb, (uint4*)subp, z16);

    // 2) IVF gather + codebook prep
    gather_kernel<<<NTOT, EMB / 4, 0, stream>>>(ivf, doc_ids, neg_ids, ccb);
    cbprep_kernel<<<MSUB * KCODE / 256, 256, 0, stream>>>(cb, cbb, bias);

    // 3) rotation: [q;d;n] @ rot^T -> rqdnb bf16; rows >= NQ also subp residual
    gemm_rot<<<dim3(EMB / BNR, (NQ + NTOT) / BMR), 256, 0, stream>>>(
        qdnb, rotb, rqdnb, ccb, subp, EMB, EMB, EMB, EMB);

    // 4) PQ argmin (MFMA) + reconstruct -> pqb
    pq_mfma_argmin<<<dim3(NTOT / 128, MSUB), 256, 0, stream>>>(subp, cbb, bias, codes);
    pq_recon_kernel<<<(NTOT * MSUB) / 256, 256, 0, stream>>>(codes, cb, ccb, pqb);

    // 5) all four score GEMMs in one z=4 dispatch (bf16 outputs)
    gemm_score4<<<dim3(NTOT / BNS, NQ / BMS, 4), 256, 0, stream>>>(
        qb, dnb, Tb,  rqb, rdnb, S0b,  rqb, ccb, S1b,  rqb, pqb, S2b);

    // 6) all three losses, teacher probs computed once per row in registers
    loss_all_kernel<<<NQ, 256, 0, stream>>>(Tb, S0b, S1b, S2b, out, scale);
}

// Round 11
// 146.801 us; speedup vs baseline: 6.8393x; 1.0934x over previous
//
#include <hip/hip_runtime.h>
#include <math.h>

#define EMB 768
#define MSUB 32
#define KCODE 256
#define DSUB 24
#define NQ 1024
#define NTOT 5120    // 1024 docs + 4096 negs
#define NCOLS 5120
#define DPAD 32      // padded subvector dim for MFMA (K=32)
#define L2E 1.4426950408889634f
#define LN2 0.6931471805599453f

// prep kernel section sizes (16B work items)
#define CVT4 ((NQ * EMB + NQ * EMB + 4096 * EMB + EMB * EMB) / 4)  // 1,327,104
#define GATW (NTOT * 256)                                           // 1,310,720
#define PADW (NTOT * MSUB)                                          // 163,840
#define CBPW (MSUB * KCODE)                                         // 8,192

typedef __attribute__((ext_vector_type(8))) short short8;
typedef __attribute__((ext_vector_type(4))) float floatx4;

__device__ __forceinline__ unsigned short f2bf(float f) {
    unsigned int u = __float_as_uint(f);
    unsigned int r = (u + 0x7FFFu + ((u >> 16) & 1u)) >> 16;   // RNE
    return (unsigned short)r;
}
__device__ __forceinline__ float bf2f(unsigned short h) {
    return __uint_as_float((unsigned int)h << 16);
}

__device__ __forceinline__ void gload16(const void* g, void* l) {
    __builtin_amdgcn_global_load_lds(
        (const __attribute__((address_space(1))) void*)g,
        (__attribute__((address_space(3))) void*)l, 16, 0, 0);
}

// ============ rotation GEMM: BM=64 x BN=128; 3-buffer counted-vmcnt pipeline ========
#define BMR 64
#define BNR 128
#define BKG 32
__global__ __launch_bounds__(256) void gemm_rot(
    const unsigned short* __restrict__ A, const unsigned short* __restrict__ B,
    unsigned short* __restrict__ Cb, const unsigned short* __restrict__ ccb,
    unsigned short* __restrict__ subp, int K, int lda, int ldb, int ldcb)
{
    __shared__ __align__(16) unsigned short As[3][BMR * BKG];   // 3 x 4 KB
    __shared__ __align__(16) unsigned short Bs[3][BNR * BKG];   // 3 x 8 KB
    const int tid  = threadIdx.x;
    const int wave = tid >> 6;
    const int lane = tid & 63;
    const int wr = wave >> 1, wc = wave & 1;
    const int row0 = blockIdx.y * BMR;
    const int col0 = blockIdx.x * BNR;

    const int ar  = tid >> 2, aks  = (tid & 3) ^ ((ar >> 1) & 3);
    const unsigned short* Ap = A + (size_t)(row0 + ar) * lda + aks * 8;
    const int br0 = tid >> 2,        bks0 = (tid & 3) ^ ((br0 >> 1) & 3);
    const int br1 = 64 + (tid >> 2), bks1 = (tid & 3) ^ ((br1 >> 1) & 3);
    const unsigned short* Bp0 = B + (size_t)(col0 + br0) * ldb + bks0 * 8;
    const unsigned short* Bp1 = B + (size_t)(col0 + br1) * ldb + bks1 * 8;

    const int frow = lane & 15;
    const int kblk = lane >> 4;
    int aoff[2], boff[4];
#pragma unroll
    for (int m = 0; m < 2; ++m) {
        const int r = wr * 32 + m * 16 + frow;
        aoff[m] = (r * 4 + (kblk ^ ((r >> 1) & 3))) * 8;
    }
#pragma unroll
    for (int n = 0; n < 4; ++n) {
        const int c = wc * 64 + n * 16 + frow;
        boff[n] = (c * 4 + (kblk ^ ((c >> 1) & 3))) * 8;
    }

    floatx4 acc[2][4];
#pragma unroll
    for (int m = 0; m < 2; ++m)
#pragma unroll
        for (int n = 0; n < 4; ++n)
            acc[m][n] = (floatx4){0.f, 0.f, 0.f, 0.f};

    auto STAGE = [&](int buf, int k0) {
        gload16(Ap + k0, &As[buf][tid * 8]);
        gload16(Bp0 + k0, &Bs[buf][tid * 8]);
        gload16(Bp1 + k0, &Bs[buf][(tid + 256) * 8]);
    };

    const int NT = K / BKG;
    STAGE(0, 0);
    STAGE(1, BKG);
    int cur = 0;
    for (int it = 0; it < NT; ++it) {
        if (it < NT - 1) asm volatile("s_waitcnt vmcnt(3)" ::: "memory");
        else             asm volatile("s_waitcnt vmcnt(0)" ::: "memory");
        __builtin_amdgcn_s_barrier();      // raw: does NOT drain in-flight prefetch
        asm volatile("" ::: "memory");
        if (it + 2 < NT) {
            int nb = cur + 2; if (nb >= 3) nb -= 3;
            STAGE(nb, (it + 2) * BKG);
        }
        short8 af[2], bf[4];
#pragma unroll
        for (int m = 0; m < 2; ++m) af[m] = *(const short8*)&As[cur][aoff[m]];
#pragma unroll
        for (int n = 0; n < 4; ++n) bf[n] = *(const short8*)&Bs[cur][boff[n]];
#pragma unroll
        for (int m = 0; m < 2; ++m)
#pragma unroll
            for (int n = 0; n < 4; ++n)
                acc[m][n] = __builtin_amdgcn_mfma_f32_16x16x32_bf16(
                    af[m], bf[n], acc[m][n], 0, 0, 0);
        ++cur; if (cur == 3) cur = 0;
    }

    const int crow = row0 + wr * 32 + (lane >> 4) * 4;
    const int ccol = col0 + wc * 64 + (lane & 15);
#pragma unroll
    for (int m = 0; m < 2; ++m)
#pragma unroll
        for (int n = 0; n < 4; ++n)
#pragma unroll
            for (int r = 0; r < 4; ++r) {
                const int rr = crow + m * 16 + r;
                const int cc = ccol + n * 16;
                const float v = acc[m][n][r];
                Cb[(size_t)rr * ldcb + cc] = f2bf(v);
                if (rr >= NQ) {
                    const int nn = rr - NQ;
                    const float cen = bf2f(ccb[(size_t)nn * EMB + cc]);
                    const unsigned mm = (unsigned)cc / 24u;
                    const unsigned jj = (unsigned)cc - mm * 24u;
                    subp[(size_t)nn * (MSUB * DPAD) + mm * DPAD + jj] = f2bf(v - cen);
                }
            }
}

// ============ z-batched score GEMM: 128x128, 3-buffer counted-vmcnt, bf16 out =======
#define BMS 128
#define BNS 128
__global__ __launch_bounds__(256) void gemm_score4(
    const unsigned short* __restrict__ A0, const unsigned short* __restrict__ B0, unsigned short* __restrict__ C0,
    const unsigned short* __restrict__ A1, const unsigned short* __restrict__ B1, unsigned short* __restrict__ C1,
    const unsigned short* __restrict__ A2, const unsigned short* __restrict__ B2, unsigned short* __restrict__ C2,
    const unsigned short* __restrict__ A3, const unsigned short* __restrict__ B3, unsigned short* __restrict__ C3)
{
    const unsigned short* A; const unsigned short* B; unsigned short* C;
    switch (blockIdx.z) {
        case 0:  A = A0; B = B0; C = C0; break;
        case 1:  A = A1; B = B1; C = C1; break;
        case 2:  A = A2; B = B2; C = C2; break;
        default: A = A3; B = B3; C = C3; break;
    }

    __shared__ __align__(16) unsigned short As[3][BMS * BKG];   // 3 x 8 KB
    __shared__ __align__(16) unsigned short Bs[3][BNS * BKG];   // 3 x 8 KB
    const int tid  = threadIdx.x;
    const int wave = tid >> 6;
    const int lane = tid & 63;
    const int wr = wave >> 1, wc = wave & 1;
    const int row0 = blockIdx.y * BMS;
    const int col0 = blockIdx.x * BNS;

    const int g0 = tid, g1 = tid + 256;
    const int ar0 = g0 >> 2, as0 = (g0 & 3) ^ ((ar0 >> 1) & 3);
    const int ar1 = g1 >> 2, as1 = (g1 & 3) ^ ((ar1 >> 1) & 3);
    const unsigned short* Ap0 = A + (size_t)(row0 + ar0) * EMB + as0 * 8;
    const unsigned short* Ap1 = A + (size_t)(row0 + ar1) * EMB + as1 * 8;
    const unsigned short* Bp0 = B + (size_t)(col0 + ar0) * EMB + as0 * 8;
    const unsigned short* Bp1 = B + (size_t)(col0 + ar1) * EMB + as1 * 8;

    const int frow = lane & 15;
    const int kblk = lane >> 4;
    int aoff[4], boff[4];
#pragma unroll
    for (int m = 0; m < 4; ++m) {
        const int r = wr * 64 + m * 16 + frow;
        aoff[m] = (r * 4 + (kblk ^ ((r >> 1) & 3))) * 8;
        const int c = wc * 64 + m * 16 + frow;
        boff[m] = (c * 4 + (kblk ^ ((c >> 1) & 3))) * 8;
    }

    floatx4 acc[4][4];
#pragma unroll
    for (int m = 0; m < 4; ++m)
#pragma unroll
        for (int n = 0; n < 4; ++n)
            acc[m][n] = (floatx4){0.f, 0.f, 0.f, 0.f};

    auto STAGE = [&](int buf, int k0) {
        gload16(Ap0 + k0, &As[buf][g0 * 8]);
        gload16(Ap1 + k0, &As[buf][g1 * 8]);
        gload16(Bp0 + k0, &Bs[buf][g0 * 8]);
        gload16(Bp1 + k0, &Bs[buf][g1 * 8]);
    };

    const int NT = EMB / BKG;
    STAGE(0, 0);
    STAGE(1, BKG);
    int cur = 0;
    for (int it = 0; it < NT; ++it) {
        if (it < NT - 1) asm volatile("s_waitcnt vmcnt(4)" ::: "memory");
        else             asm volatile("s_waitcnt vmcnt(0)" ::: "memory");
        __builtin_amdgcn_s_barrier();
        asm volatile("" ::: "memory");
        if (it + 2 < NT) {
            int nb = cur + 2; if (nb >= 3) nb -= 3;
            STAGE(nb, (it + 2) * BKG);
        }
        short8 af[4], bf[4];
#pragma unroll
        for (int m = 0; m < 4; ++m) af[m] = *(const short8*)&As[cur][aoff[m]];
#pragma unroll
        for (int n = 0; n < 4; ++n) bf[n] = *(const short8*)&Bs[cur][boff[n]];
#pragma unroll
        for (int m = 0; m < 4; ++m)
#pragma unroll
            for (int n = 0; n < 4; ++n)
                acc[m][n] = __builtin_amdgcn_mfma_f32_16x16x32_bf16(
                    af[m], bf[n], acc[m][n], 0, 0, 0);
        ++cur; if (cur == 3) cur = 0;
    }

    const int crow = row0 + wr * 64 + (lane >> 4) * 4;
    const int ccol = col0 + wc * 64 + (lane & 15);
#pragma unroll
    for (int m = 0; m < 4; ++m)
#pragma unroll
        for (int n = 0; n < 4; ++n)
#pragma unroll
            for (int r = 0; r < 4; ++r)
                C[(size_t)(crow + m * 16 + r) * NCOLS + ccol + n * 16] = f2bf(acc[m][n][r]);
}

// ============ fused prep: out-zero + cvt + IVF gather + subp pad-zero + cbprep ======
__global__ __launch_bounds__(256) void prep_kernel(
    const float* __restrict__ q, const float* __restrict__ d,
    const float* __restrict__ n, const float* __restrict__ rot,
    const float* __restrict__ cb, const float* __restrict__ ivf,
    const int* __restrict__ doc_ids, const int* __restrict__ neg_ids,
    unsigned short* __restrict__ qdnb, unsigned short* __restrict__ rotb,
    unsigned short* __restrict__ ccb, unsigned short* __restrict__ subp,
    unsigned short* __restrict__ cbb, float* __restrict__ bias,
    float* __restrict__ out, int out_n)
{
    int i = blockIdx.x * 256 + threadIdx.x;

    // --- section A: fp32 -> bf16 conversions (q, d, n, rot) ---
    if (i < CVT4) {
        const int S1 = NQ * EMB / 4;
        const int S2 = S1 + NQ * EMB / 4;
        const int S3 = S2 + 4096 * EMB / 4;
        const float* src; unsigned short* dst; int off;
        if (i < S1)      { src = q;   dst = qdnb;                        off = i; }
        else if (i < S2) { src = d;   dst = qdnb + (size_t)NQ * EMB;     off = i - S1; }
        else if (i < S3) { src = n;   dst = qdnb + (size_t)2 * NQ * EMB; off = i - S2; }
        else             { src = rot; dst = rotb;                        off = i - S3; }
        const float4 v = ((const float4*)src)[off];
        ushort4 b;
        b.x = f2bf(v.x); b.y = f2bf(v.y); b.z = f2bf(v.z); b.w = f2bf(v.w);
        ((ushort4*)dst)[off] = b;
        return;
    }
    i -= CVT4;

    // --- section B: IVF gather (bf16); 192 of every 256 threads active ---
    if (i < GATW) {
        const int row = i >> 8, t = i & 255;
        if (t < EMB / 4) {
            const int id = (row < NQ) ? doc_ids[row] : neg_ids[row - NQ];
            const float4 v = ((const float4*)(ivf + (size_t)id * EMB))[t];
            ushort4 b;
            b.x = f2bf(v.x); b.y = f2bf(v.y); b.z = f2bf(v.z); b.w = f2bf(v.w);
            ((ushort4*)(ccb + (size_t)row * EMB))[t] = b;
        }
        return;
    }
    i -= GATW;

    // --- section C: zero subp pad columns (j in [24,32) of each (n,m)) ---
    if (i < PADW) {
        const int nn = i >> 5, mm = i & 31;
        *(uint4*)(subp + (size_t)nn * (MSUB * DPAD) + mm * DPAD + DSUB) =
            make_uint4(0u, 0u, 0u, 0u);
        return;
    }
    i -= PADW;

    // --- section D: codebook prep (padded bf16 + 0.5*||c||^2) ---
    if (i < CBPW) {
        const float* cp = cb + (size_t)i * DSUB;
        unsigned short o[DPAD];
        float ss = 0.f;
#pragma unroll
        for (int j = 0; j < 6; ++j) {
            const float4 v = *(const float4*)(cp + j * 4);
            o[j * 4 + 0] = f2bf(v.x); o[j * 4 + 1] = f2bf(v.y);
            o[j * 4 + 2] = f2bf(v.z); o[j * 4 + 3] = f2bf(v.w);
            ss = fmaf(v.x, v.x, ss); ss = fmaf(v.y, v.y, ss);
            ss = fmaf(v.z, v.z, ss); ss = fmaf(v.w, v.w, ss);
        }
#pragma unroll
        for (int j = DSUB; j < DPAD; ++j) o[j] = 0;
        unsigned short* op = cbb + (size_t)i * DPAD;
#pragma unroll
        for (int j = 0; j < DPAD / 4; ++j)
            ((ushort4*)op)[j] = make_ushort4(o[j*4], o[j*4+1], o[j*4+2], o[j*4+3]);
        bias[i] = 0.5f * ss;
        return;
    }
    i -= CBPW;

    // --- section E: zero output ---
    if (i < 64 && i < out_n) out[i] = 0.f;
}

// ============ PQ argmin via MFMA + fused reconstruct ============
// block = 128 rows x 256 codewords x one m; writes pqb[row][m*24..] = cb[k]+center
__global__ __launch_bounds__(256) void pq_mfma_argmin(
    const unsigned short* __restrict__ subp,   // [NTOT][MSUB*DPAD]
    const unsigned short* __restrict__ cbb,    // [MSUB][KCODE][DPAD]
    const float* __restrict__ bias,            // [MSUB][KCODE]
    const unsigned short* __restrict__ ccb,    // [NTOT][EMB]
    unsigned short* __restrict__ pqb)          // [NTOT][EMB]
{
    const int m = blockIdx.y;
    const int row0 = blockIdx.x * 128;
    __shared__ __align__(16) unsigned short As[128 * DPAD];   // 8 KB
    __shared__ __align__(16) unsigned short Bs[KCODE * DPAD]; // 16 KB
    __shared__ __align__(16) float bs[KCODE];                 // 1 KB
    __shared__ unsigned char kbest[128];
    const int tid = threadIdx.x;
    const int wave = tid >> 6, lane = tid & 63;

    {
        const int g = tid;
        const int r = g >> 2, kc = (g & 3) ^ ((r >> 1) & 3);
        gload16(subp + (size_t)(row0 + r) * (MSUB * DPAD) + m * DPAD + kc * 8, &As[g * 8]);
    }
    {
        const int g = tid + 256;
        const int r = g >> 2, kc = (g & 3) ^ ((r >> 1) & 3);
        gload16(subp + (size_t)(row0 + r) * (MSUB * DPAD) + m * DPAD + kc * 8, &As[g * 8]);
    }
#pragma unroll
    for (int i = 0; i < 4; ++i) {
        const int g = tid + i * 256;
        const int r = g >> 2, kc = (g & 3) ^ ((r >> 1) & 3);
        gload16(cbb + (size_t)m * (KCODE * DPAD) + r * DPAD + kc * 8, &Bs[g * 8]);
    }
    if (tid < 64) gload16(bias + m * KCODE + tid * 4, &bs[tid * 4]);
    __syncthreads();

    const int frow = lane & 15, kblk = lane >> 4;
    short8 af[2];
#pragma unroll
    for (int t = 0; t < 2; ++t) {
        const int r = wave * 32 + t * 16 + frow;
        af[t] = *(const short8*)&As[(r * 4 + (kblk ^ ((r >> 1) & 3))) * 8];
    }
    unsigned best[2][4];
#pragma unroll
    for (int t = 0; t < 2; ++t)
#pragma unroll
        for (int r = 0; r < 4; ++r) best[t][r] = 0xFFFFFFFFu;

#pragma unroll
    for (int n = 0; n < 16; ++n) {
        const int br = n * 16 + frow;                 // codeword index for this lane
        const short8 bf = *(const short8*)&Bs[(br * 4 + (kblk ^ ((br >> 1) & 3))) * 8];
        const float bv = bs[br];
        const unsigned kid = (unsigned)br;
        floatx4 a0 = __builtin_amdgcn_mfma_f32_16x16x32_bf16(
            af[0], bf, (floatx4){0.f, 0.f, 0.f, 0.f}, 0, 0, 0);
        floatx4 a1 = __builtin_amdgcn_mfma_f32_16x16x32_bf16(
            af[1], bf, (floatx4){0.f, 0.f, 0.f, 0.f}, 0, 0, 0);
#pragma unroll
        for (int r = 0; r < 4; ++r) {
            const float d0 = bv - a0[r];
            const float d1 = bv - a1[r];
            unsigned u0 = __float_as_uint(d0); u0 ^= (unsigned)((int)u0 >> 31) | 0x80000000u;
            unsigned u1 = __float_as_uint(d1); u1 ^= (unsigned)((int)u1 >> 31) | 0x80000000u;
            best[0][r] = min(best[0][r], (u0 & 0xFFFFFF00u) | kid);
            best[1][r] = min(best[1][r], (u1 & 0xFFFFFF00u) | kid);
        }
    }
#pragma unroll
    for (int off = 1; off <= 8; off <<= 1)
#pragma unroll
        for (int t = 0; t < 2; ++t)
#pragma unroll
            for (int r = 0; r < 4; ++r)
                best[t][r] = min(best[t][r], (unsigned)__shfl_xor((int)best[t][r], off));
    if (frow == 0) {
        const int rbase = wave * 32 + kblk * 4;       // local row
#pragma unroll
        for (int t = 0; t < 2; ++t)
#pragma unroll
            for (int r = 0; r < 4; ++r)
                kbest[rbase + t * 16 + r] = (unsigned char)(best[t][r] & 0xFFu);
    }
    __syncthreads();

    // fused reconstruct: one thread per row
    if (tid < 128) {
        const int row = row0 + tid;
        const int k = kbest[tid];
        const unsigned short* cbp = cbb + ((size_t)m * KCODE + k) * DPAD;
        const unsigned short* ccp = ccb + (size_t)row * EMB + m * DSUB;
        unsigned short* op = pqb + (size_t)row * EMB + m * DSUB;
#pragma unroll
        for (int j = 0; j < 6; ++j) {
            const ushort4 cw = ((const ushort4*)cbp)[j];
            const ushort4 cc = ((const ushort4*)ccp)[j];
            ushort4 o;
            o.x = f2bf(bf2f(cw.x) + bf2f(cc.x)); o.y = f2bf(bf2f(cw.y) + bf2f(cc.y));
            o.z = f2bf(bf2f(cw.z) + bf2f(cc.z)); o.w = f2bf(bf2f(cw.w) + bf2f(cc.w));
            ((ushort4*)op)[j] = o;
        }
    }
}

// ============ fused 3-loss kernel: block per row; slot-based 1-barrier reductions ===
__global__ __launch_bounds__(256) void loss_all_kernel(
    const unsigned short* __restrict__ Tb, const unsigned short* __restrict__ S0b,
    const unsigned short* __restrict__ S1b, const unsigned short* __restrict__ S2b,
    float* __restrict__ out, float scale)
{
    const int row = blockIdx.x;
    const int t = threadIdx.x, wid = t >> 6, lane = t & 63;
    __shared__ float red[12][4];

    auto blk_max = [&](float v, int slot) -> float {
#pragma unroll
        for (int off = 32; off >= 1; off >>= 1) v = fmaxf(v, __shfl_xor(v, off));
        if (lane == 0) red[slot][wid] = v;
        __syncthreads();
        return fmaxf(fmaxf(red[slot][0], red[slot][1]),
                     fmaxf(red[slot][2], red[slot][3]));
    };
    auto blk_sum = [&](float v, int slot) -> float {
#pragma unroll
        for (int off = 32; off >= 1; off >>= 1) v += __shfl_xor(v, off);
        if (lane == 0) red[slot][wid] = v;
        __syncthreads();
        return red[slot][0] + red[slot][1] + red[slot][2] + red[slot][3];
    };

    // teacher probs -> registers (computed ONCE, reused by 3 losses)
    const ushort4* t4 = (const ushort4*)(Tb + (size_t)row * NCOLS);
    float tv[20];
#pragma unroll
    for (int i = 0; i < 5; ++i) {
        const ushort4 u = t4[t + i * 256];
        tv[i*4+0] = bf2f(u.x); tv[i*4+1] = bf2f(u.y);
        tv[i*4+2] = bf2f(u.z); tv[i*4+3] = bf2f(u.w);
    }
    float pm = -3.4e38f;
#pragma unroll
    for (int j = 0; j < 20; ++j) pm = fmaxf(pm, tv[j]);
    const float tm = blk_max(pm, 0);
    float ps = 0.f;
#pragma unroll
    for (int j = 0; j < 20; ++j) ps += __builtin_amdgcn_exp2f((tv[j] - tm) * L2E);
    const float inv_t = 1.f / blk_sum(ps, 1);
#pragma unroll
    for (int j = 0; j < 20; ++j)
        tv[j] = __builtin_amdgcn_exp2f((tv[j] - tm) * L2E) * inv_t;   // now probs

    auto do_loss = [&](const unsigned short* S, int ls) {
        const ushort4* s4 = (const ushort4*)(S + (size_t)row * NCOLS);
        float sv[20];
#pragma unroll
        for (int i = 0; i < 5; ++i) {
            const ushort4 u = s4[t + i * 256];
            sv[i*4+0] = bf2f(u.x); sv[i*4+1] = bf2f(u.y);
            sv[i*4+2] = bf2f(u.z); sv[i*4+3] = bf2f(u.w);
        }
        float m2 = -3.4e38f;
#pragma unroll
        for (int j = 0; j < 20; ++j) m2 = fmaxf(m2, sv[j]);
        const float sm = blk_max(m2, 2 + ls * 3);
        float s2 = 0.f;
#pragma unroll
        for (int j = 0; j < 20; ++j) s2 += __builtin_amdgcn_exp2f((sv[j] - sm) * L2E);
        const float inv_s = 1.f / blk_sum(s2, 3 + ls * 3);
        float acc = 0.f;
#pragma unroll
        for (int j = 0; j < 20; ++j)
            acc += tv[j] * __builtin_amdgcn_logf(
                __builtin_amdgcn_exp2f((sv[j] - sm) * L2E) * inv_s + 1e-6f);
        const float tot = blk_sum(acc, 4 + ls * 3);
        if (t == 0) atomicAdd(out + ls, -tot * LN2 * scale);
    };
    do_loss(S0b, 0);
    do_loss(S1b, 1);
    do_loss(S2b, 2);
}

// ============ launch ============
extern "C" void kernel_launch(void* const* d_in, const int* in_sizes, int n_in,
                              void* d_out, int out_size, void* d_ws, size_t ws_size,
                              hipStream_t stream)
{
    const float* q    = (const float*)d_in[0];
    const float* dpos = (const float*)d_in[1];
    const float* nneg = (const float*)d_in[2];
    const float* rot  = (const float*)d_in[3];
    const float* cb   = (const float*)d_in[4];
    const float* ivf  = (const float*)d_in[5];
    const int* doc_ids = (const int*)d_in[6];
    const int* neg_ids = (const int*)d_in[7];
    float* out = (float*)d_out;

    char* p = (char*)d_ws;
    auto take = [&](size_t bytes) { char* r = p; p += (bytes + 255) & ~(size_t)255; return r; };
    unsigned short* qdnb  = (unsigned short*)take((size_t)(NQ + NTOT) * EMB * 2);
    unsigned short* rqdnb = (unsigned short*)take((size_t)(NQ + NTOT) * EMB * 2);
    unsigned short* rotb  = (unsigned short*)take((size_t)EMB * EMB * 2);
    unsigned short* ccb   = (unsigned short*)take((size_t)NTOT * EMB * 2);
    unsigned short* pqb   = (unsigned short*)take((size_t)NTOT * EMB * 2);
    unsigned short* cbb   = (unsigned short*)take((size_t)MSUB * KCODE * DPAD * 2);
    float*          bias  = (float*)take((size_t)MSUB * KCODE * 4);
    unsigned short* subp  = (unsigned short*)take((size_t)NTOT * MSUB * DPAD * 2);
    unsigned short* Tb    = (unsigned short*)take((size_t)NQ * NCOLS * 2);
    unsigned short* S0b   = (unsigned short*)take((size_t)NQ * NCOLS * 2);
    unsigned short* S1b   = (unsigned short*)take((size_t)NQ * NCOLS * 2);
    unsigned short* S2b   = (unsigned short*)take((size_t)NQ * NCOLS * 2);

    unsigned short* qb   = qdnb;
    unsigned short* dnb  = qdnb + (size_t)NQ * EMB;
    unsigned short* rqb  = rqdnb;
    unsigned short* rdnb = rqdnb + (size_t)NQ * EMB;

    const float scale = 1.f / NQ;

    // 1) fused prep: out-zero + cvt + gather + subp-pad-zero + cbprep
    const int prepW = CVT4 + GATW + PADW + CBPW + 64;
    prep_kernel<<<(prepW + 255) / 256, 256, 0, stream>>>(
        q, dpos, nneg, rot, cb, ivf, doc_ids, neg_ids,
        qdnb, rotb, ccb, subp, cbb, bias, out, out_size);

    // 2) rotation: [q;d;n] @ rot^T -> rqdnb bf16; rows >= NQ also subp residual
    gemm_rot<<<dim3(EMB / BNR, (NQ + NTOT) / BMR), 256, 0, stream>>>(
        qdnb, rotb, rqdnb, ccb, subp, EMB, EMB, EMB, EMB);

    // 3) PQ argmin (MFMA) with fused reconstruct -> pqb
    pq_mfma_argmin<<<dim3(NTOT / 128, MSUB), 256, 0, stream>>>(
        subp, cbb, bias, ccb, pqb);

    // 4) all four score GEMMs in one z=4 dispatch (bf16 outputs)
    gemm_score4<<<dim3(NTOT / BNS, NQ / BMS, 4), 256, 0, stream>>>(
        qb, dnb, Tb,  rqb, rdnb, S0b,  rqb, ccb, S1b,  rqb, pqb, S2b);

    // 5) all three losses, teacher probs computed once per row in registers
    loss_all_kernel<<<NQ, 256, 0, stream>>>(Tb, S0b, S1b, S2b, out, scale);
}